// Round 11
// baseline (18150.249 us; speedup 1.0000x reference)
//
#include <hip/hip_runtime.h>
#include <hip/hip_bf16.h>
#include <cstdint>

typedef __hip_bfloat16 bf16;
typedef __attribute__((ext_vector_type(8))) short bf16x8v;   // 8 bf16 in 4 VGPRs
typedef __attribute__((ext_vector_type(4))) float f32x4;

#define NB 256          // persistent blocks (1 per CU)
#define NT 512          // 8 waves (2 per SIMD)
#define TM1 64

// output offsets (elements) in d_out, per reference return order
#define OUT_BEL  ((size_t)0)
#define OUT_PST  ((size_t)67108864)
#define OUT_PMU  ((size_t)75497472)
#define OUT_PSD  ((size_t)83886080)
#define OUT_QST  ((size_t)92274688)
#define OUT_QMU  ((size_t)100663296)
#define OUT_QSD  ((size_t)109051904)

__device__ __forceinline__ void gload_lds16(const bf16* g, bf16* l) {
  __builtin_amdgcn_global_load_lds(
      (const __attribute__((address_space(1))) unsigned int*)g,
      (__attribute__((address_space(3))) unsigned int*)l, 16, 0, 0);
}

__device__ __forceinline__ unsigned short bfb(float f) {
  bf16 h = __float2bfloat16(f);
  return *reinterpret_cast<unsigned short*>(&h);
}

__device__ __forceinline__ float sigmoidf_(float x) { return 1.f / (1.f + __expf(-x)); }

// XCD-spread job id: block bid gets job (bid&7)*(nj/8)+(bid>>3), or -1 if idle.
__device__ __forceinline__ int jid(int bid, int nj) {
  return (bid < nj) ? ((bid & 7) * (nj >> 3) + (bid >> 3)) : -1;
}

// ---------------------------------------------------------------------------
// hierarchical device-scope grid barrier (epoch-monotone, memset-zeroed)
// ---------------------------------------------------------------------------
__device__ __forceinline__ void gbar(unsigned* bars, unsigned e, int bid) {
  __syncthreads();
  const int g = bid & 7;
  const int tid = threadIdx.x;
  if (tid == 0) {
    __threadfence();   // release
    __hip_atomic_fetch_add(&bars[16 * g], 1u, __ATOMIC_RELAXED, __HIP_MEMORY_SCOPE_AGENT);
  }
  if (bid == 0) {
    if (tid < 8) {
      while (__hip_atomic_load(&bars[16 * tid], __ATOMIC_RELAXED, __HIP_MEMORY_SCOPE_AGENT) < 32u * e)
        __builtin_amdgcn_s_sleep(1);
    }
    __syncthreads();
    if (tid < 8)
      __hip_atomic_store(&bars[128 + 16 * tid], e, __ATOMIC_RELAXED, __HIP_MEMORY_SCOPE_AGENT);
  } else if (tid == 0) {
    while (__hip_atomic_load(&bars[128 + 16 * g], __ATOMIC_RELAXED, __HIP_MEMORY_SCOPE_AGENT) < e)
      __builtin_amdgcn_s_sleep(2);
  }
  if (tid == 0) __threadfence();   // acquire
  __syncthreads();
}

// ---------------------------------------------------------------------------
// generic GEMM tile: counted-vmcnt depth-DEPTH pipeline.
// C[M,N] = A[M,K](bf16,row) @ B[N,K](bf16,row)^T + bias.
// waves 4m x 2n. T2 XOR swizzle on global src + ds_read addr.
// mode 0: C fp32. mode 1: C bf16 + relu. job decode: m fastest.
// ---------------------------------------------------------------------------
template<int BM, int BN, int DEPTH>
__device__ void gemm_tile(const bf16* __restrict__ A, const bf16* __restrict__ B,
                          const float* __restrict__ bias, void* __restrict__ C,
                          int N, int K, int nm, int mode, int job, int tid,
                          char* pool)
{
  constexpr int LA = BM * 8 / NT;
  constexpr int LB = BN * 8 / NT;
  constexpr int L = LA + LB;
  constexpr int WMt = BM / 4, WNt = BN / 2;
  constexpr int MR = WMt / 16, NR = WNt / 16;
  bf16* sAb = (bf16*)pool;                              // DEPTH x BM*64
  bf16* sBb = (bf16*)(pool + (size_t)DEPTH * BM * 64 * 2);

  const int m0 = (job % nm) * BM;
  const int n0 = (job / nm) * BN;
  const int lane = tid & 63;
  const int wid = tid >> 6;
  const int wm = wid >> 1, wn = wid & 1;
  const int lr = lane & 15;
  const int lg = lane >> 4;

  const bf16* Abase = A + (size_t)m0 * K;
  const bf16* Bbase = B + (size_t)n0 * K;

  auto stage = [&](int buf, int k0) {
    bf16* dA = sAb + buf * (BM * 64);
    bf16* dB = sBb + buf * (BN * 64);
    #pragma unroll
    for (int i = 0; i < LA; ++i) {
      int c = i * NT + tid;
      int row = c >> 3, kc = c & 7;
      gload_lds16(Abase + (size_t)row * K + k0 + ((kc ^ (row & 7)) << 3), &dA[c * 8]);
    }
    #pragma unroll
    for (int i = 0; i < LB; ++i) {
      int c = i * NT + tid;
      int row = c >> 3, kc = c & 7;
      gload_lds16(Bbase + (size_t)row * K + k0 + ((kc ^ (row & 7)) << 3), &dB[c * 8]);
    }
  };

  f32x4 acc[MR][NR] = {};
  __syncthreads();                 // pool handoff
  const int nk = K >> 6;
  #pragma unroll
  for (int d = 0; d < DEPTH; ++d)
    if (d < nk) stage(d, d << 6);
  int cur = 0;
  for (int it = 0; it < nk; ++it) {
    if (DEPTH == 3) {
      if (it + 2 < nk)      { asm volatile("s_waitcnt vmcnt(%0)" :: "n"(2 * L) : "memory"); }
      else if (it + 1 < nk) { asm volatile("s_waitcnt vmcnt(%0)" :: "n"(L) : "memory"); }
      else                  { asm volatile("s_waitcnt vmcnt(0)" ::: "memory"); }
    } else {
      if (it + 1 < nk)      { asm volatile("s_waitcnt vmcnt(%0)" :: "n"(L) : "memory"); }
      else                  { asm volatile("s_waitcnt vmcnt(0)" ::: "memory"); }
    }
    __builtin_amdgcn_sched_barrier(0);
    __builtin_amdgcn_s_barrier();
    __builtin_amdgcn_sched_barrier(0);
    const bf16* cA = sAb + cur * (BM * 64);
    const bf16* cB = sBb + cur * (BN * 64);
    #pragma unroll
    for (int kk = 0; kk < 2; ++kk) {
      const int jg = kk * 4 + lg;
      bf16x8v af[MR], bfv[NR];
      #pragma unroll
      for (int m = 0; m < MR; ++m) {
        int ar = wm * WMt + m * 16 + lr;
        af[m] = *(const bf16x8v*)&cA[ar * 64 + ((jg ^ (ar & 7)) << 3)];
      }
      #pragma unroll
      for (int n = 0; n < NR; ++n) {
        int br = wn * WNt + n * 16 + lr;
        bfv[n] = *(const bf16x8v*)&cB[br * 64 + ((jg ^ (br & 7)) << 3)];
      }
      #pragma unroll
      for (int m = 0; m < MR; ++m)
        #pragma unroll
        for (int n = 0; n < NR; ++n)
          acc[m][n] = __builtin_amdgcn_mfma_f32_16x16x32_bf16(af[m], bfv[n], acc[m][n], 0, 0, 0);
    }
    __builtin_amdgcn_sched_barrier(0);
    __builtin_amdgcn_s_barrier();
    __builtin_amdgcn_sched_barrier(0);
    if (it + DEPTH < nk) stage(cur, (it + DEPTH) << 6);
    cur = (cur + 1 == DEPTH) ? 0 : cur + 1;
  }

  const int r0 = (lane >> 4) * 4;
  #pragma unroll
  for (int m = 0; m < MR; ++m) {
    #pragma unroll
    for (int n = 0; n < NR; ++n) {
      int gc = n0 + wn * WNt + n * 16 + lr;
      float bv = bias[gc];
      #pragma unroll
      for (int r = 0; r < 4; ++r) {
        int gr = m0 + wm * WMt + m * 16 + r0 + r;
        float v = acc[m][n][r] + bv;
        if (mode == 1)
          ((bf16*)C)[(size_t)gr * N + gc] = __float2bfloat16(v > 0.f ? v : 0.f);
        else
          ((float*)C)[(size_t)gr * N + gc] = v;
      }
    }
  }
}

// ---------------------------------------------------------------------------
// FUSED GRU: 64 jobs of (128 rows x 128 gate-cols x 3 gates).
// K = 32 Wi-tiles then 32 Wh-tiles; r,z summed across both halves; i_n, h_n
// kept separate. Epilogue applies GRU nonlinearity + carry.
// LDS: A 2x16KB at [0,32K) + B 2x48KB at [32K,128K). L=8, depth-2.
// ---------------------------------------------------------------------------
__device__ void fused_gru(const bf16* __restrict__ hidden, const bf16* __restrict__ belsrc,
                          const bf16* __restrict__ WiT, const bf16* __restrict__ WhT,
                          const float* __restrict__ bi, const float* __restrict__ bh,
                          float* __restrict__ belief_f32, float* __restrict__ out_bel,
                          bf16* __restrict__ belslot,
                          int job, int tid, char* pool)
{
  bf16 (*sA)[128 * 64] = (bf16(*)[128 * 64])pool;              // 2 x 16KB
  bf16 (*sB)[384 * 64] = (bf16(*)[384 * 64])(pool + 32768);    // 2 x 48KB (FIX: was 65536, overflowed 128KB)

  const int m0 = (job & 3) * 128;
  const int j0 = (job >> 2) * 128;
  const int lane = tid & 63;
  const int wid = tid >> 6;
  const int wm = wid >> 1, wn = wid & 1;   // 4m x 2n: WMt=32, WNt=64
  const int lr = lane & 15;
  const int lg = lane >> 4;

  auto stage = [&](int buf, int gt) {
    const bf16* Ab; const bf16* Bb; int k0;
    if (gt < 32) { Ab = hidden; Bb = WiT; k0 = gt << 6; }
    else         { Ab = belsrc; Bb = WhT; k0 = (gt - 32) << 6; }
    #pragma unroll
    for (int i = 0; i < 2; ++i) {        // A: 128 rows x 8 chunks
      int c = i * NT + tid;
      int row = c >> 3, kc = c & 7;
      gload_lds16(Ab + (size_t)(m0 + row) * 2048 + k0 + ((kc ^ (row & 7)) << 3),
                  &sA[buf][c * 8]);
    }
    #pragma unroll
    for (int i = 0; i < 6; ++i) {        // B: 384 rows (3 gates x 128 cols)
      int c = i * NT + tid;
      int r = c >> 3, kc = c & 7;
      int grow = (r >> 7) * 2048 + j0 + (r & 127);
      gload_lds16(Bb + (size_t)grow * 2048 + k0 + ((kc ^ (r & 7)) << 3),
                  &sB[buf][c * 8]);
    }
  };

  f32x4 ar_[2][4] = {}, az_[2][4] = {}, ain[2][4] = {}, ahn[2][4] = {};

  auto body = [&](int gt, f32x4 (&ax)[2][4]) {
    const int cur = gt & 1;
    if (gt < 63) { asm volatile("s_waitcnt vmcnt(8)" ::: "memory"); }
    else         { asm volatile("s_waitcnt vmcnt(0)" ::: "memory"); }
    __builtin_amdgcn_sched_barrier(0);
    __builtin_amdgcn_s_barrier();
    __builtin_amdgcn_sched_barrier(0);
    #pragma unroll
    for (int kk = 0; kk < 2; ++kk) {
      const int jg = kk * 4 + lg;
      bf16x8v af[2], bg[3][4];
      #pragma unroll
      for (int m = 0; m < 2; ++m) {
        int arow = wm * 32 + m * 16 + lr;
        af[m] = *(const bf16x8v*)&sA[cur][arow * 64 + ((jg ^ (arow & 7)) << 3)];
      }
      #pragma unroll
      for (int g = 0; g < 3; ++g)
        #pragma unroll
        for (int n = 0; n < 4; ++n) {
          int br = g * 128 + wn * 64 + n * 16 + lr;
          bg[g][n] = *(const bf16x8v*)&sB[cur][br * 64 + ((jg ^ (br & 7)) << 3)];
        }
      #pragma unroll
      for (int m = 0; m < 2; ++m)
        #pragma unroll
        for (int n = 0; n < 4; ++n) {
          ar_[m][n] = __builtin_amdgcn_mfma_f32_16x16x32_bf16(af[m], bg[0][n], ar_[m][n], 0, 0, 0);
          az_[m][n] = __builtin_amdgcn_mfma_f32_16x16x32_bf16(af[m], bg[1][n], az_[m][n], 0, 0, 0);
          ax[m][n]  = __builtin_amdgcn_mfma_f32_16x16x32_bf16(af[m], bg[2][n], ax[m][n], 0, 0, 0);
        }
    }
    __builtin_amdgcn_sched_barrier(0);
    __builtin_amdgcn_s_barrier();
    __builtin_amdgcn_sched_barrier(0);
    if (gt + 2 < 64) stage(cur, gt + 2);
  };

  __syncthreads();                 // pool handoff
  stage(0, 0);
  stage(1, 1);
  for (int gt = 0; gt < 32; ++gt) body(gt, ain);
  for (int gt = 32; gt < 64; ++gt) body(gt, ahn);

  // epilogue: GRU nonlinearity + carry
  const int r0 = (lane >> 4) * 4;
  #pragma unroll
  for (int n = 0; n < 4; ++n) {
    const int gc = j0 + wn * 64 + n * 16 + lr;
    const float br_b  = bi[gc] + bh[gc];
    const float bz_b  = bi[2048 + gc] + bh[2048 + gc];
    const float bin_b = bi[4096 + gc];
    const float bhn_b = bh[4096 + gc];
    #pragma unroll
    for (int m = 0; m < 2; ++m) {
      #pragma unroll
      for (int r = 0; r < 4; ++r) {
        int grow = m0 + wm * 32 + m * 16 + r0 + r;
        size_t idx = (size_t)grow * 2048 + gc;
        float rr = sigmoidf_(ar_[m][n][r] + br_b);
        float zz = sigmoidf_(az_[m][n][r] + bz_b);
        float nn = tanhf(ain[m][n][r] + bin_b + rr * (ahn[m][n][r] + bhn_b));
        float bo = belief_f32[idx];
        float nb = (1.f - zz) * nn + zz * bo;
        belief_f32[idx] = nb;
        out_bel[idx] = nb;
        belslot[idx] = __float2bfloat16(nb);
      }
    }
  }
}

// ---------------------------------------------------------------------------
// W1p GEMM, dual-source A (belA[t] 2048 ++ obsB[t] 1024), K=3072, 64 jobs of
// 128x128, depth-3 (96KB), relu->bf16.
// ---------------------------------------------------------------------------
__device__ void gemm_w1p(const bf16* __restrict__ Abel, const bf16* __restrict__ Aobs,
                         const bf16* __restrict__ B, const float* __restrict__ bias,
                         bf16* __restrict__ C, int job, int tid, char* pool)
{
  constexpr int K = 3072, NK = 48;
  bf16* sAb = (bf16*)pool;                 // 3 x 16KB
  bf16* sBb = (bf16*)(pool + 49152);       // 3 x 16KB

  const int m0 = (job & 3) * 128;
  const int n0 = (job >> 2) * 128;
  const int lane = tid & 63;
  const int wid = tid >> 6;
  const int wm = wid >> 1, wn = wid & 1;   // WMt=32, WNt=64: MR=2, NR=4
  const int lr = lane & 15;
  const int lg = lane >> 4;

  auto stage = [&](int buf, int k0) {
    bf16* dA = sAb + buf * (128 * 64);
    bf16* dB = sBb + buf * (128 * 64);
    #pragma unroll
    for (int i = 0; i < 2; ++i) {
      int c = i * NT + tid;
      int row = c >> 3, kc = c & 7;
      int sw = (kc ^ (row & 7)) << 3;
      const bf16* src = (k0 < 2048)
          ? Abel + (size_t)(m0 + row) * 2048 + k0 + sw
          : Aobs + (size_t)(m0 + row) * 1024 + (k0 - 2048) + sw;
      gload_lds16(src, &dA[c * 8]);
    }
    #pragma unroll
    for (int i = 0; i < 2; ++i) {
      int c = i * NT + tid;
      int row = c >> 3, kc = c & 7;
      gload_lds16(B + (size_t)(n0 + row) * K + k0 + ((kc ^ (row & 7)) << 3), &dB[c * 8]);
    }
  };

  f32x4 acc[2][4] = {};
  __syncthreads();
  stage(0, 0); stage(1, 64); stage(2, 128);
  int cur = 0;
  for (int it = 0; it < NK; ++it) {
    if (it + 2 < NK)      { asm volatile("s_waitcnt vmcnt(8)" ::: "memory"); }
    else if (it + 1 < NK) { asm volatile("s_waitcnt vmcnt(4)" ::: "memory"); }
    else                  { asm volatile("s_waitcnt vmcnt(0)" ::: "memory"); }
    __builtin_amdgcn_sched_barrier(0);
    __builtin_amdgcn_s_barrier();
    __builtin_amdgcn_sched_barrier(0);
    const bf16* cA = sAb + cur * (128 * 64);
    const bf16* cB = sBb + cur * (128 * 64);
    #pragma unroll
    for (int kk = 0; kk < 2; ++kk) {
      const int jg = kk * 4 + lg;
      bf16x8v af[2], bfv[4];
      #pragma unroll
      for (int m = 0; m < 2; ++m) {
        int ar = wm * 32 + m * 16 + lr;
        af[m] = *(const bf16x8v*)&cA[ar * 64 + ((jg ^ (ar & 7)) << 3)];
      }
      #pragma unroll
      for (int n = 0; n < 4; ++n) {
        int br = wn * 64 + n * 16 + lr;
        bfv[n] = *(const bf16x8v*)&cB[br * 64 + ((jg ^ (br & 7)) << 3)];
      }
      #pragma unroll
      for (int m = 0; m < 2; ++m)
        #pragma unroll
        for (int n = 0; n < 4; ++n)
          acc[m][n] = __builtin_amdgcn_mfma_f32_16x16x32_bf16(af[m], bfv[n], acc[m][n], 0, 0, 0);
    }
    __builtin_amdgcn_sched_barrier(0);
    __builtin_amdgcn_s_barrier();
    __builtin_amdgcn_sched_barrier(0);
    if (it + 3 < NK) stage(cur, (it + 3) << 6);
    cur = (cur + 1 == 3) ? 0 : cur + 1;
  }

  const int r0 = (lane >> 4) * 4;
  #pragma unroll
  for (int n = 0; n < 4; ++n) {
    int gcn = n0 + wn * 64 + n * 16 + lr;
    float bv = bias[gcn];
    #pragma unroll
    for (int m = 0; m < 2; ++m)
      #pragma unroll
      for (int r = 0; r < 4; ++r) {
        int gr = m0 + wm * 32 + m * 16 + r0 + r;
        float v = acc[m][n][r] + bv;
        C[(size_t)gr * 2048 + gcn] = __float2bfloat16(v > 0.f ? v : 0.f);
      }
  }
}

// ---------------------------------------------------------------------------
// fused W2p GEMM (512x512, K=2048) + posterior epilogue (proven R9 code)
// ---------------------------------------------------------------------------
__device__ void w2p_tile(const bf16* __restrict__ hq, const bf16* __restrict__ W2pT,
                         const float* __restrict__ b2p, const float* __restrict__ eps,
                         float* __restrict__ o_mu, float* __restrict__ o_sd,
                         float* __restrict__ o_st,
                         const float* __restrict__ nt_next,
                         const float* __restrict__ act_next,
                         bf16* __restrict__ xcat, int make_xcat,
                         int blk, int tid, char* pool)
{
  constexpr int K = 2048, NK = K / 64;
  const int mb = blk & 7, nl = blk >> 3;
  const int m0 = mb * 64;
  const int j0 = nl * 32;

  bf16 (*sA)[64 * 64] = (bf16(*)[64 * 64])pool;
  bf16 (*sB)[64 * 64] = (bf16(*)[64 * 64])(pool + 16384);
  float* tile = (float*)pool;

  const int lane = tid & 63;
  const int wid = tid >> 6;
  const int wm = wid >> 1, wn = wid & 1;
  const int lr = lane & 15;
  const int lg = lane >> 4;

  const bf16* Abase = hq + (size_t)m0 * K;

  auto stage = [&](int buf, int k0) {
    {
      int c = tid;
      int row = c >> 3, kc = c & 7;
      gload_lds16(Abase + (size_t)row * K + k0 + ((kc ^ (row & 7)) << 3), &sA[buf][c * 8]);
    }
    {
      int c = tid;
      int row = c >> 3, kc = c & 7;
      int grow = (row < 32) ? (j0 + row) : (224 + j0 + row);
      gload_lds16(W2pT + (size_t)grow * K + k0 + ((kc ^ (row & 7)) << 3), &sB[buf][c * 8]);
    }
  };

  f32x4 acc[2] = {};
  __syncthreads();
  stage(0, 0);
  stage(1, 64);
  for (int it = 0; it < NK; ++it) {
    const int cur = it & 1;
    if (it + 1 < NK) { asm volatile("s_waitcnt vmcnt(2)" ::: "memory"); }
    else             { asm volatile("s_waitcnt vmcnt(0)" ::: "memory"); }
    __builtin_amdgcn_sched_barrier(0);
    __builtin_amdgcn_s_barrier();
    __builtin_amdgcn_sched_barrier(0);
    #pragma unroll
    for (int kk = 0; kk < 2; ++kk) {
      const int jg = kk * 4 + lg;
      int ar = wm * 16 + lr;
      bf16x8v af = *(const bf16x8v*)&sA[cur][ar * 64 + ((jg ^ (ar & 7)) << 3)];
      #pragma unroll
      for (int n = 0; n < 2; ++n) {
        int br = wn * 32 + n * 16 + lr;
        bf16x8v bfv = *(const bf16x8v*)&sB[cur][br * 64 + ((jg ^ (br & 7)) << 3)];
        acc[n] = __builtin_amdgcn_mfma_f32_16x16x32_bf16(af, bfv, acc[n], 0, 0, 0);
      }
    }
    __builtin_amdgcn_sched_barrier(0);
    __builtin_amdgcn_s_barrier();
    __builtin_amdgcn_sched_barrier(0);
    if (it + 2 < NK) stage(cur, (it + 2) << 6);
  }

  const int r0 = (lane >> 4) * 4;
  #pragma unroll
  for (int n = 0; n < 2; ++n) {
    int tc = wn * 32 + n * 16 + lr;
    #pragma unroll
    for (int r = 0; r < 4; ++r)
      tile[(wm * 16 + r0 + r) * 64 + tc] = acc[n][r];
  }
  __syncthreads();

  for (int e = tid; e < 64 * 32; e += NT) {
    int rr = e >> 5, cc = e & 31;
    int b = m0 + rr;
    int j = j0 + cc;
    float loc = tile[rr * 64 + cc] + b2p[j];
    float raw = tile[rr * 64 + 32 + cc] + b2p[256 + j];
    float sp = (raw > 20.f) ? raw : log1pf(__expf(raw));
    float scale = sp + 0.1f;
    float st = loc + scale * eps[(size_t)b * 256 + j];
    o_mu[(size_t)b * 256 + j] = loc;
    o_sd[(size_t)b * 256 + j] = scale;
    o_st[(size_t)b * 256 + j] = st;
    if (make_xcat)
      xcat[(size_t)b * 320 + j] = __float2bfloat16(st * nt_next[b]);
  }
  if (make_xcat && nl == 0) {
    for (int e = tid; e < 64 * 64; e += NT) {
      int rr = e >> 6, cc = e & 63;
      int b = m0 + rr;
      xcat[(size_t)b * 320 + 256 + cc] = __float2bfloat16(act_next[(size_t)b * 64 + cc]);
    }
  }
}

// ---------------------------------------------------------------------------
__device__ void transpose_phase(const float* __restrict__ src, bf16* __restrict__ dst,
                                int K, int N, int bid, int tid, float* t /*32x33*/)
{
  const int ntile = (K / 32) * (N / 32);
  const int tx = tid & 31, ty = tid >> 5;   // 32 x 16
  for (int it = bid; it < ntile; it += NB) {
    int kt = it % (K / 32), nt = it / (K / 32);
    int k0 = kt * 32, n0 = nt * 32;
    __syncthreads();
    #pragma unroll
    for (int i = 0; i < 32; i += 16)
      t[(ty + i) * 33 + tx] = src[(size_t)(k0 + ty + i) * N + n0 + tx];
    __syncthreads();
    #pragma unroll
    for (int i = 0; i < 32; i += 16)
      dst[(size_t)(n0 + ty + i) * K + k0 + tx] = __float2bfloat16(t[tx * 33 + ty + i]);
  }
}

struct Args {
  const float *prev_state, *actions, *prev_belief, *obs_emb, *nonterm;
  const float *W_embed, *b_embed, *Wi, *bi, *Wh, *bh;
  const float *W1, *b1, *W2, *b2, *W1p, *b1p, *W2p, *b2p;
  const float *eps_p, *eps_q;
  bf16 *WembT, *WiT, *WhT, *W1T, *W2T, *W1pT, *W2pT;
  float* belief_f32; bf16 *bel_init, *xcat, *hidden, *obsB;
  bf16 *hq, *belA, *hp; float* yp;
  float* out;
  unsigned* cnt;
};

// ---------------------------------------------------------------------------
__global__ __launch_bounds__(NT, 2) void mega(Args a)
{
  extern __shared__ char pool[];        // 128 KB
  const int bid = blockIdx.x;
  const int tid = threadIdx.x;
  unsigned ep = 0;

  // ---- P0: weight transposes + init + obs bf16 precompute ----
  transpose_phase(a.W_embed, a.WembT, 320, 2048, bid, tid, (float*)pool);
  transpose_phase(a.Wi,  a.WiT,  2048, 6144, bid, tid, (float*)pool);
  transpose_phase(a.Wh,  a.WhT,  2048, 6144, bid, tid, (float*)pool);
  transpose_phase(a.W1,  a.W1T,  2048, 2048, bid, tid, (float*)pool);
  transpose_phase(a.W2,  a.W2T,  2048, 512,  bid, tid, (float*)pool);
  transpose_phase(a.W1p, a.W1pT, 3072, 2048, bid, tid, (float*)pool);
  transpose_phase(a.W2p, a.W2pT, 2048, 512,  bid, tid, (float*)pool);
  for (int i = bid * NT + tid; i < 512 * 2048; i += NB * NT) {
    float v = a.prev_belief[i];
    a.belief_f32[i] = v;
    a.bel_init[i] = __float2bfloat16(v);
  }
  for (int i = bid * NT + tid; i < 512 * 320; i += NB * NT) {
    int b = i / 320, c = i - b * 320;
    float v = (c < 256) ? a.prev_state[b * 256 + c] * a.nonterm[b]
                        : a.actions[b * 64 + (c - 256)];
    a.xcat[i] = __float2bfloat16(v);
  }
  for (int i = bid * NT + tid; i < TM1 * 512 * 1024 / 4; i += NB * NT) {
    float4 v = *(const float4*)&a.obs_emb[(size_t)i * 4];
    ushort4 u; u.x = bfb(v.x); u.y = bfb(v.y); u.z = bfb(v.z); u.w = bfb(v.w);
    *(ushort4*)&a.obsB[(size_t)i * 4] = u;
  }
  gbar(a.cnt, ++ep, bid);

  // ---- hidden_0 = relu(xcat @ WembT + b_embed), 64 jobs 128x128 ----
  {
    int j = jid(bid, 64);
    if (j >= 0)
      gemm_tile<128, 128, 2>(a.xcat, a.WembT, a.b_embed, a.hidden, 2048, 320, 4, 1, j, tid, pool);
  }
  gbar(a.cnt, ++ep, bid);

  for (int t = 0; t < TM1; ++t) {
    // ---- fused GRU, 64 jobs 128x128x3 ----
    const bf16* belsrc = (t == 0) ? a.bel_init : a.belA + (size_t)(t - 1) * 512 * 2048;
    {
      int j = jid(bid, 64);
      if (j >= 0)
        fused_gru(a.hidden, belsrc, a.WiT, a.WhT, a.bi, a.bh,
                  a.belief_f32,
                  a.out + OUT_BEL + (size_t)t * 512 * 2048,
                  a.belA + (size_t)t * 512 * 2048,
                  j, tid, pool);
    }
    gbar(a.cnt, ++ep, bid);

    // ---- W1p, 64 jobs 128x128, depth-3 ----
    {
      int j = jid(bid, 64);
      if (j >= 0)
        gemm_w1p(a.belA + (size_t)t * 512 * 2048,
                 a.obsB + (size_t)t * 512 * 1024,
                 a.W1pT, a.b1p, a.hq, j, tid, pool);
    }
    gbar(a.cnt, ++ep, bid);

    // ---- fused W2p + posterior sample + next xcat ----
    {
      int tn = (t < TM1 - 1) ? t + 1 : t;
      if (bid < 64)
        w2p_tile(a.hq, a.W2pT, a.b2p,
                 a.eps_q + (size_t)t * 512 * 256,
                 a.out + OUT_QMU + (size_t)t * 512 * 256,
                 a.out + OUT_QSD + (size_t)t * 512 * 256,
                 a.out + OUT_QST + (size_t)t * 512 * 256,
                 a.nonterm + (size_t)tn * 512,
                 a.actions + (size_t)tn * 512 * 64,
                 a.xcat, (t < TM1 - 1) ? 1 : 0, bid, tid, pool);
    }
    gbar(a.cnt, ++ep, bid);

    // ---- embed: hidden_{t+1}, 64 jobs 128x128 ----
    if (t < TM1 - 1) {
      int j = jid(bid, 64);
      if (j >= 0)
        gemm_tile<128, 128, 2>(a.xcat, a.WembT, a.b_embed, a.hidden, 2048, 320, 4, 1, j, tid, pool);
      gbar(a.cnt, ++ep, bid);
    }
  }

  // ---- batched prior: 8 chunks of 4096 rows, 256x256 tiles ----
  for (int ch = 0; ch < 8; ++ch) {
    const bf16* Ach = a.belA + (size_t)ch * 4096 * 2048;
    {
      int j = jid(bid, 128);
      if (j >= 0)
        gemm_tile<256, 256, 2>(Ach, a.W1T, a.b1, a.hp, 2048, 2048, 16, 1, j, tid, pool);
    }
    gbar(a.cnt, ++ep, bid);

    {
      int j = jid(bid, 32);
      if (j >= 0)
        gemm_tile<256, 256, 2>(a.hp, a.W2T, a.b2, a.yp, 512, 2048, 16, 0, j, tid, pool);
    }
    gbar(a.cnt, ++ep, bid);

    for (int i = bid * NT + tid; i < 4096 * 256; i += NB * NT) {
      int r = i >> 8, j = i & 255;
      float loc = a.yp[(size_t)r * 512 + j];
      float raw = a.yp[(size_t)r * 512 + 256 + j];
      float sp = (raw > 20.f) ? raw : log1pf(__expf(raw));
      float scale = sp + 0.1f;
      size_t o = (size_t)ch * 4096 * 256 + i;
      a.out[OUT_PMU + o] = loc;
      a.out[OUT_PSD + o] = scale;
      a.out[OUT_PST + o] = loc + scale * a.eps_p[o];
    }
    gbar(a.cnt, ++ep, bid);
  }
}

// ---------------------------------------------------------------------------
extern "C" void kernel_launch(void* const* d_in, const int* in_sizes, int n_in,
                              void* d_out, int out_size, void* d_ws, size_t ws_size,
                              hipStream_t stream)
{
  (void)in_sizes; (void)n_in; (void)out_size; (void)ws_size;
  Args a;
  a.prev_state = (const float*)d_in[0];
  a.actions    = (const float*)d_in[1];
  a.prev_belief= (const float*)d_in[2];
  a.obs_emb    = (const float*)d_in[3];
  a.nonterm    = (const float*)d_in[4];
  a.W_embed    = (const float*)d_in[5];
  a.b_embed    = (const float*)d_in[6];
  a.Wi         = (const float*)d_in[7];
  a.bi         = (const float*)d_in[8];
  a.Wh         = (const float*)d_in[9];
  a.bh         = (const float*)d_in[10];
  a.W1         = (const float*)d_in[11];
  a.b1         = (const float*)d_in[12];
  a.W2         = (const float*)d_in[13];
  a.b2         = (const float*)d_in[14];
  a.W1p        = (const float*)d_in[15];
  a.b1p        = (const float*)d_in[16];
  a.W2p        = (const float*)d_in[17];
  a.b2p        = (const float*)d_in[18];
  a.eps_p      = (const float*)d_in[19];
  a.eps_q      = (const float*)d_in[20];
  a.out        = (float*)d_out;

  char* ws = (char*)d_ws;
  size_t off = 0;
  auto alloc = [&](size_t bytes) -> char* {
    char* p = ws + off;
    off = (off + bytes + 255) & ~(size_t)255;
    return p;
  };
  a.cnt        = (unsigned*)alloc(4096);
  a.WembT      = (bf16*)alloc((size_t)2048 * 320 * 2);
  a.WiT        = (bf16*)alloc((size_t)6144 * 2048 * 2);
  a.WhT        = (bf16*)alloc((size_t)6144 * 2048 * 2);
  a.W1T        = (bf16*)alloc((size_t)2048 * 2048 * 2);
  a.W2T        = (bf16*)alloc((size_t)512 * 2048 * 2);
  a.W1pT       = (bf16*)alloc((size_t)2048 * 3072 * 2);
  a.W2pT       = (bf16*)alloc((size_t)512 * 2048 * 2);
  a.belief_f32 = (float*)alloc((size_t)512 * 2048 * 4);
  a.bel_init   = (bf16*)alloc((size_t)512 * 2048 * 2);
  a.xcat       = (bf16*)alloc((size_t)512 * 320 * 2);
  a.hidden     = (bf16*)alloc((size_t)512 * 2048 * 2);
  a.obsB       = (bf16*)alloc((size_t)TM1 * 512 * 1024 * 2);   // 67 MB
  a.hq         = (bf16*)alloc((size_t)512 * 2048 * 2);
  a.belA       = (bf16*)alloc((size_t)TM1 * 512 * 2048 * 2);   // 128 MB
  a.hp         = (bf16*)alloc((size_t)4096 * 2048 * 2);
  a.yp         = (float*)alloc((size_t)4096 * 512 * 4);

  hipFuncSetAttribute((const void*)mega,
                      hipFuncAttributeMaxDynamicSharedMemorySize, 131072);
  hipMemsetAsync(a.cnt, 0, 4096, stream);
  mega<<<NB, NT, 131072, stream>>>(a);
}

// Round 12
// 10237.474 us; speedup vs baseline: 1.7729x; 1.7729x over previous
//
#include <hip/hip_runtime.h>
#include <hip/hip_bf16.h>
#include <cstdint>

typedef __hip_bfloat16 bf16;
typedef __attribute__((ext_vector_type(8))) short bf16x8v;   // 8 bf16 in 4 VGPRs
typedef __attribute__((ext_vector_type(4))) float f32x4;

#define NB 256          // persistent blocks (1 per CU)
#define NT 512          // 8 waves (2 per SIMD)
#define TM1 64

// output offsets (elements) in d_out, per reference return order
#define OUT_BEL  ((size_t)0)
#define OUT_PST  ((size_t)67108864)
#define OUT_PMU  ((size_t)75497472)
#define OUT_PSD  ((size_t)83886080)
#define OUT_QST  ((size_t)92274688)
#define OUT_QMU  ((size_t)100663296)
#define OUT_QSD  ((size_t)109051904)

__device__ __forceinline__ void gload_lds16(const bf16* g, bf16* l) {
  __builtin_amdgcn_global_load_lds(
      (const __attribute__((address_space(1))) unsigned int*)g,
      (__attribute__((address_space(3))) unsigned int*)l, 16, 0, 0);
}

__device__ __forceinline__ unsigned short bfb(float f) {
  bf16 h = __float2bfloat16(f);
  return *reinterpret_cast<unsigned short*>(&h);
}

__device__ __forceinline__ float sigmoidf_(float x) { return 1.f / (1.f + __expf(-x)); }

// XCD-spread job id for nj<=256 jobs over NB blocks (nj multiple of 8)
__device__ __forceinline__ int jid(int bid, int nj) {
  return (bid < nj) ? ((bid & 7) * (nj >> 3) + (bid >> 3)) : -1;
}

// ---------------------------------------------------------------------------
// hierarchical device-scope grid barrier (epoch-monotone, memset-zeroed)
// ---------------------------------------------------------------------------
__device__ __forceinline__ void gbar(unsigned* bars, unsigned e, int bid) {
  __syncthreads();
  const int g = bid & 7;
  const int tid = threadIdx.x;
  if (tid == 0) {
    __threadfence();   // release
    __hip_atomic_fetch_add(&bars[16 * g], 1u, __ATOMIC_RELAXED, __HIP_MEMORY_SCOPE_AGENT);
  }
  if (bid == 0) {
    if (tid < 8) {
      while (__hip_atomic_load(&bars[16 * tid], __ATOMIC_RELAXED, __HIP_MEMORY_SCOPE_AGENT) < 32u * e)
        __builtin_amdgcn_s_sleep(1);
    }
    __syncthreads();
    if (tid < 8)
      __hip_atomic_store(&bars[128 + 16 * tid], e, __ATOMIC_RELAXED, __HIP_MEMORY_SCOPE_AGENT);
  } else if (tid == 0) {
    while (__hip_atomic_load(&bars[128 + 16 * g], __ATOMIC_RELAXED, __HIP_MEMORY_SCOPE_AGENT) < e)
      __builtin_amdgcn_s_sleep(2);
  }
  if (tid == 0) __threadfence();   // acquire
  __syncthreads();
}

// ---------------------------------------------------------------------------
// generic GEMM tile: counted-vmcnt depth-DEPTH pipeline.  acc <= 32 VGPRs for
// all instantiations used (BM<=128, BN<=128: MR=2, NR=4).
// ---------------------------------------------------------------------------
template<int BM, int BN, int DEPTH>
__device__ void gemm_tile(const bf16* __restrict__ A, const bf16* __restrict__ B,
                          const float* __restrict__ bias, void* __restrict__ C,
                          int N, int K, int nm, int mode, int job, int tid,
                          char* pool)
{
  constexpr int LA = BM * 8 / NT;
  constexpr int LB = BN * 8 / NT;
  constexpr int L = LA + LB;
  constexpr int WMt = BM / 4, WNt = BN / 2;
  constexpr int MR = WMt / 16, NR = WNt / 16;
  bf16* sAb = (bf16*)pool;
  bf16* sBb = (bf16*)(pool + (size_t)DEPTH * BM * 64 * 2);

  const int m0 = (job % nm) * BM;
  const int n0 = (job / nm) * BN;
  const int lane = tid & 63;
  const int wid = tid >> 6;
  const int wm = wid >> 1, wn = wid & 1;
  const int lr = lane & 15;
  const int lg = lane >> 4;

  const bf16* Abase = A + (size_t)m0 * K;
  const bf16* Bbase = B + (size_t)n0 * K;

  auto stage = [&](int buf, int k0) {
    bf16* dA = sAb + buf * (BM * 64);
    bf16* dB = sBb + buf * (BN * 64);
    #pragma unroll
    for (int i = 0; i < LA; ++i) {
      int c = i * NT + tid;
      int row = c >> 3, kc = c & 7;
      gload_lds16(Abase + (size_t)row * K + k0 + ((kc ^ (row & 7)) << 3), &dA[c * 8]);
    }
    #pragma unroll
    for (int i = 0; i < LB; ++i) {
      int c = i * NT + tid;
      int row = c >> 3, kc = c & 7;
      gload_lds16(Bbase + (size_t)row * K + k0 + ((kc ^ (row & 7)) << 3), &dB[c * 8]);
    }
  };

  f32x4 acc[MR][NR] = {};
  __syncthreads();                 // pool handoff
  const int nk = K >> 6;
  #pragma unroll
  for (int d = 0; d < DEPTH; ++d)
    if (d < nk) stage(d, d << 6);
  int cur = 0;
  for (int it = 0; it < nk; ++it) {
    if (DEPTH == 3) {
      if (it + 2 < nk)      { asm volatile("s_waitcnt vmcnt(%0)" :: "n"(2 * L) : "memory"); }
      else if (it + 1 < nk) { asm volatile("s_waitcnt vmcnt(%0)" :: "n"(L) : "memory"); }
      else                  { asm volatile("s_waitcnt vmcnt(0)" ::: "memory"); }
    } else {
      if (it + 1 < nk)      { asm volatile("s_waitcnt vmcnt(%0)" :: "n"(L) : "memory"); }
      else                  { asm volatile("s_waitcnt vmcnt(0)" ::: "memory"); }
    }
    __builtin_amdgcn_sched_barrier(0);
    __builtin_amdgcn_s_barrier();
    __builtin_amdgcn_sched_barrier(0);
    const bf16* cA = sAb + cur * (BM * 64);
    const bf16* cB = sBb + cur * (BN * 64);
    #pragma unroll
    for (int kk = 0; kk < 2; ++kk) {
      const int jg = kk * 4 + lg;
      bf16x8v af[MR], bfv[NR];
      #pragma unroll
      for (int m = 0; m < MR; ++m) {
        int ar = wm * WMt + m * 16 + lr;
        af[m] = *(const bf16x8v*)&cA[ar * 64 + ((jg ^ (ar & 7)) << 3)];
      }
      #pragma unroll
      for (int n = 0; n < NR; ++n) {
        int br = wn * WNt + n * 16 + lr;
        bfv[n] = *(const bf16x8v*)&cB[br * 64 + ((jg ^ (br & 7)) << 3)];
      }
      #pragma unroll
      for (int m = 0; m < MR; ++m)
        #pragma unroll
        for (int n = 0; n < NR; ++n)
          acc[m][n] = __builtin_amdgcn_mfma_f32_16x16x32_bf16(af[m], bfv[n], acc[m][n], 0, 0, 0);
    }
    __builtin_amdgcn_sched_barrier(0);
    __builtin_amdgcn_s_barrier();
    __builtin_amdgcn_sched_barrier(0);
    if (it + DEPTH < nk) stage(cur, (it + DEPTH) << 6);
    cur = (cur + 1 == DEPTH) ? 0 : cur + 1;
  }

  const int r0 = (lane >> 4) * 4;
  #pragma unroll
  for (int m = 0; m < MR; ++m) {
    #pragma unroll
    for (int n = 0; n < NR; ++n) {
      int gc = n0 + wn * WNt + n * 16 + lr;
      float bv = bias[gc];
      #pragma unroll
      for (int r = 0; r < 4; ++r) {
        int gr = m0 + wm * WMt + m * 16 + r0 + r;
        float v = acc[m][n][r] + bv;
        if (mode == 1)
          ((bf16*)C)[(size_t)gr * N + gc] = __float2bfloat16(v > 0.f ? v : 0.f);
        else
          ((float*)C)[(size_t)gr * N + gc] = v;
      }
    }
  }
}

// ---------------------------------------------------------------------------
// FUSED GRU (R9-proven 64x64 shape, acc = 32 VGPRs): 256 jobs of
// (64 rows x 64 gate-cols x 3 gates). LDS 2x8KB + 2x24KB = 64KB. L=4, depth-2.
// ---------------------------------------------------------------------------
__device__ void fused_gru(const bf16* __restrict__ hidden, const bf16* __restrict__ belsrc,
                          const bf16* __restrict__ WiT, const bf16* __restrict__ WhT,
                          const float* __restrict__ bi, const float* __restrict__ bh,
                          float* __restrict__ belief_f32, float* __restrict__ out_bel,
                          bf16* __restrict__ belslot,
                          int job, int tid, char* pool)
{
  bf16 (*sA)[64 * 64]  = (bf16(*)[64 * 64])pool;              // 2 x 8KB
  bf16 (*sB)[192 * 64] = (bf16(*)[192 * 64])(pool + 16384);   // 2 x 24KB

  const int m0 = (job & 7) * 64;
  const int j0 = (job >> 3) * 64;
  const int lane = tid & 63;
  const int wid = tid >> 6;
  const int wm = wid >> 2, wn = wid & 3;   // 2 m x 4 n; WMt=32, WNt=16
  const int lr = lane & 15;
  const int lg = lane >> 4;

  auto stage = [&](int buf, int gt) {
    const bf16* Ab; const bf16* Bb; int k0;
    if (gt < 32) { Ab = hidden; Bb = WiT; k0 = gt << 6; }
    else         { Ab = belsrc; Bb = WhT; k0 = (gt - 32) << 6; }
    {
      int c = tid;                       // A: 64 rows x 8 chunks = 512
      int row = c >> 3, kc = c & 7;
      gload_lds16(Ab + (size_t)(m0 + row) * 2048 + k0 + ((kc ^ (row & 7)) << 3),
                  &sA[buf][c * 8]);
    }
    #pragma unroll
    for (int i = 0; i < 3; ++i) {        // B: 192 rows (3 gates x 64)
      int c = i * NT + tid;
      int r = c >> 3, kc = c & 7;
      int grow = (r >> 6) * 2048 + j0 + (r & 63);
      gload_lds16(Bb + (size_t)grow * 2048 + k0 + ((kc ^ (r & 7)) << 3),
                  &sB[buf][c * 8]);
    }
  };

  f32x4 ar_[2] = {}, az_[2] = {}, ain[2] = {}, ahn[2] = {};

  auto body = [&](int gt, f32x4 (&ax)[2]) {
    const int cur = gt & 1;
    if (gt < 63) { asm volatile("s_waitcnt vmcnt(4)" ::: "memory"); }
    else         { asm volatile("s_waitcnt vmcnt(0)" ::: "memory"); }
    __builtin_amdgcn_sched_barrier(0);
    __builtin_amdgcn_s_barrier();
    __builtin_amdgcn_sched_barrier(0);
    #pragma unroll
    for (int kk = 0; kk < 2; ++kk) {
      const int jg = kk * 4 + lg;
      bf16x8v af[2], bg[3];
      #pragma unroll
      for (int m = 0; m < 2; ++m) {
        int arow = wm * 32 + m * 16 + lr;
        af[m] = *(const bf16x8v*)&sA[cur][arow * 64 + ((jg ^ (arow & 7)) << 3)];
      }
      #pragma unroll
      for (int g = 0; g < 3; ++g) {
        int br = g * 64 + wn * 16 + lr;
        bg[g] = *(const bf16x8v*)&sB[cur][br * 64 + ((jg ^ (br & 7)) << 3)];
      }
      #pragma unroll
      for (int m = 0; m < 2; ++m) {
        ar_[m] = __builtin_amdgcn_mfma_f32_16x16x32_bf16(af[m], bg[0], ar_[m], 0, 0, 0);
        az_[m] = __builtin_amdgcn_mfma_f32_16x16x32_bf16(af[m], bg[1], az_[m], 0, 0, 0);
        ax[m]  = __builtin_amdgcn_mfma_f32_16x16x32_bf16(af[m], bg[2], ax[m], 0, 0, 0);
      }
    }
    __builtin_amdgcn_sched_barrier(0);
    __builtin_amdgcn_s_barrier();
    __builtin_amdgcn_sched_barrier(0);
    if (gt + 2 < 64) stage(cur, gt + 2);
  };

  __syncthreads();                 // pool handoff
  stage(0, 0);
  stage(1, 1);
  for (int gt = 0; gt < 32; ++gt) body(gt, ain);
  for (int gt = 32; gt < 64; ++gt) body(gt, ahn);

  const int gc = j0 + wn * 16 + lr;
  const float br_b  = bi[gc] + bh[gc];
  const float bz_b  = bi[2048 + gc] + bh[2048 + gc];
  const float bin_b = bi[4096 + gc];
  const float bhn_b = bh[4096 + gc];
  const int r0 = (lane >> 4) * 4;
  #pragma unroll
  for (int m = 0; m < 2; ++m) {
    #pragma unroll
    for (int r = 0; r < 4; ++r) {
      int grow = m0 + wm * 32 + m * 16 + r0 + r;
      size_t idx = (size_t)grow * 2048 + gc;
      float rr = sigmoidf_(ar_[m][r] + br_b);
      float zz = sigmoidf_(az_[m][r] + bz_b);
      float nn = tanhf(ain[m][r] + bin_b + rr * (ahn[m][r] + bhn_b));
      float bo = belief_f32[idx];
      float nb = (1.f - zz) * nn + zz * bo;
      belief_f32[idx] = nb;
      out_bel[idx] = nb;
      belslot[idx] = __float2bfloat16(nb);
    }
  }
}

// ---------------------------------------------------------------------------
// W1p GEMM, dual-source A (belA[t] 2048 ++ obsB[t] 1024), K=3072, 64 jobs of
// 128x128, depth-3 (96KB), relu->bf16.  acc = 32 VGPRs.
// ---------------------------------------------------------------------------
__device__ void gemm_w1p(const bf16* __restrict__ Abel, const bf16* __restrict__ Aobs,
                         const bf16* __restrict__ B, const float* __restrict__ bias,
                         bf16* __restrict__ C, int job, int tid, char* pool)
{
  constexpr int K = 3072, NK = 48;
  bf16* sAb = (bf16*)pool;                 // 3 x 16KB
  bf16* sBb = (bf16*)(pool + 49152);       // 3 x 16KB

  const int m0 = (job & 3) * 128;
  const int n0 = (job >> 2) * 128;
  const int lane = tid & 63;
  const int wid = tid >> 6;
  const int wm = wid >> 1, wn = wid & 1;   // WMt=32, WNt=64: MR=2, NR=4
  const int lr = lane & 15;
  const int lg = lane >> 4;

  auto stage = [&](int buf, int k0) {
    bf16* dA = sAb + buf * (128 * 64);
    bf16* dB = sBb + buf * (128 * 64);
    #pragma unroll
    for (int i = 0; i < 2; ++i) {
      int c = i * NT + tid;
      int row = c >> 3, kc = c & 7;
      int sw = (kc ^ (row & 7)) << 3;
      const bf16* src = (k0 < 2048)
          ? Abel + (size_t)(m0 + row) * 2048 + k0 + sw
          : Aobs + (size_t)(m0 + row) * 1024 + (k0 - 2048) + sw;
      gload_lds16(src, &dA[c * 8]);
    }
    #pragma unroll
    for (int i = 0; i < 2; ++i) {
      int c = i * NT + tid;
      int row = c >> 3, kc = c & 7;
      gload_lds16(B + (size_t)(n0 + row) * K + k0 + ((kc ^ (row & 7)) << 3), &dB[c * 8]);
    }
  };

  f32x4 acc[2][4] = {};
  __syncthreads();
  stage(0, 0); stage(1, 64); stage(2, 128);
  int cur = 0;
  for (int it = 0; it < NK; ++it) {
    if (it + 2 < NK)      { asm volatile("s_waitcnt vmcnt(8)" ::: "memory"); }
    else if (it + 1 < NK) { asm volatile("s_waitcnt vmcnt(4)" ::: "memory"); }
    else                  { asm volatile("s_waitcnt vmcnt(0)" ::: "memory"); }
    __builtin_amdgcn_sched_barrier(0);
    __builtin_amdgcn_s_barrier();
    __builtin_amdgcn_sched_barrier(0);
    const bf16* cA = sAb + cur * (128 * 64);
    const bf16* cB = sBb + cur * (128 * 64);
    #pragma unroll
    for (int kk = 0; kk < 2; ++kk) {
      const int jg = kk * 4 + lg;
      bf16x8v af[2], bfv[4];
      #pragma unroll
      for (int m = 0; m < 2; ++m) {
        int ar = wm * 32 + m * 16 + lr;
        af[m] = *(const bf16x8v*)&cA[ar * 64 + ((jg ^ (ar & 7)) << 3)];
      }
      #pragma unroll
      for (int n = 0; n < 4; ++n) {
        int br = wn * 64 + n * 16 + lr;
        bfv[n] = *(const bf16x8v*)&cB[br * 64 + ((jg ^ (br & 7)) << 3)];
      }
      #pragma unroll
      for (int m = 0; m < 2; ++m)
        #pragma unroll
        for (int n = 0; n < 4; ++n)
          acc[m][n] = __builtin_amdgcn_mfma_f32_16x16x32_bf16(af[m], bfv[n], acc[m][n], 0, 0, 0);
    }
    __builtin_amdgcn_sched_barrier(0);
    __builtin_amdgcn_s_barrier();
    __builtin_amdgcn_sched_barrier(0);
    if (it + 3 < NK) stage(cur, (it + 3) << 6);
    cur = (cur + 1 == 3) ? 0 : cur + 1;
  }

  const int r0 = (lane >> 4) * 4;
  #pragma unroll
  for (int n = 0; n < 4; ++n) {
    int gcn = n0 + wn * 64 + n * 16 + lr;
    float bv = bias[gcn];
    #pragma unroll
    for (int m = 0; m < 2; ++m)
      #pragma unroll
      for (int r = 0; r < 4; ++r) {
        int gr = m0 + wm * 32 + m * 16 + r0 + r;
        float v = acc[m][n][r] + bv;
        C[(size_t)gr * 2048 + gcn] = __float2bfloat16(v > 0.f ? v : 0.f);
      }
  }
}

// ---------------------------------------------------------------------------
// fused W2p GEMM (512x512, K=2048) + posterior epilogue (R9-proven)
// ---------------------------------------------------------------------------
__device__ void w2p_tile(const bf16* __restrict__ hq, const bf16* __restrict__ W2pT,
                         const float* __restrict__ b2p, const float* __restrict__ eps,
                         float* __restrict__ o_mu, float* __restrict__ o_sd,
                         float* __restrict__ o_st,
                         const float* __restrict__ nt_next,
                         const float* __restrict__ act_next,
                         bf16* __restrict__ xcat, int make_xcat,
                         int blk, int tid, char* pool)
{
  constexpr int K = 2048, NK = K / 64;
  const int mb = blk & 7, nl = blk >> 3;
  const int m0 = mb * 64;
  const int j0 = nl * 32;

  bf16 (*sA)[64 * 64] = (bf16(*)[64 * 64])pool;
  bf16 (*sB)[64 * 64] = (bf16(*)[64 * 64])(pool + 16384);
  float* tile = (float*)pool;

  const int lane = tid & 63;
  const int wid = tid >> 6;
  const int wm = wid >> 1, wn = wid & 1;
  const int lr = lane & 15;
  const int lg = lane >> 4;

  const bf16* Abase = hq + (size_t)m0 * K;

  auto stage = [&](int buf, int k0) {
    {
      int c = tid;
      int row = c >> 3, kc = c & 7;
      gload_lds16(Abase + (size_t)row * K + k0 + ((kc ^ (row & 7)) << 3), &sA[buf][c * 8]);
    }
    {
      int c = tid;
      int row = c >> 3, kc = c & 7;
      int grow = (row < 32) ? (j0 + row) : (224 + j0 + row);
      gload_lds16(W2pT + (size_t)grow * K + k0 + ((kc ^ (row & 7)) << 3), &sB[buf][c * 8]);
    }
  };

  f32x4 acc[2] = {};
  __syncthreads();
  stage(0, 0);
  stage(1, 64);
  for (int it = 0; it < NK; ++it) {
    const int cur = it & 1;
    if (it + 1 < NK) { asm volatile("s_waitcnt vmcnt(2)" ::: "memory"); }
    else             { asm volatile("s_waitcnt vmcnt(0)" ::: "memory"); }
    __builtin_amdgcn_sched_barrier(0);
    __builtin_amdgcn_s_barrier();
    __builtin_amdgcn_sched_barrier(0);
    #pragma unroll
    for (int kk = 0; kk < 2; ++kk) {
      const int jg = kk * 4 + lg;
      int ar = wm * 16 + lr;
      bf16x8v af = *(const bf16x8v*)&sA[cur][ar * 64 + ((jg ^ (ar & 7)) << 3)];
      #pragma unroll
      for (int n = 0; n < 2; ++n) {
        int br = wn * 32 + n * 16 + lr;
        bf16x8v bfv = *(const bf16x8v*)&sB[cur][br * 64 + ((jg ^ (br & 7)) << 3)];
        acc[n] = __builtin_amdgcn_mfma_f32_16x16x32_bf16(af, bfv, acc[n], 0, 0, 0);
      }
    }
    __builtin_amdgcn_sched_barrier(0);
    __builtin_amdgcn_s_barrier();
    __builtin_amdgcn_sched_barrier(0);
    if (it + 2 < NK) stage(cur, (it + 2) << 6);
  }

  const int r0 = (lane >> 4) * 4;
  #pragma unroll
  for (int n = 0; n < 2; ++n) {
    int tc = wn * 32 + n * 16 + lr;
    #pragma unroll
    for (int r = 0; r < 4; ++r)
      tile[(wm * 16 + r0 + r) * 64 + tc] = acc[n][r];
  }
  __syncthreads();

  for (int e = tid; e < 64 * 32; e += NT) {
    int rr = e >> 5, cc = e & 31;
    int b = m0 + rr;
    int j = j0 + cc;
    float loc = tile[rr * 64 + cc] + b2p[j];
    float raw = tile[rr * 64 + 32 + cc] + b2p[256 + j];
    float sp = (raw > 20.f) ? raw : log1pf(__expf(raw));
    float scale = sp + 0.1f;
    float st = loc + scale * eps[(size_t)b * 256 + j];
    o_mu[(size_t)b * 256 + j] = loc;
    o_sd[(size_t)b * 256 + j] = scale;
    o_st[(size_t)b * 256 + j] = st;
    if (make_xcat)
      xcat[(size_t)b * 320 + j] = __float2bfloat16(st * nt_next[b]);
  }
  if (make_xcat && nl == 0) {
    for (int e = tid; e < 64 * 64; e += NT) {
      int rr = e >> 6, cc = e & 63;
      int b = m0 + rr;
      xcat[(size_t)b * 320 + 256 + cc] = __float2bfloat16(act_next[(size_t)b * 64 + cc]);
    }
  }
}

// ---------------------------------------------------------------------------
__device__ void transpose_phase(const float* __restrict__ src, bf16* __restrict__ dst,
                                int K, int N, int bid, int tid, float* t /*32x33*/)
{
  const int ntile = (K / 32) * (N / 32);
  const int tx = tid & 31, ty = tid >> 5;   // 32 x 16
  for (int it = bid; it < ntile; it += NB) {
    int kt = it % (K / 32), nt = it / (K / 32);
    int k0 = kt * 32, n0 = nt * 32;
    __syncthreads();
    #pragma unroll
    for (int i = 0; i < 32; i += 16)
      t[(ty + i) * 33 + tx] = src[(size_t)(k0 + ty + i) * N + n0 + tx];
    __syncthreads();
    #pragma unroll
    for (int i = 0; i < 32; i += 16)
      dst[(size_t)(n0 + ty + i) * K + k0 + tx] = __float2bfloat16(t[tx * 33 + ty + i]);
  }
}

struct Args {
  const float *prev_state, *actions, *prev_belief, *obs_emb, *nonterm;
  const float *W_embed, *b_embed, *Wi, *bi, *Wh, *bh;
  const float *W1, *b1, *W2, *b2, *W1p, *b1p, *W2p, *b2p;
  const float *eps_p, *eps_q;
  bf16 *WembT, *WiT, *WhT, *W1T, *W2T, *W1pT, *W2pT;
  float* belief_f32; bf16 *bel_init, *xcat, *hidden, *obsB;
  bf16 *hq, *belA, *hp; float* yp;
  float* out;
  unsigned* cnt;
};

// ---------------------------------------------------------------------------
__global__ __launch_bounds__(NT, 2) void mega(Args a)
{
  extern __shared__ char pool[];        // 96 KB
  const int bid = blockIdx.x;
  const int tid = threadIdx.x;
  const int sj = ((bid & 7) << 5) | (bid >> 3);   // XCD-grouped job id (256 jobs)
  unsigned ep = 0;

  // ---- P0: weight transposes + init + obs bf16 precompute ----
  transpose_phase(a.W_embed, a.WembT, 320, 2048, bid, tid, (float*)pool);
  transpose_phase(a.Wi,  a.WiT,  2048, 6144, bid, tid, (float*)pool);
  transpose_phase(a.Wh,  a.WhT,  2048, 6144, bid, tid, (float*)pool);
  transpose_phase(a.W1,  a.W1T,  2048, 2048, bid, tid, (float*)pool);
  transpose_phase(a.W2,  a.W2T,  2048, 512,  bid, tid, (float*)pool);
  transpose_phase(a.W1p, a.W1pT, 3072, 2048, bid, tid, (float*)pool);
  transpose_phase(a.W2p, a.W2pT, 2048, 512,  bid, tid, (float*)pool);
  for (int i = bid * NT + tid; i < 512 * 2048; i += NB * NT) {
    float v = a.prev_belief[i];
    a.belief_f32[i] = v;
    a.bel_init[i] = __float2bfloat16(v);
  }
  for (int i = bid * NT + tid; i < 512 * 320; i += NB * NT) {
    int b = i / 320, c = i - b * 320;
    float v = (c < 256) ? a.prev_state[b * 256 + c] * a.nonterm[b]
                        : a.actions[b * 64 + (c - 256)];
    a.xcat[i] = __float2bfloat16(v);
  }
  for (int i = bid * NT + tid; i < TM1 * 512 * 1024 / 4; i += NB * NT) {
    float4 v = *(const float4*)&a.obs_emb[(size_t)i * 4];
    ushort4 u; u.x = bfb(v.x); u.y = bfb(v.y); u.z = bfb(v.z); u.w = bfb(v.w);
    *(ushort4*)&a.obsB[(size_t)i * 4] = u;
  }
  gbar(a.cnt, ++ep, bid);

  // ---- hidden_0 = relu(xcat @ WembT + b_embed), 256 jobs 64x64 ----
  gemm_tile<64, 64, 2>(a.xcat, a.WembT, a.b_embed, a.hidden, 2048, 320, 8, 1, sj, tid, pool);
  gbar(a.cnt, ++ep, bid);

  for (int t = 0; t < TM1; ++t) {
    // ---- fused GRU, 256 jobs 64x64x3 ----
    const bf16* belsrc = (t == 0) ? a.bel_init : a.belA + (size_t)(t - 1) * 512 * 2048;
    fused_gru(a.hidden, belsrc, a.WiT, a.WhT, a.bi, a.bh,
              a.belief_f32,
              a.out + OUT_BEL + (size_t)t * 512 * 2048,
              a.belA + (size_t)t * 512 * 2048,
              sj, tid, pool);
    gbar(a.cnt, ++ep, bid);

    // ---- W1p, 64 jobs 128x128, depth-3 ----
    {
      int j = jid(bid, 64);
      if (j >= 0)
        gemm_w1p(a.belA + (size_t)t * 512 * 2048,
                 a.obsB + (size_t)t * 512 * 1024,
                 a.W1pT, a.b1p, a.hq, j, tid, pool);
    }
    gbar(a.cnt, ++ep, bid);

    // ---- fused W2p + posterior sample + next xcat ;  prior filler on 64..255 ----
    {
      int tn = (t < TM1 - 1) ? t + 1 : t;
      if (bid < 64) {
        w2p_tile(a.hq, a.W2pT, a.b2p,
                 a.eps_q + (size_t)t * 512 * 256,
                 a.out + OUT_QMU + (size_t)t * 512 * 256,
                 a.out + OUT_QSD + (size_t)t * 512 * 256,
                 a.out + OUT_QST + (size_t)t * 512 * 256,
                 a.nonterm + (size_t)tn * 512,
                 a.actions + (size_t)tn * 512 * 64,
                 a.xcat, (t < TM1 - 1) ? 1 : 0, bid, tid, pool);
      } else if (t >= 8) {
        // folded prior for chunk fc = t/8 - 1 (steps 8fc..8fc+7 complete)
        const int fc = (t >> 3) - 1;
        const int q  = t & 7;
        const int fb = bid - 64;                     // 0..191
        const bf16* Ach = a.belA + (size_t)fc * 4096 * 2048;
        if (q < 2) {                                 // W1 jobs 0..383
          gemm_tile<128, 128, 2>(Ach, a.W1T, a.b1, a.hp, 2048, 2048, 32, 1,
                                 q * 192 + fb, tid, pool);
        } else if (q == 2) {                         // W1 jobs 384..511
          if (fb < 128)
            gemm_tile<128, 128, 2>(Ach, a.W1T, a.b1, a.hp, 2048, 2048, 32, 1,
                                   384 + fb, tid, pool);
        } else if (q == 3) {                         // W2 jobs 0..127
          if (fb < 128)
            gemm_tile<128, 128, 2>(a.hp, a.W2T, a.b2, a.yp, 512, 2048, 32, 0,
                                   fb, tid, pool);
        } else if (q == 4) {                         // prior elementwise
          for (int i = fb * NT + tid; i < 4096 * 256; i += 192 * NT) {
            int r = i >> 8, j = i & 255;
            float loc = a.yp[(size_t)r * 512 + j];
            float raw = a.yp[(size_t)r * 512 + 256 + j];
            float sp = (raw > 20.f) ? raw : log1pf(__expf(raw));
            float scale = sp + 0.1f;
            size_t o = (size_t)fc * 4096 * 256 + i;
            a.out[OUT_PMU + o] = loc;
            a.out[OUT_PSD + o] = scale;
            a.out[OUT_PST + o] = loc + scale * a.eps_p[o];
          }
        }
      }
    }
    gbar(a.cnt, ++ep, bid);

    // ---- embed: hidden_{t+1}, 256 jobs 64x64 ----
    if (t < TM1 - 1) {
      gemm_tile<64, 64, 2>(a.xcat, a.WembT, a.b_embed, a.hidden, 2048, 320, 8, 1, sj, tid, pool);
      gbar(a.cnt, ++ep, bid);
    }
  }

  // ---- tail: prior chunk 7 ----
  {
    const bf16* Ach = a.belA + (size_t)7 * 4096 * 2048;
    gemm_tile<128, 128, 2>(Ach, a.W1T, a.b1, a.hp, 2048, 2048, 32, 1, sj, tid, pool);
    gemm_tile<128, 128, 2>(Ach, a.W1T, a.b1, a.hp, 2048, 2048, 32, 1, sj + 256, tid, pool);
    gbar(a.cnt, ++ep, bid);

    if (sj < 128)
      gemm_tile<128, 128, 2>(a.hp, a.W2T, a.b2, a.yp, 512, 2048, 32, 0, sj, tid, pool);
    gbar(a.cnt, ++ep, bid);

    for (int i = bid * NT + tid; i < 4096 * 256; i += NB * NT) {
      int r = i >> 8, j = i & 255;
      float loc = a.yp[(size_t)r * 512 + j];
      float raw = a.yp[(size_t)r * 512 + 256 + j];
      float sp = (raw > 20.f) ? raw : log1pf(__expf(raw));
      float scale = sp + 0.1f;
      size_t o = (size_t)7 * 4096 * 256 + i;
      a.out[OUT_PMU + o] = loc;
      a.out[OUT_PSD + o] = scale;
      a.out[OUT_PST + o] = loc + scale * a.eps_p[o];
    }
    gbar(a.cnt, ++ep, bid);
  }
}

// ---------------------------------------------------------------------------
extern "C" void kernel_launch(void* const* d_in, const int* in_sizes, int n_in,
                              void* d_out, int out_size, void* d_ws, size_t ws_size,
                              hipStream_t stream)
{
  (void)in_sizes; (void)n_in; (void)out_size; (void)ws_size;
  Args a;
  a.prev_state = (const float*)d_in[0];
  a.actions    = (const float*)d_in[1];
  a.prev_belief= (const float*)d_in[2];
  a.obs_emb    = (const float*)d_in[3];
  a.nonterm    = (const float*)d_in[4];
  a.W_embed    = (const float*)d_in[5];
  a.b_embed    = (const float*)d_in[6];
  a.Wi         = (const float*)d_in[7];
  a.bi         = (const float*)d_in[8];
  a.Wh         = (const float*)d_in[9];
  a.bh         = (const float*)d_in[10];
  a.W1         = (const float*)d_in[11];
  a.b1         = (const float*)d_in[12];
  a.W2         = (const float*)d_in[13];
  a.b2         = (const float*)d_in[14];
  a.W1p        = (const float*)d_in[15];
  a.b1p        = (const float*)d_in[16];
  a.W2p        = (const float*)d_in[17];
  a.b2p        = (const float*)d_in[18];
  a.eps_p      = (const float*)d_in[19];
  a.eps_q      = (const float*)d_in[20];
  a.out        = (float*)d_out;

  char* ws = (char*)d_ws;
  size_t off = 0;
  auto alloc = [&](size_t bytes) -> char* {
    char* p = ws + off;
    off = (off + bytes + 255) & ~(size_t)255;
    return p;
  };
  a.cnt        = (unsigned*)alloc(4096);
  a.WembT      = (bf16*)alloc((size_t)2048 * 320 * 2);
  a.WiT        = (bf16*)alloc((size_t)6144 * 2048 * 2);
  a.WhT        = (bf16*)alloc((size_t)6144 * 2048 * 2);
  a.W1T        = (bf16*)alloc((size_t)2048 * 2048 * 2);
  a.W2T        = (bf16*)alloc((size_t)512 * 2048 * 2);
  a.W1pT       = (bf16*)alloc((size_t)2048 * 3072 * 2);
  a.W2pT       = (bf16*)alloc((size_t)512 * 2048 * 2);
  a.belief_f32 = (float*)alloc((size_t)512 * 2048 * 4);
  a.bel_init   = (bf16*)alloc((size_t)512 * 2048 * 2);
  a.xcat       = (bf16*)alloc((size_t)512 * 320 * 2);
  a.hidden     = (bf16*)alloc((size_t)512 * 2048 * 2);
  a.obsB       = (bf16*)alloc((size_t)TM1 * 512 * 1024 * 2);   // 67 MB
  a.hq         = (bf16*)alloc((size_t)512 * 2048 * 2);
  a.belA       = (bf16*)alloc((size_t)TM1 * 512 * 2048 * 2);   // 128 MB
  a.hp         = (bf16*)alloc((size_t)4096 * 2048 * 2);
  a.yp         = (float*)alloc((size_t)4096 * 512 * 4);

  hipFuncSetAttribute((const void*)mega,
                      hipFuncAttributeMaxDynamicSharedMemorySize, 98304);
  hipMemsetAsync(a.cnt, 0, 4096, stream);
  mega<<<NB, NT, 98304, stream>>>(a);
}

// Round 13
// 8937.132 us; speedup vs baseline: 2.0309x; 1.1455x over previous
//
#include <hip/hip_runtime.h>
#include <hip/hip_bf16.h>
#include <cstdint>

typedef __hip_bfloat16 bf16;
typedef __attribute__((ext_vector_type(8))) short bf16x8v;   // 8 bf16 in 4 VGPRs
typedef __attribute__((ext_vector_type(4))) float f32x4;

#define NB 256          // persistent blocks (1 per CU)
#define NT 512          // 8 waves (2 per SIMD)
#define TM1 64

// output offsets (elements) in d_out, per reference return order
#define OUT_BEL  ((size_t)0)
#define OUT_PST  ((size_t)67108864)
#define OUT_PMU  ((size_t)75497472)
#define OUT_PSD  ((size_t)83886080)
#define OUT_QST  ((size_t)92274688)
#define OUT_QMU  ((size_t)100663296)
#define OUT_QSD  ((size_t)109051904)

__device__ __forceinline__ void gload_lds16(const bf16* g, bf16* l) {
  __builtin_amdgcn_global_load_lds(
      (const __attribute__((address_space(1))) unsigned int*)g,
      (__attribute__((address_space(3))) unsigned int*)l, 16, 0, 0);
}

__device__ __forceinline__ unsigned short bfb(float f) {
  bf16 h = __float2bfloat16(f);
  return *reinterpret_cast<unsigned short*>(&h);
}

__device__ __forceinline__ float sigmoidf_(float x) { return 1.f / (1.f + __expf(-x)); }

// XCD-spread job id for nj<=256 jobs over NB blocks (nj multiple of 8)
__device__ __forceinline__ int jid(int bid, int nj) {
  return (bid < nj) ? ((bid & 7) * (nj >> 3) + (bid >> 3)) : -1;
}

// ---------------------------------------------------------------------------
// hierarchical device-scope grid barrier (epoch-monotone, memset-zeroed)
// ---------------------------------------------------------------------------
__device__ __forceinline__ void gbar(unsigned* bars, unsigned e, int bid) {
  __syncthreads();
  const int g = bid & 7;
  const int tid = threadIdx.x;
  if (tid == 0) {
    __threadfence();   // release
    __hip_atomic_fetch_add(&bars[16 * g], 1u, __ATOMIC_RELAXED, __HIP_MEMORY_SCOPE_AGENT);
  }
  if (bid == 0) {
    if (tid < 8) {
      while (__hip_atomic_load(&bars[16 * tid], __ATOMIC_RELAXED, __HIP_MEMORY_SCOPE_AGENT) < 32u * e)
        __builtin_amdgcn_s_sleep(1);
    }
    __syncthreads();
    if (tid < 8)
      __hip_atomic_store(&bars[128 + 16 * tid], e, __ATOMIC_RELAXED, __HIP_MEMORY_SCOPE_AGENT);
  } else if (tid == 0) {
    while (__hip_atomic_load(&bars[128 + 16 * g], __ATOMIC_RELAXED, __HIP_MEMORY_SCOPE_AGENT) < e)
      __builtin_amdgcn_s_sleep(2);
  }
  if (tid == 0) __threadfence();   // acquire
  __syncthreads();
}

// ---------------------------------------------------------------------------
// generic GEMM tile: counted-vmcnt depth-DEPTH pipeline. acc <= 32 VGPRs.
// ---------------------------------------------------------------------------
template<int BM, int BN, int DEPTH>
__device__ void gemm_tile(const bf16* __restrict__ A, const bf16* __restrict__ B,
                          const float* __restrict__ bias, void* __restrict__ C,
                          int N, int K, int nm, int mode, int job, int tid,
                          char* pool)
{
  constexpr int LA = BM * 8 / NT;
  constexpr int LB = BN * 8 / NT;
  constexpr int L = LA + LB;
  constexpr int WMt = BM / 4, WNt = BN / 2;
  constexpr int MR = WMt / 16, NR = WNt / 16;
  bf16* sAb = (bf16*)pool;
  bf16* sBb = (bf16*)(pool + (size_t)DEPTH * BM * 64 * 2);

  const int m0 = (job % nm) * BM;
  const int n0 = (job / nm) * BN;
  const int lane = tid & 63;
  const int wid = tid >> 6;
  const int wm = wid >> 1, wn = wid & 1;
  const int lr = lane & 15;
  const int lg = lane >> 4;

  const bf16* Abase = A + (size_t)m0 * K;
  const bf16* Bbase = B + (size_t)n0 * K;

  auto stage = [&](int buf, int k0) {
    bf16* dA = sAb + buf * (BM * 64);
    bf16* dB = sBb + buf * (BN * 64);
    #pragma unroll
    for (int i = 0; i < LA; ++i) {
      int c = i * NT + tid;
      int row = c >> 3, kc = c & 7;
      gload_lds16(Abase + (size_t)row * K + k0 + ((kc ^ (row & 7)) << 3), &dA[c * 8]);
    }
    #pragma unroll
    for (int i = 0; i < LB; ++i) {
      int c = i * NT + tid;
      int row = c >> 3, kc = c & 7;
      gload_lds16(Bbase + (size_t)row * K + k0 + ((kc ^ (row & 7)) << 3), &dB[c * 8]);
    }
  };

  f32x4 acc[MR][NR] = {};
  __syncthreads();                 // pool handoff
  const int nk = K >> 6;
  #pragma unroll
  for (int d = 0; d < DEPTH; ++d)
    if (d < nk) stage(d, d << 6);
  int cur = 0;
  for (int it = 0; it < nk; ++it) {
    if (DEPTH == 3) {
      if (it + 2 < nk)      { asm volatile("s_waitcnt vmcnt(%0)" :: "n"(2 * L) : "memory"); }
      else if (it + 1 < nk) { asm volatile("s_waitcnt vmcnt(%0)" :: "n"(L) : "memory"); }
      else                  { asm volatile("s_waitcnt vmcnt(0)" ::: "memory"); }
    } else {
      if (it + 1 < nk)      { asm volatile("s_waitcnt vmcnt(%0)" :: "n"(L) : "memory"); }
      else                  { asm volatile("s_waitcnt vmcnt(0)" ::: "memory"); }
    }
    __builtin_amdgcn_sched_barrier(0);
    __builtin_amdgcn_s_barrier();
    __builtin_amdgcn_sched_barrier(0);
    const bf16* cA = sAb + cur * (BM * 64);
    const bf16* cB = sBb + cur * (BN * 64);
    #pragma unroll
    for (int kk = 0; kk < 2; ++kk) {
      const int jg = kk * 4 + lg;
      bf16x8v af[MR], bfv[NR];
      #pragma unroll
      for (int m = 0; m < MR; ++m) {
        int ar = wm * WMt + m * 16 + lr;
        af[m] = *(const bf16x8v*)&cA[ar * 64 + ((jg ^ (ar & 7)) << 3)];
      }
      #pragma unroll
      for (int n = 0; n < NR; ++n) {
        int br = wn * WNt + n * 16 + lr;
        bfv[n] = *(const bf16x8v*)&cB[br * 64 + ((jg ^ (br & 7)) << 3)];
      }
      #pragma unroll
      for (int m = 0; m < MR; ++m)
        #pragma unroll
        for (int n = 0; n < NR; ++n)
          acc[m][n] = __builtin_amdgcn_mfma_f32_16x16x32_bf16(af[m], bfv[n], acc[m][n], 0, 0, 0);
    }
    __builtin_amdgcn_sched_barrier(0);
    __builtin_amdgcn_s_barrier();
    __builtin_amdgcn_sched_barrier(0);
    if (it + DEPTH < nk) stage(cur, (it + DEPTH) << 6);
    cur = (cur + 1 == DEPTH) ? 0 : cur + 1;
  }

  const int r0 = (lane >> 4) * 4;
  #pragma unroll
  for (int m = 0; m < MR; ++m) {
    #pragma unroll
    for (int n = 0; n < NR; ++n) {
      int gc = n0 + wn * WNt + n * 16 + lr;
      float bv = bias[gc];
      #pragma unroll
      for (int r = 0; r < 4; ++r) {
        int gr = m0 + wm * WMt + m * 16 + r0 + r;
        float v = acc[m][n][r] + bv;
        if (mode == 1)
          ((bf16*)C)[(size_t)gr * N + gc] = __float2bfloat16(v > 0.f ? v : 0.f);
        else
          ((float*)C)[(size_t)gr * N + gc] = v;
      }
    }
  }
}

// ---------------------------------------------------------------------------
// FUSED GRU (R9-proven 64x64 shape, acc = 32 VGPRs), DEPTH-3 pipeline:
// 256 jobs of (64 rows x 64 gate-cols x 3 gates).
// LDS: A 3x8KB [0,24K) + B 3x24KB [24K,96K) = 96KB. L=4 per stage.
// ---------------------------------------------------------------------------
__device__ void fused_gru(const bf16* __restrict__ hidden, const bf16* __restrict__ belsrc,
                          const bf16* __restrict__ WiT, const bf16* __restrict__ WhT,
                          const float* __restrict__ bi, const float* __restrict__ bh,
                          float* __restrict__ belief_f32, float* __restrict__ out_bel,
                          bf16* __restrict__ belslot,
                          int job, int tid, char* pool)
{
  bf16 (*sA)[64 * 64]  = (bf16(*)[64 * 64])pool;              // 3 x 8KB
  bf16 (*sB)[192 * 64] = (bf16(*)[192 * 64])(pool + 24576);   // 3 x 24KB

  const int m0 = (job & 7) * 64;
  const int j0 = (job >> 3) * 64;
  const int lane = tid & 63;
  const int wid = tid >> 6;
  const int wm = wid >> 2, wn = wid & 3;   // 2 m x 4 n; WMt=32, WNt=16
  const int lr = lane & 15;
  const int lg = lane >> 4;

  auto stage = [&](int buf, int gt) {
    const bf16* Ab; const bf16* Bb; int k0;
    if (gt < 32) { Ab = hidden; Bb = WiT; k0 = gt << 6; }
    else         { Ab = belsrc; Bb = WhT; k0 = (gt - 32) << 6; }
    {
      int c = tid;                       // A: 64 rows x 8 chunks = 512
      int row = c >> 3, kc = c & 7;
      gload_lds16(Ab + (size_t)(m0 + row) * 2048 + k0 + ((kc ^ (row & 7)) << 3),
                  &sA[buf][c * 8]);
    }
    #pragma unroll
    for (int i = 0; i < 3; ++i) {        // B: 192 rows (3 gates x 64)
      int c = i * NT + tid;
      int r = c >> 3, kc = c & 7;
      int grow = (r >> 6) * 2048 + j0 + (r & 63);
      gload_lds16(Bb + (size_t)grow * 2048 + k0 + ((kc ^ (r & 7)) << 3),
                  &sB[buf][c * 8]);
    }
  };

  f32x4 ar_[2] = {}, az_[2] = {}, ain[2] = {}, ahn[2] = {};
  int cur = 0;

  auto body = [&](int gt, f32x4 (&ax)[2]) {
    if (gt < 62)      { asm volatile("s_waitcnt vmcnt(8)" ::: "memory"); }
    else if (gt == 62){ asm volatile("s_waitcnt vmcnt(4)" ::: "memory"); }
    else              { asm volatile("s_waitcnt vmcnt(0)" ::: "memory"); }
    __builtin_amdgcn_sched_barrier(0);
    __builtin_amdgcn_s_barrier();
    __builtin_amdgcn_sched_barrier(0);
    #pragma unroll
    for (int kk = 0; kk < 2; ++kk) {
      const int jg = kk * 4 + lg;
      bf16x8v af[2], bg[3];
      #pragma unroll
      for (int m = 0; m < 2; ++m) {
        int arow = wm * 32 + m * 16 + lr;
        af[m] = *(const bf16x8v*)&sA[cur][arow * 64 + ((jg ^ (arow & 7)) << 3)];
      }
      #pragma unroll
      for (int g = 0; g < 3; ++g) {
        int br = g * 64 + wn * 16 + lr;
        bg[g] = *(const bf16x8v*)&sB[cur][br * 64 + ((jg ^ (br & 7)) << 3)];
      }
      #pragma unroll
      for (int m = 0; m < 2; ++m) {
        ar_[m] = __builtin_amdgcn_mfma_f32_16x16x32_bf16(af[m], bg[0], ar_[m], 0, 0, 0);
        az_[m] = __builtin_amdgcn_mfma_f32_16x16x32_bf16(af[m], bg[1], az_[m], 0, 0, 0);
        ax[m]  = __builtin_amdgcn_mfma_f32_16x16x32_bf16(af[m], bg[2], ax[m], 0, 0, 0);
      }
    }
    __builtin_amdgcn_sched_barrier(0);
    __builtin_amdgcn_s_barrier();
    __builtin_amdgcn_sched_barrier(0);
    if (gt + 3 < 64) stage(cur, gt + 3);
    cur = (cur + 1 == 3) ? 0 : cur + 1;
  };

  __syncthreads();                 // pool handoff
  stage(0, 0);
  stage(1, 1);
  stage(2, 2);
  for (int gt = 0; gt < 32; ++gt) body(gt, ain);
  for (int gt = 32; gt < 64; ++gt) body(gt, ahn);

  const int gc = j0 + wn * 16 + lr;
  const float br_b  = bi[gc] + bh[gc];
  const float bz_b  = bi[2048 + gc] + bh[2048 + gc];
  const float bin_b = bi[4096 + gc];
  const float bhn_b = bh[4096 + gc];
  const int r0 = (lane >> 4) * 4;
  #pragma unroll
  for (int m = 0; m < 2; ++m) {
    #pragma unroll
    for (int r = 0; r < 4; ++r) {
      int grow = m0 + wm * 32 + m * 16 + r0 + r;
      size_t idx = (size_t)grow * 2048 + gc;
      float rr = sigmoidf_(ar_[m][r] + br_b);
      float zz = sigmoidf_(az_[m][r] + bz_b);
      float nn = tanhf(ain[m][r] + bin_b + rr * (ahn[m][r] + bhn_b));
      float bo = belief_f32[idx];
      float nb = (1.f - zz) * nn + zz * bo;
      belief_f32[idx] = nb;
      out_bel[idx] = nb;
      belslot[idx] = __float2bfloat16(nb);
    }
  }
}

// ---------------------------------------------------------------------------
// W1p GEMM (R9-proven 64x64 shape), DEPTH-3: dual-source A (belA 2048 ++ obs
// 1024), K=3072, 256 jobs. LDS 3x8KB + 3x8KB = 48KB. L=2.
// ---------------------------------------------------------------------------
__device__ void gemm_w1p(const bf16* __restrict__ Abel, const bf16* __restrict__ Aobs,
                         const bf16* __restrict__ B, const float* __restrict__ bias,
                         bf16* __restrict__ C, int job, int tid, char* pool)
{
  constexpr int K = 3072, NK = 48;
  bf16 (*sA)[64 * 64] = (bf16(*)[64 * 64])pool;               // 3 x 8KB
  bf16 (*sB)[64 * 64] = (bf16(*)[64 * 64])(pool + 24576);     // 3 x 8KB

  const int m0 = (job & 7) * 64;
  const int n0 = (job >> 3) * 64;
  const int lane = tid & 63;
  const int wid = tid >> 6;
  const int wm = wid >> 1, wn = wid & 1;   // 4 x 2; WMt=16, WNt=32
  const int lr = lane & 15;
  const int lg = lane >> 4;

  auto stage = [&](int buf, int k0) {
    {
      int c = tid;
      int row = c >> 3, kc = c & 7;
      int sw = (kc ^ (row & 7)) << 3;
      const bf16* src = (k0 < 2048)
          ? Abel + (size_t)(m0 + row) * 2048 + k0 + sw
          : Aobs + (size_t)(m0 + row) * 1024 + (k0 - 2048) + sw;
      gload_lds16(src, &sA[buf][c * 8]);
    }
    {
      int c = tid;
      int row = c >> 3, kc = c & 7;
      gload_lds16(B + (size_t)(n0 + row) * K + k0 + ((kc ^ (row & 7)) << 3), &sB[buf][c * 8]);
    }
  };

  f32x4 acc[2] = {};
  __syncthreads();
  stage(0, 0); stage(1, 64); stage(2, 128);
  int cur = 0;
  for (int it = 0; it < NK; ++it) {
    if (it + 2 < NK)      { asm volatile("s_waitcnt vmcnt(4)" ::: "memory"); }
    else if (it + 1 < NK) { asm volatile("s_waitcnt vmcnt(2)" ::: "memory"); }
    else                  { asm volatile("s_waitcnt vmcnt(0)" ::: "memory"); }
    __builtin_amdgcn_sched_barrier(0);
    __builtin_amdgcn_s_barrier();
    __builtin_amdgcn_sched_barrier(0);
    #pragma unroll
    for (int kk = 0; kk < 2; ++kk) {
      const int jg = kk * 4 + lg;
      int arow = wm * 16 + lr;
      bf16x8v af = *(const bf16x8v*)&sA[cur][arow * 64 + ((jg ^ (arow & 7)) << 3)];
      #pragma unroll
      for (int n = 0; n < 2; ++n) {
        int br = wn * 32 + n * 16 + lr;
        bf16x8v bv = *(const bf16x8v*)&sB[cur][br * 64 + ((jg ^ (br & 7)) << 3)];
        acc[n] = __builtin_amdgcn_mfma_f32_16x16x32_bf16(af, bv, acc[n], 0, 0, 0);
      }
    }
    __builtin_amdgcn_sched_barrier(0);
    __builtin_amdgcn_s_barrier();
    __builtin_amdgcn_sched_barrier(0);
    if (it + 3 < NK) stage(cur, (it + 3) << 6);
    cur = (cur + 1 == 3) ? 0 : cur + 1;
  }

  const int r0 = (lane >> 4) * 4;
  #pragma unroll
  for (int n = 0; n < 2; ++n) {
    int gcn = n0 + wn * 32 + n * 16 + lr;
    float bv = bias[gcn];
    #pragma unroll
    for (int r = 0; r < 4; ++r) {
      int gr = m0 + wm * 16 + r0 + r;
      float v = acc[n][r] + bv;
      C[(size_t)gr * 2048 + gcn] = __float2bfloat16(v > 0.f ? v : 0.f);
    }
  }
}

// ---------------------------------------------------------------------------
// fused W2p GEMM (512x512, K=2048) + posterior epilogue (R9-proven)
// ---------------------------------------------------------------------------
__device__ void w2p_tile(const bf16* __restrict__ hq, const bf16* __restrict__ W2pT,
                         const float* __restrict__ b2p, const float* __restrict__ eps,
                         float* __restrict__ o_mu, float* __restrict__ o_sd,
                         float* __restrict__ o_st,
                         const float* __restrict__ nt_next,
                         const float* __restrict__ act_next,
                         bf16* __restrict__ xcat, int make_xcat,
                         int blk, int tid, char* pool)
{
  constexpr int K = 2048, NK = K / 64;
  const int mb = blk & 7, nl = blk >> 3;
  const int m0 = mb * 64;
  const int j0 = nl * 32;

  bf16 (*sA)[64 * 64] = (bf16(*)[64 * 64])pool;
  bf16 (*sB)[64 * 64] = (bf16(*)[64 * 64])(pool + 16384);
  float* tile = (float*)pool;

  const int lane = tid & 63;
  const int wid = tid >> 6;
  const int wm = wid >> 1, wn = wid & 1;
  const int lr = lane & 15;
  const int lg = lane >> 4;

  const bf16* Abase = hq + (size_t)m0 * K;

  auto stage = [&](int buf, int k0) {
    {
      int c = tid;
      int row = c >> 3, kc = c & 7;
      gload_lds16(Abase + (size_t)row * K + k0 + ((kc ^ (row & 7)) << 3), &sA[buf][c * 8]);
    }
    {
      int c = tid;
      int row = c >> 3, kc = c & 7;
      int grow = (row < 32) ? (j0 + row) : (224 + j0 + row);
      gload_lds16(W2pT + (size_t)grow * K + k0 + ((kc ^ (row & 7)) << 3), &sB[buf][c * 8]);
    }
  };

  f32x4 acc[2] = {};
  __syncthreads();
  stage(0, 0);
  stage(1, 64);
  for (int it = 0; it < NK; ++it) {
    const int cur = it & 1;
    if (it + 1 < NK) { asm volatile("s_waitcnt vmcnt(2)" ::: "memory"); }
    else             { asm volatile("s_waitcnt vmcnt(0)" ::: "memory"); }
    __builtin_amdgcn_sched_barrier(0);
    __builtin_amdgcn_s_barrier();
    __builtin_amdgcn_sched_barrier(0);
    #pragma unroll
    for (int kk = 0; kk < 2; ++kk) {
      const int jg = kk * 4 + lg;
      int ar = wm * 16 + lr;
      bf16x8v af = *(const bf16x8v*)&sA[cur][ar * 64 + ((jg ^ (ar & 7)) << 3)];
      #pragma unroll
      for (int n = 0; n < 2; ++n) {
        int br = wn * 32 + n * 16 + lr;
        bf16x8v bfv = *(const bf16x8v*)&sB[cur][br * 64 + ((jg ^ (br & 7)) << 3)];
        acc[n] = __builtin_amdgcn_mfma_f32_16x16x32_bf16(af, bfv, acc[n], 0, 0, 0);
      }
    }
    __builtin_amdgcn_sched_barrier(0);
    __builtin_amdgcn_s_barrier();
    __builtin_amdgcn_sched_barrier(0);
    if (it + 2 < NK) stage(cur, (it + 2) << 6);
  }

  const int r0 = (lane >> 4) * 4;
  #pragma unroll
  for (int n = 0; n < 2; ++n) {
    int tc = wn * 32 + n * 16 + lr;
    #pragma unroll
    for (int r = 0; r < 4; ++r)
      tile[(wm * 16 + r0 + r) * 64 + tc] = acc[n][r];
  }
  __syncthreads();

  for (int e = tid; e < 64 * 32; e += NT) {
    int rr = e >> 5, cc = e & 31;
    int b = m0 + rr;
    int j = j0 + cc;
    float loc = tile[rr * 64 + cc] + b2p[j];
    float raw = tile[rr * 64 + 32 + cc] + b2p[256 + j];
    float sp = (raw > 20.f) ? raw : log1pf(__expf(raw));
    float scale = sp + 0.1f;
    float st = loc + scale * eps[(size_t)b * 256 + j];
    o_mu[(size_t)b * 256 + j] = loc;
    o_sd[(size_t)b * 256 + j] = scale;
    o_st[(size_t)b * 256 + j] = st;
    if (make_xcat)
      xcat[(size_t)b * 320 + j] = __float2bfloat16(st * nt_next[b]);
  }
  if (make_xcat && nl == 0) {
    for (int e = tid; e < 64 * 64; e += NT) {
      int rr = e >> 6, cc = e & 63;
      int b = m0 + rr;
      xcat[(size_t)b * 320 + 256 + cc] = __float2bfloat16(act_next[(size_t)b * 64 + cc]);
    }
  }
}

// ---------------------------------------------------------------------------
__device__ void transpose_phase(const float* __restrict__ src, bf16* __restrict__ dst,
                                int K, int N, int bid, int tid, float* t /*32x33*/)
{
  const int ntile = (K / 32) * (N / 32);
  const int tx = tid & 31, ty = tid >> 5;   // 32 x 16
  for (int it = bid; it < ntile; it += NB) {
    int kt = it % (K / 32), nt = it / (K / 32);
    int k0 = kt * 32, n0 = nt * 32;
    __syncthreads();
    #pragma unroll
    for (int i = 0; i < 32; i += 16)
      t[(ty + i) * 33 + tx] = src[(size_t)(k0 + ty + i) * N + n0 + tx];
    __syncthreads();
    #pragma unroll
    for (int i = 0; i < 32; i += 16)
      dst[(size_t)(n0 + ty + i) * K + k0 + tx] = __float2bfloat16(t[tx * 33 + ty + i]);
  }
}

struct Args {
  const float *prev_state, *actions, *prev_belief, *obs_emb, *nonterm;
  const float *W_embed, *b_embed, *Wi, *bi, *Wh, *bh;
  const float *W1, *b1, *W2, *b2, *W1p, *b1p, *W2p, *b2p;
  const float *eps_p, *eps_q;
  bf16 *WembT, *WiT, *WhT, *W1T, *W2T, *W1pT, *W2pT;
  float* belief_f32; bf16 *bel_init, *xcat, *hidden, *obsB;
  bf16 *hq, *belA, *hp; float* yp;
  float* out;
  unsigned* cnt;
};

// ---------------------------------------------------------------------------
__global__ __launch_bounds__(NT, 2) void mega(Args a)
{
  extern __shared__ char pool[];        // 96 KB
  const int bid = blockIdx.x;
  const int tid = threadIdx.x;
  const int sj = ((bid & 7) << 5) | (bid >> 3);   // XCD-grouped job id (256 jobs)
  unsigned ep = 0;

  // ---- P0: weight transposes + init + obs bf16 precompute ----
  transpose_phase(a.W_embed, a.WembT, 320, 2048, bid, tid, (float*)pool);
  transpose_phase(a.Wi,  a.WiT,  2048, 6144, bid, tid, (float*)pool);
  transpose_phase(a.Wh,  a.WhT,  2048, 6144, bid, tid, (float*)pool);
  transpose_phase(a.W1,  a.W1T,  2048, 2048, bid, tid, (float*)pool);
  transpose_phase(a.W2,  a.W2T,  2048, 512,  bid, tid, (float*)pool);
  transpose_phase(a.W1p, a.W1pT, 3072, 2048, bid, tid, (float*)pool);
  transpose_phase(a.W2p, a.W2pT, 2048, 512,  bid, tid, (float*)pool);
  for (int i = bid * NT + tid; i < 512 * 2048; i += NB * NT) {
    float v = a.prev_belief[i];
    a.belief_f32[i] = v;
    a.bel_init[i] = __float2bfloat16(v);
  }
  for (int i = bid * NT + tid; i < 512 * 320; i += NB * NT) {
    int b = i / 320, c = i - b * 320;
    float v = (c < 256) ? a.prev_state[b * 256 + c] * a.nonterm[b]
                        : a.actions[b * 64 + (c - 256)];
    a.xcat[i] = __float2bfloat16(v);
  }
  for (int i = bid * NT + tid; i < TM1 * 512 * 1024 / 4; i += NB * NT) {
    float4 v = *(const float4*)&a.obs_emb[(size_t)i * 4];
    ushort4 u; u.x = bfb(v.x); u.y = bfb(v.y); u.z = bfb(v.z); u.w = bfb(v.w);
    *(ushort4*)&a.obsB[(size_t)i * 4] = u;
  }
  gbar(a.cnt, ++ep, bid);

  // ---- hidden_0 = relu(xcat @ WembT + b_embed), 256 jobs 64x64 ----
  gemm_tile<64, 64, 2>(a.xcat, a.WembT, a.b_embed, a.hidden, 2048, 320, 8, 1, sj, tid, pool);
  gbar(a.cnt, ++ep, bid);

  for (int t = 0; t < TM1; ++t) {
    // ---- fused GRU, 256 jobs 64x64x3, depth-3 ----
    const bf16* belsrc = (t == 0) ? a.bel_init : a.belA + (size_t)(t - 1) * 512 * 2048;
    fused_gru(a.hidden, belsrc, a.WiT, a.WhT, a.bi, a.bh,
              a.belief_f32,
              a.out + OUT_BEL + (size_t)t * 512 * 2048,
              a.belA + (size_t)t * 512 * 2048,
              sj, tid, pool);
    gbar(a.cnt, ++ep, bid);

    // ---- W1p, 256 jobs 64x64, depth-3 ----
    gemm_w1p(a.belA + (size_t)t * 512 * 2048,
             a.obsB + (size_t)t * 512 * 1024,
             a.W1pT, a.b1p, a.hq, sj, tid, pool);
    gbar(a.cnt, ++ep, bid);

    // ---- fused W2p + posterior (blocks 0..63) ; prior filler (64..255) ----
    {
      int tn = (t < TM1 - 1) ? t + 1 : t;
      if (bid < 64) {
        w2p_tile(a.hq, a.W2pT, a.b2p,
                 a.eps_q + (size_t)t * 512 * 256,
                 a.out + OUT_QMU + (size_t)t * 512 * 256,
                 a.out + OUT_QSD + (size_t)t * 512 * 256,
                 a.out + OUT_QST + (size_t)t * 512 * 256,
                 a.nonterm + (size_t)tn * 512,
                 a.actions + (size_t)tn * 512 * 64,
                 a.xcat, (t < TM1 - 1) ? 1 : 0, bid, tid, pool);
      } else if (t >= 8) {
        // folded prior for chunk fc = t/8 - 1
        const int fc = (t >> 3) - 1;
        const int q  = t & 7;
        const int fb = bid - 64;                     // 0..191
        const bf16* Ach = a.belA + (size_t)fc * 4096 * 2048;
        if (q < 2) {
          gemm_tile<128, 128, 2>(Ach, a.W1T, a.b1, a.hp, 2048, 2048, 32, 1,
                                 q * 192 + fb, tid, pool);
        } else if (q == 2) {
          if (fb < 128)
            gemm_tile<128, 128, 2>(Ach, a.W1T, a.b1, a.hp, 2048, 2048, 32, 1,
                                   384 + fb, tid, pool);
        } else if (q == 3) {
          if (fb < 128)
            gemm_tile<128, 128, 2>(a.hp, a.W2T, a.b2, a.yp, 512, 2048, 32, 0,
                                   fb, tid, pool);
        } else if (q == 4) {
          for (int i = fb * NT + tid; i < 4096 * 256; i += 192 * NT) {
            int r = i >> 8, j = i & 255;
            float loc = a.yp[(size_t)r * 512 + j];
            float raw = a.yp[(size_t)r * 512 + 256 + j];
            float sp = (raw > 20.f) ? raw : log1pf(__expf(raw));
            float scale = sp + 0.1f;
            size_t o = (size_t)fc * 4096 * 256 + i;
            a.out[OUT_PMU + o] = loc;
            a.out[OUT_PSD + o] = scale;
            a.out[OUT_PST + o] = loc + scale * a.eps_p[o];
          }
        }
      }
    }
    gbar(a.cnt, ++ep, bid);

    // ---- embed: hidden_{t+1}, 256 jobs 64x64 ----
    if (t < TM1 - 1) {
      gemm_tile<64, 64, 2>(a.xcat, a.WembT, a.b_embed, a.hidden, 2048, 320, 8, 1, sj, tid, pool);
      gbar(a.cnt, ++ep, bid);
    }
  }

  // ---- tail: prior chunk 7 only ----
  {
    const bf16* Ach = a.belA + (size_t)7 * 4096 * 2048;
    gemm_tile<128, 128, 2>(Ach, a.W1T, a.b1, a.hp, 2048, 2048, 32, 1, sj, tid, pool);
    gemm_tile<128, 128, 2>(Ach, a.W1T, a.b1, a.hp, 2048, 2048, 32, 1, sj + 256, tid, pool);
    gbar(a.cnt, ++ep, bid);

    if (sj < 128)
      gemm_tile<128, 128, 2>(a.hp, a.W2T, a.b2, a.yp, 512, 2048, 32, 0, sj, tid, pool);
    gbar(a.cnt, ++ep, bid);

    for (int i = bid * NT + tid; i < 4096 * 256; i += NB * NT) {
      int r = i >> 8, j = i & 255;
      float loc = a.yp[(size_t)r * 512 + j];
      float raw = a.yp[(size_t)r * 512 + 256 + j];
      float sp = (raw > 20.f) ? raw : log1pf(__expf(raw));
      float scale = sp + 0.1f;
      size_t o = (size_t)7 * 4096 * 256 + i;
      a.out[OUT_PMU + o] = loc;
      a.out[OUT_PSD + o] = scale;
      a.out[OUT_PST + o] = loc + scale * a.eps_p[o];
    }
    gbar(a.cnt, ++ep, bid);
  }
}

// ---------------------------------------------------------------------------
extern "C" void kernel_launch(void* const* d_in, const int* in_sizes, int n_in,
                              void* d_out, int out_size, void* d_ws, size_t ws_size,
                              hipStream_t stream)
{
  (void)in_sizes; (void)n_in; (void)out_size; (void)ws_size;
  Args a;
  a.prev_state = (const float*)d_in[0];
  a.actions    = (const float*)d_in[1];
  a.prev_belief= (const float*)d_in[2];
  a.obs_emb    = (const float*)d_in[3];
  a.nonterm    = (const float*)d_in[4];
  a.W_embed    = (const float*)d_in[5];
  a.b_embed    = (const float*)d_in[6];
  a.Wi         = (const float*)d_in[7];
  a.bi         = (const float*)d_in[8];
  a.Wh         = (const float*)d_in[9];
  a.bh         = (const float*)d_in[10];
  a.W1         = (const float*)d_in[11];
  a.b1         = (const float*)d_in[12];
  a.W2         = (const float*)d_in[13];
  a.b2         = (const float*)d_in[14];
  a.W1p        = (const float*)d_in[15];
  a.b1p        = (const float*)d_in[16];
  a.W2p        = (const float*)d_in[17];
  a.b2p        = (const float*)d_in[18];
  a.eps_p      = (const float*)d_in[19];
  a.eps_q      = (const float*)d_in[20];
  a.out        = (float*)d_out;

  char* ws = (char*)d_ws;
  size_t off = 0;
  auto alloc = [&](size_t bytes) -> char* {
    char* p = ws + off;
    off = (off + bytes + 255) & ~(size_t)255;
    return p;
  };
  a.cnt        = (unsigned*)alloc(4096);
  a.WembT      = (bf16*)alloc((size_t)2048 * 320 * 2);
  a.WiT        = (bf16*)alloc((size_t)6144 * 2048 * 2);
  a.WhT        = (bf16*)alloc((size_t)6144 * 2048 * 2);
  a.W1T        = (bf16*)alloc((size_t)2048 * 2048 * 2);
  a.W2T        = (bf16*)alloc((size_t)512 * 2048 * 2);
  a.W1pT       = (bf16*)alloc((size_t)2048 * 3072 * 2);
  a.W2pT       = (bf16*)alloc((size_t)512 * 2048 * 2);
  a.belief_f32 = (float*)alloc((size_t)512 * 2048 * 4);
  a.bel_init   = (bf16*)alloc((size_t)512 * 2048 * 2);
  a.xcat       = (bf16*)alloc((size_t)512 * 320 * 2);
  a.hidden     = (bf16*)alloc((size_t)512 * 2048 * 2);
  a.obsB       = (bf16*)alloc((size_t)TM1 * 512 * 1024 * 2);   // 67 MB
  a.hq         = (bf16*)alloc((size_t)512 * 2048 * 2);
  a.belA       = (bf16*)alloc((size_t)TM1 * 512 * 2048 * 2);   // 128 MB
  a.hp         = (bf16*)alloc((size_t)4096 * 2048 * 2);
  a.yp         = (float*)alloc((size_t)4096 * 512 * 4);

  hipFuncSetAttribute((const void*)mega,
                      hipFuncAttributeMaxDynamicSharedMemorySize, 98304);
  hipMemsetAsync(a.cnt, 0, 4096, stream);
  mega<<<NB, NT, 98304, stream>>>(a);
}

// Round 14
// 8850.917 us; speedup vs baseline: 2.0507x; 1.0097x over previous
//
#include <hip/hip_runtime.h>
#include <hip/hip_bf16.h>
#include <cstdint>

typedef __hip_bfloat16 bf16;
typedef __attribute__((ext_vector_type(8))) short bf16x8v;   // 8 bf16 in 4 VGPRs
typedef __attribute__((ext_vector_type(4))) float f32x4;

#define NB 256          // persistent blocks (1 per CU)
#define NT 512          // 8 waves (2 per SIMD)
#define TM1 64

// output offsets (elements) in d_out, per reference return order
#define OUT_BEL  ((size_t)0)
#define OUT_PST  ((size_t)67108864)
#define OUT_PMU  ((size_t)75497472)
#define OUT_PSD  ((size_t)83886080)
#define OUT_QST  ((size_t)92274688)
#define OUT_QMU  ((size_t)100663296)
#define OUT_QSD  ((size_t)109051904)

__device__ __forceinline__ void gload_lds16(const bf16* g, bf16* l) {
  __builtin_amdgcn_global_load_lds(
      (const __attribute__((address_space(1))) unsigned int*)g,
      (__attribute__((address_space(3))) unsigned int*)l, 16, 0, 0);
}

__device__ __forceinline__ unsigned short bfb(float f) {
  bf16 h = __float2bfloat16(f);
  return *reinterpret_cast<unsigned short*>(&h);
}

__device__ __forceinline__ float sigmoidf_(float x) { return 1.f / (1.f + __expf(-x)); }

// non-temporal store: write-only output streams bypass cache allocation so
// they don't evict the L3-resident weights (the R13 FETCH analysis).
__device__ __forceinline__ void nts(float v, float* p) {
  __builtin_nontemporal_store(v, p);
}

// XCD-spread job id for nj<=256 jobs over NB blocks (nj multiple of 8)
__device__ __forceinline__ int jid(int bid, int nj) {
  return (bid < nj) ? ((bid & 7) * (nj >> 3) + (bid >> 3)) : -1;
}

// ---------------------------------------------------------------------------
// hierarchical device-scope grid barrier (epoch-monotone, memset-zeroed)
// ---------------------------------------------------------------------------
__device__ __forceinline__ void gbar(unsigned* bars, unsigned e, int bid) {
  __syncthreads();
  const int g = bid & 7;
  const int tid = threadIdx.x;
  if (tid == 0) {
    __threadfence();   // release
    __hip_atomic_fetch_add(&bars[16 * g], 1u, __ATOMIC_RELAXED, __HIP_MEMORY_SCOPE_AGENT);
  }
  if (bid == 0) {
    if (tid < 8) {
      while (__hip_atomic_load(&bars[16 * tid], __ATOMIC_RELAXED, __HIP_MEMORY_SCOPE_AGENT) < 32u * e)
        __builtin_amdgcn_s_sleep(1);
    }
    __syncthreads();
    if (tid < 8)
      __hip_atomic_store(&bars[128 + 16 * tid], e, __ATOMIC_RELAXED, __HIP_MEMORY_SCOPE_AGENT);
  } else if (tid == 0) {
    while (__hip_atomic_load(&bars[128 + 16 * g], __ATOMIC_RELAXED, __HIP_MEMORY_SCOPE_AGENT) < e)
      __builtin_amdgcn_s_sleep(2);
  }
  if (tid == 0) __threadfence();   // acquire
  __syncthreads();
}

// ---------------------------------------------------------------------------
// generic GEMM tile: counted-vmcnt depth-DEPTH pipeline. acc <= 32 VGPRs.
// ---------------------------------------------------------------------------
template<int BM, int BN, int DEPTH>
__device__ void gemm_tile(const bf16* __restrict__ A, const bf16* __restrict__ B,
                          const float* __restrict__ bias, void* __restrict__ C,
                          int N, int K, int nm, int mode, int job, int tid,
                          char* pool)
{
  constexpr int LA = BM * 8 / NT;
  constexpr int LB = BN * 8 / NT;
  constexpr int L = LA + LB;
  constexpr int WMt = BM / 4, WNt = BN / 2;
  constexpr int MR = WMt / 16, NR = WNt / 16;
  bf16* sAb = (bf16*)pool;
  bf16* sBb = (bf16*)(pool + (size_t)DEPTH * BM * 64 * 2);

  const int m0 = (job % nm) * BM;
  const int n0 = (job / nm) * BN;
  const int lane = tid & 63;
  const int wid = tid >> 6;
  const int wm = wid >> 1, wn = wid & 1;
  const int lr = lane & 15;
  const int lg = lane >> 4;

  const bf16* Abase = A + (size_t)m0 * K;
  const bf16* Bbase = B + (size_t)n0 * K;

  auto stage = [&](int buf, int k0) {
    bf16* dA = sAb + buf * (BM * 64);
    bf16* dB = sBb + buf * (BN * 64);
    #pragma unroll
    for (int i = 0; i < LA; ++i) {
      int c = i * NT + tid;
      int row = c >> 3, kc = c & 7;
      gload_lds16(Abase + (size_t)row * K + k0 + ((kc ^ (row & 7)) << 3), &dA[c * 8]);
    }
    #pragma unroll
    for (int i = 0; i < LB; ++i) {
      int c = i * NT + tid;
      int row = c >> 3, kc = c & 7;
      gload_lds16(Bbase + (size_t)row * K + k0 + ((kc ^ (row & 7)) << 3), &dB[c * 8]);
    }
  };

  f32x4 acc[MR][NR] = {};
  __syncthreads();                 // pool handoff
  const int nk = K >> 6;
  #pragma unroll
  for (int d = 0; d < DEPTH; ++d)
    if (d < nk) stage(d, d << 6);
  int cur = 0;
  for (int it = 0; it < nk; ++it) {
    if (DEPTH == 3) {
      if (it + 2 < nk)      { asm volatile("s_waitcnt vmcnt(%0)" :: "n"(2 * L) : "memory"); }
      else if (it + 1 < nk) { asm volatile("s_waitcnt vmcnt(%0)" :: "n"(L) : "memory"); }
      else                  { asm volatile("s_waitcnt vmcnt(0)" ::: "memory"); }
    } else {
      if (it + 1 < nk)      { asm volatile("s_waitcnt vmcnt(%0)" :: "n"(L) : "memory"); }
      else                  { asm volatile("s_waitcnt vmcnt(0)" ::: "memory"); }
    }
    __builtin_amdgcn_sched_barrier(0);
    __builtin_amdgcn_s_barrier();
    __builtin_amdgcn_sched_barrier(0);
    const bf16* cA = sAb + cur * (BM * 64);
    const bf16* cB = sBb + cur * (BN * 64);
    #pragma unroll
    for (int kk = 0; kk < 2; ++kk) {
      const int jg = kk * 4 + lg;
      bf16x8v af[MR], bfv[NR];
      #pragma unroll
      for (int m = 0; m < MR; ++m) {
        int ar = wm * WMt + m * 16 + lr;
        af[m] = *(const bf16x8v*)&cA[ar * 64 + ((jg ^ (ar & 7)) << 3)];
      }
      #pragma unroll
      for (int n = 0; n < NR; ++n) {
        int br = wn * WNt + n * 16 + lr;
        bfv[n] = *(const bf16x8v*)&cB[br * 64 + ((jg ^ (br & 7)) << 3)];
      }
      #pragma unroll
      for (int m = 0; m < MR; ++m)
        #pragma unroll
        for (int n = 0; n < NR; ++n)
          acc[m][n] = __builtin_amdgcn_mfma_f32_16x16x32_bf16(af[m], bfv[n], acc[m][n], 0, 0, 0);
    }
    __builtin_amdgcn_sched_barrier(0);
    __builtin_amdgcn_s_barrier();
    __builtin_amdgcn_sched_barrier(0);
    if (it + DEPTH < nk) stage(cur, (it + DEPTH) << 6);
    cur = (cur + 1 == DEPTH) ? 0 : cur + 1;
  }

  const int r0 = (lane >> 4) * 4;
  #pragma unroll
  for (int m = 0; m < MR; ++m) {
    #pragma unroll
    for (int n = 0; n < NR; ++n) {
      int gc = n0 + wn * WNt + n * 16 + lr;
      float bv = bias[gc];
      #pragma unroll
      for (int r = 0; r < 4; ++r) {
        int gr = m0 + wm * WMt + m * 16 + r0 + r;
        float v = acc[m][n][r] + bv;
        if (mode == 1)
          ((bf16*)C)[(size_t)gr * N + gc] = __float2bfloat16(v > 0.f ? v : 0.f);
        else
          ((float*)C)[(size_t)gr * N + gc] = v;
      }
    }
  }
}

// ---------------------------------------------------------------------------
// FUSED GRU (R9-proven 64x64 shape, acc = 32 VGPRs), DEPTH-3 pipeline:
// 256 jobs of (64 rows x 64 gate-cols x 3 gates).
// LDS: A 3x8KB [0,24K) + B 3x24KB [24K,96K) = 96KB. L=4 per stage.
// ---------------------------------------------------------------------------
__device__ void fused_gru(const bf16* __restrict__ hidden, const bf16* __restrict__ belsrc,
                          const bf16* __restrict__ WiT, const bf16* __restrict__ WhT,
                          const float* __restrict__ bi, const float* __restrict__ bh,
                          float* __restrict__ belief_f32, float* __restrict__ out_bel,
                          bf16* __restrict__ belslot,
                          int job, int tid, char* pool)
{
  bf16 (*sA)[64 * 64]  = (bf16(*)[64 * 64])pool;              // 3 x 8KB
  bf16 (*sB)[192 * 64] = (bf16(*)[192 * 64])(pool + 24576);   // 3 x 24KB

  const int m0 = (job & 7) * 64;
  const int j0 = (job >> 3) * 64;
  const int lane = tid & 63;
  const int wid = tid >> 6;
  const int wm = wid >> 2, wn = wid & 3;   // 2 m x 4 n; WMt=32, WNt=16
  const int lr = lane & 15;
  const int lg = lane >> 4;

  auto stage = [&](int buf, int gt) {
    const bf16* Ab; const bf16* Bb; int k0;
    if (gt < 32) { Ab = hidden; Bb = WiT; k0 = gt << 6; }
    else         { Ab = belsrc; Bb = WhT; k0 = (gt - 32) << 6; }
    {
      int c = tid;                       // A: 64 rows x 8 chunks = 512
      int row = c >> 3, kc = c & 7;
      gload_lds16(Ab + (size_t)(m0 + row) * 2048 + k0 + ((kc ^ (row & 7)) << 3),
                  &sA[buf][c * 8]);
    }
    #pragma unroll
    for (int i = 0; i < 3; ++i) {        // B: 192 rows (3 gates x 64)
      int c = i * NT + tid;
      int r = c >> 3, kc = c & 7;
      int grow = (r >> 6) * 2048 + j0 + (r & 63);
      gload_lds16(Bb + (size_t)grow * 2048 + k0 + ((kc ^ (r & 7)) << 3),
                  &sB[buf][c * 8]);
    }
  };

  f32x4 ar_[2] = {}, az_[2] = {}, ain[2] = {}, ahn[2] = {};
  int cur = 0;

  auto body = [&](int gt, f32x4 (&ax)[2]) {
    if (gt < 62)      { asm volatile("s_waitcnt vmcnt(8)" ::: "memory"); }
    else if (gt == 62){ asm volatile("s_waitcnt vmcnt(4)" ::: "memory"); }
    else              { asm volatile("s_waitcnt vmcnt(0)" ::: "memory"); }
    __builtin_amdgcn_sched_barrier(0);
    __builtin_amdgcn_s_barrier();
    __builtin_amdgcn_sched_barrier(0);
    #pragma unroll
    for (int kk = 0; kk < 2; ++kk) {
      const int jg = kk * 4 + lg;
      bf16x8v af[2], bg[3];
      #pragma unroll
      for (int m = 0; m < 2; ++m) {
        int arow = wm * 32 + m * 16 + lr;
        af[m] = *(const bf16x8v*)&sA[cur][arow * 64 + ((jg ^ (arow & 7)) << 3)];
      }
      #pragma unroll
      for (int g = 0; g < 3; ++g) {
        int br = g * 64 + wn * 16 + lr;
        bg[g] = *(const bf16x8v*)&sB[cur][br * 64 + ((jg ^ (br & 7)) << 3)];
      }
      #pragma unroll
      for (int m = 0; m < 2; ++m) {
        ar_[m] = __builtin_amdgcn_mfma_f32_16x16x32_bf16(af[m], bg[0], ar_[m], 0, 0, 0);
        az_[m] = __builtin_amdgcn_mfma_f32_16x16x32_bf16(af[m], bg[1], az_[m], 0, 0, 0);
        ax[m]  = __builtin_amdgcn_mfma_f32_16x16x32_bf16(af[m], bg[2], ax[m], 0, 0, 0);
      }
    }
    __builtin_amdgcn_sched_barrier(0);
    __builtin_amdgcn_s_barrier();
    __builtin_amdgcn_sched_barrier(0);
    if (gt + 3 < 64) stage(cur, gt + 3);
    cur = (cur + 1 == 3) ? 0 : cur + 1;
  };

  __syncthreads();                 // pool handoff
  stage(0, 0);
  stage(1, 1);
  stage(2, 2);
  for (int gt = 0; gt < 32; ++gt) body(gt, ain);
  for (int gt = 32; gt < 64; ++gt) body(gt, ahn);

  const int gc = j0 + wn * 16 + lr;
  const float br_b  = bi[gc] + bh[gc];
  const float bz_b  = bi[2048 + gc] + bh[2048 + gc];
  const float bin_b = bi[4096 + gc];
  const float bhn_b = bh[4096 + gc];
  const int r0 = (lane >> 4) * 4;
  #pragma unroll
  for (int m = 0; m < 2; ++m) {
    #pragma unroll
    for (int r = 0; r < 4; ++r) {
      int grow = m0 + wm * 32 + m * 16 + r0 + r;
      size_t idx = (size_t)grow * 2048 + gc;
      float rr = sigmoidf_(ar_[m][r] + br_b);
      float zz = sigmoidf_(az_[m][r] + bz_b);
      float nn = tanhf(ain[m][r] + bin_b + rr * (ahn[m][r] + bhn_b));
      float bo = belief_f32[idx];
      float nb = (1.f - zz) * nn + zz * bo;
      belief_f32[idx] = nb;
      nts(nb, &out_bel[idx]);              // write-only stream: non-temporal
      belslot[idx] = __float2bfloat16(nb); // re-read by W1p/prior: cached
    }
  }
}

// ---------------------------------------------------------------------------
// W1p GEMM (R9-proven 64x64 shape), DEPTH-3: dual-source A (belA 2048 ++ obs
// 1024), K=3072, 256 jobs. LDS 3x8KB + 3x8KB = 48KB. L=2.
// ---------------------------------------------------------------------------
__device__ void gemm_w1p(const bf16* __restrict__ Abel, const bf16* __restrict__ Aobs,
                         const bf16* __restrict__ B, const float* __restrict__ bias,
                         bf16* __restrict__ C, int job, int tid, char* pool)
{
  constexpr int K = 3072, NK = 48;
  bf16 (*sA)[64 * 64] = (bf16(*)[64 * 64])pool;               // 3 x 8KB
  bf16 (*sB)[64 * 64] = (bf16(*)[64 * 64])(pool + 24576);     // 3 x 8KB

  const int m0 = (job & 7) * 64;
  const int n0 = (job >> 3) * 64;
  const int lane = tid & 63;
  const int wid = tid >> 6;
  const int wm = wid >> 1, wn = wid & 1;   // 4 x 2; WMt=16, WNt=32
  const int lr = lane & 15;
  const int lg = lane >> 4;

  auto stage = [&](int buf, int k0) {
    {
      int c = tid;
      int row = c >> 3, kc = c & 7;
      int sw = (kc ^ (row & 7)) << 3;
      const bf16* src = (k0 < 2048)
          ? Abel + (size_t)(m0 + row) * 2048 + k0 + sw
          : Aobs + (size_t)(m0 + row) * 1024 + (k0 - 2048) + sw;
      gload_lds16(src, &sA[buf][c * 8]);
    }
    {
      int c = tid;
      int row = c >> 3, kc = c & 7;
      gload_lds16(B + (size_t)(n0 + row) * K + k0 + ((kc ^ (row & 7)) << 3), &sB[buf][c * 8]);
    }
  };

  f32x4 acc[2] = {};
  __syncthreads();
  stage(0, 0); stage(1, 64); stage(2, 128);
  int cur = 0;
  for (int it = 0; it < NK; ++it) {
    if (it + 2 < NK)      { asm volatile("s_waitcnt vmcnt(4)" ::: "memory"); }
    else if (it + 1 < NK) { asm volatile("s_waitcnt vmcnt(2)" ::: "memory"); }
    else                  { asm volatile("s_waitcnt vmcnt(0)" ::: "memory"); }
    __builtin_amdgcn_sched_barrier(0);
    __builtin_amdgcn_s_barrier();
    __builtin_amdgcn_sched_barrier(0);
    #pragma unroll
    for (int kk = 0; kk < 2; ++kk) {
      const int jg = kk * 4 + lg;
      int arow = wm * 16 + lr;
      bf16x8v af = *(const bf16x8v*)&sA[cur][arow * 64 + ((jg ^ (arow & 7)) << 3)];
      #pragma unroll
      for (int n = 0; n < 2; ++n) {
        int br = wn * 32 + n * 16 + lr;
        bf16x8v bv = *(const bf16x8v*)&sB[cur][br * 64 + ((jg ^ (br & 7)) << 3)];
        acc[n] = __builtin_amdgcn_mfma_f32_16x16x32_bf16(af, bv, acc[n], 0, 0, 0);
      }
    }
    __builtin_amdgcn_sched_barrier(0);
    __builtin_amdgcn_s_barrier();
    __builtin_amdgcn_sched_barrier(0);
    if (it + 3 < NK) stage(cur, (it + 3) << 6);
    cur = (cur + 1 == 3) ? 0 : cur + 1;
  }

  const int r0 = (lane >> 4) * 4;
  #pragma unroll
  for (int n = 0; n < 2; ++n) {
    int gcn = n0 + wn * 32 + n * 16 + lr;
    float bv = bias[gcn];
    #pragma unroll
    for (int r = 0; r < 4; ++r) {
      int gr = m0 + wm * 16 + r0 + r;
      float v = acc[n][r] + bv;
      C[(size_t)gr * 2048 + gcn] = __float2bfloat16(v > 0.f ? v : 0.f);
    }
  }
}

// ---------------------------------------------------------------------------
// fused W2p GEMM (512x512, K=2048) + posterior epilogue (R9-proven)
// ---------------------------------------------------------------------------
__device__ void w2p_tile(const bf16* __restrict__ hq, const bf16* __restrict__ W2pT,
                         const float* __restrict__ b2p, const float* __restrict__ eps,
                         float* __restrict__ o_mu, float* __restrict__ o_sd,
                         float* __restrict__ o_st,
                         const float* __restrict__ nt_next,
                         const float* __restrict__ act_next,
                         bf16* __restrict__ xcat, int make_xcat,
                         int blk, int tid, char* pool)
{
  constexpr int K = 2048, NK = K / 64;
  const int mb = blk & 7, nl = blk >> 3;
  const int m0 = mb * 64;
  const int j0 = nl * 32;

  bf16 (*sA)[64 * 64] = (bf16(*)[64 * 64])pool;
  bf16 (*sB)[64 * 64] = (bf16(*)[64 * 64])(pool + 16384);
  float* tile = (float*)pool;

  const int lane = tid & 63;
  const int wid = tid >> 6;
  const int wm = wid >> 1, wn = wid & 1;
  const int lr = lane & 15;
  const int lg = lane >> 4;

  const bf16* Abase = hq + (size_t)m0 * K;

  auto stage = [&](int buf, int k0) {
    {
      int c = tid;
      int row = c >> 3, kc = c & 7;
      gload_lds16(Abase + (size_t)row * K + k0 + ((kc ^ (row & 7)) << 3), &sA[buf][c * 8]);
    }
    {
      int c = tid;
      int row = c >> 3, kc = c & 7;
      int grow = (row < 32) ? (j0 + row) : (224 + j0 + row);
      gload_lds16(W2pT + (size_t)grow * K + k0 + ((kc ^ (row & 7)) << 3), &sB[buf][c * 8]);
    }
  };

  f32x4 acc[2] = {};
  __syncthreads();
  stage(0, 0);
  stage(1, 64);
  for (int it = 0; it < NK; ++it) {
    const int cur = it & 1;
    if (it + 1 < NK) { asm volatile("s_waitcnt vmcnt(2)" ::: "memory"); }
    else             { asm volatile("s_waitcnt vmcnt(0)" ::: "memory"); }
    __builtin_amdgcn_sched_barrier(0);
    __builtin_amdgcn_s_barrier();
    __builtin_amdgcn_sched_barrier(0);
    #pragma unroll
    for (int kk = 0; kk < 2; ++kk) {
      const int jg = kk * 4 + lg;
      int ar = wm * 16 + lr;
      bf16x8v af = *(const bf16x8v*)&sA[cur][ar * 64 + ((jg ^ (ar & 7)) << 3)];
      #pragma unroll
      for (int n = 0; n < 2; ++n) {
        int br = wn * 32 + n * 16 + lr;
        bf16x8v bfv = *(const bf16x8v*)&sB[cur][br * 64 + ((jg ^ (br & 7)) << 3)];
        acc[n] = __builtin_amdgcn_mfma_f32_16x16x32_bf16(af, bfv, acc[n], 0, 0, 0);
      }
    }
    __builtin_amdgcn_sched_barrier(0);
    __builtin_amdgcn_s_barrier();
    __builtin_amdgcn_sched_barrier(0);
    if (it + 2 < NK) stage(cur, (it + 2) << 6);
  }

  const int r0 = (lane >> 4) * 4;
  #pragma unroll
  for (int n = 0; n < 2; ++n) {
    int tc = wn * 32 + n * 16 + lr;
    #pragma unroll
    for (int r = 0; r < 4; ++r)
      tile[(wm * 16 + r0 + r) * 64 + tc] = acc[n][r];
  }
  __syncthreads();

  for (int e = tid; e < 64 * 32; e += NT) {
    int rr = e >> 5, cc = e & 31;
    int b = m0 + rr;
    int j = j0 + cc;
    float loc = tile[rr * 64 + cc] + b2p[j];
    float raw = tile[rr * 64 + 32 + cc] + b2p[256 + j];
    float sp = (raw > 20.f) ? raw : log1pf(__expf(raw));
    float scale = sp + 0.1f;
    float st = loc + scale * eps[(size_t)b * 256 + j];
    nts(loc,   &o_mu[(size_t)b * 256 + j]);
    nts(scale, &o_sd[(size_t)b * 256 + j]);
    nts(st,    &o_st[(size_t)b * 256 + j]);
    if (make_xcat)
      xcat[(size_t)b * 320 + j] = __float2bfloat16(st * nt_next[b]);
  }
  if (make_xcat && nl == 0) {
    for (int e = tid; e < 64 * 64; e += NT) {
      int rr = e >> 6, cc = e & 63;
      int b = m0 + rr;
      xcat[(size_t)b * 320 + 256 + cc] = __float2bfloat16(act_next[(size_t)b * 64 + cc]);
    }
  }
}

// ---------------------------------------------------------------------------
__device__ void transpose_phase(const float* __restrict__ src, bf16* __restrict__ dst,
                                int K, int N, int bid, int tid, float* t /*32x33*/)
{
  const int ntile = (K / 32) * (N / 32);
  const int tx = tid & 31, ty = tid >> 5;   // 32 x 16
  for (int it = bid; it < ntile; it += NB) {
    int kt = it % (K / 32), nt = it / (K / 32);
    int k0 = kt * 32, n0 = nt * 32;
    __syncthreads();
    #pragma unroll
    for (int i = 0; i < 32; i += 16)
      t[(ty + i) * 33 + tx] = src[(size_t)(k0 + ty + i) * N + n0 + tx];
    __syncthreads();
    #pragma unroll
    for (int i = 0; i < 32; i += 16)
      dst[(size_t)(n0 + ty + i) * K + k0 + tx] = __float2bfloat16(t[tx * 33 + ty + i]);
  }
}

struct Args {
  const float *prev_state, *actions, *prev_belief, *obs_emb, *nonterm;
  const float *W_embed, *b_embed, *Wi, *bi, *Wh, *bh;
  const float *W1, *b1, *W2, *b2, *W1p, *b1p, *W2p, *b2p;
  const float *eps_p, *eps_q;
  bf16 *WembT, *WiT, *WhT, *W1T, *W2T, *W1pT, *W2pT;
  float* belief_f32; bf16 *bel_init, *xcat, *hidden, *obsB;
  bf16 *hq, *belA, *hp; float* yp;
  float* out;
  unsigned* cnt;
};

// ---------------------------------------------------------------------------
__global__ __launch_bounds__(NT, 2) void mega(Args a)
{
  extern __shared__ char pool[];        // 96 KB
  const int bid = blockIdx.x;
  const int tid = threadIdx.x;
  const int sj = ((bid & 7) << 5) | (bid >> 3);   // XCD-grouped job id (256 jobs)
  unsigned ep = 0;

  // ---- P0: weight transposes + init + obs bf16 precompute ----
  transpose_phase(a.W_embed, a.WembT, 320, 2048, bid, tid, (float*)pool);
  transpose_phase(a.Wi,  a.WiT,  2048, 6144, bid, tid, (float*)pool);
  transpose_phase(a.Wh,  a.WhT,  2048, 6144, bid, tid, (float*)pool);
  transpose_phase(a.W1,  a.W1T,  2048, 2048, bid, tid, (float*)pool);
  transpose_phase(a.W2,  a.W2T,  2048, 512,  bid, tid, (float*)pool);
  transpose_phase(a.W1p, a.W1pT, 3072, 2048, bid, tid, (float*)pool);
  transpose_phase(a.W2p, a.W2pT, 2048, 512,  bid, tid, (float*)pool);
  for (int i = bid * NT + tid; i < 512 * 2048; i += NB * NT) {
    float v = a.prev_belief[i];
    a.belief_f32[i] = v;
    a.bel_init[i] = __float2bfloat16(v);
  }
  for (int i = bid * NT + tid; i < 512 * 320; i += NB * NT) {
    int b = i / 320, c = i - b * 320;
    float v = (c < 256) ? a.prev_state[b * 256 + c] * a.nonterm[b]
                        : a.actions[b * 64 + (c - 256)];
    a.xcat[i] = __float2bfloat16(v);
  }
  for (int i = bid * NT + tid; i < TM1 * 512 * 1024 / 4; i += NB * NT) {
    float4 v = *(const float4*)&a.obs_emb[(size_t)i * 4];
    ushort4 u; u.x = bfb(v.x); u.y = bfb(v.y); u.z = bfb(v.z); u.w = bfb(v.w);
    *(ushort4*)&a.obsB[(size_t)i * 4] = u;
  }
  gbar(a.cnt, ++ep, bid);

  // ---- hidden_0 = relu(xcat @ WembT + b_embed), 256 jobs 64x64 ----
  gemm_tile<64, 64, 2>(a.xcat, a.WembT, a.b_embed, a.hidden, 2048, 320, 8, 1, sj, tid, pool);
  gbar(a.cnt, ++ep, bid);

  for (int t = 0; t < TM1; ++t) {
    // ---- fused GRU, 256 jobs 64x64x3, depth-3 ----
    const bf16* belsrc = (t == 0) ? a.bel_init : a.belA + (size_t)(t - 1) * 512 * 2048;
    fused_gru(a.hidden, belsrc, a.WiT, a.WhT, a.bi, a.bh,
              a.belief_f32,
              a.out + OUT_BEL + (size_t)t * 512 * 2048,
              a.belA + (size_t)t * 512 * 2048,
              sj, tid, pool);
    gbar(a.cnt, ++ep, bid);

    // ---- W1p, 256 jobs 64x64, depth-3 ----
    gemm_w1p(a.belA + (size_t)t * 512 * 2048,
             a.obsB + (size_t)t * 512 * 1024,
             a.W1pT, a.b1p, a.hq, sj, tid, pool);
    gbar(a.cnt, ++ep, bid);

    // ---- fused W2p + posterior (blocks 0..63) ; prior filler (64..255) ----
    {
      int tn = (t < TM1 - 1) ? t + 1 : t;
      if (bid < 64) {
        w2p_tile(a.hq, a.W2pT, a.b2p,
                 a.eps_q + (size_t)t * 512 * 256,
                 a.out + OUT_QMU + (size_t)t * 512 * 256,
                 a.out + OUT_QSD + (size_t)t * 512 * 256,
                 a.out + OUT_QST + (size_t)t * 512 * 256,
                 a.nonterm + (size_t)tn * 512,
                 a.actions + (size_t)tn * 512 * 64,
                 a.xcat, (t < TM1 - 1) ? 1 : 0, bid, tid, pool);
      } else if (t >= 8) {
        // folded prior for chunk fc = t/8 - 1
        const int fc = (t >> 3) - 1;
        const int q  = t & 7;
        const int fb = bid - 64;                     // 0..191
        const bf16* Ach = a.belA + (size_t)fc * 4096 * 2048;
        if (q < 2) {
          gemm_tile<128, 128, 2>(Ach, a.W1T, a.b1, a.hp, 2048, 2048, 32, 1,
                                 q * 192 + fb, tid, pool);
        } else if (q == 2) {
          if (fb < 128)
            gemm_tile<128, 128, 2>(Ach, a.W1T, a.b1, a.hp, 2048, 2048, 32, 1,
                                   384 + fb, tid, pool);
        } else if (q == 3) {
          if (fb < 128)
            gemm_tile<128, 128, 2>(a.hp, a.W2T, a.b2, a.yp, 512, 2048, 32, 0,
                                   fb, tid, pool);
        } else if (q == 4) {
          for (int i = fb * NT + tid; i < 4096 * 256; i += 192 * NT) {
            int r = i >> 8, j = i & 255;
            float loc = a.yp[(size_t)r * 512 + j];
            float raw = a.yp[(size_t)r * 512 + 256 + j];
            float sp = (raw > 20.f) ? raw : log1pf(__expf(raw));
            float scale = sp + 0.1f;
            size_t o = (size_t)fc * 4096 * 256 + i;
            nts(loc,                    &a.out[OUT_PMU + o]);
            nts(scale,                  &a.out[OUT_PSD + o]);
            nts(loc + scale * a.eps_p[o], &a.out[OUT_PST + o]);
          }
        }
      }
    }
    gbar(a.cnt, ++ep, bid);

    // ---- embed: hidden_{t+1}, 256 jobs 64x64 ----
    if (t < TM1 - 1) {
      gemm_tile<64, 64, 2>(a.xcat, a.WembT, a.b_embed, a.hidden, 2048, 320, 8, 1, sj, tid, pool);
      gbar(a.cnt, ++ep, bid);
    }
  }

  // ---- tail: prior chunk 7 only ----
  {
    const bf16* Ach = a.belA + (size_t)7 * 4096 * 2048;
    gemm_tile<128, 128, 2>(Ach, a.W1T, a.b1, a.hp, 2048, 2048, 32, 1, sj, tid, pool);
    gemm_tile<128, 128, 2>(Ach, a.W1T, a.b1, a.hp, 2048, 2048, 32, 1, sj + 256, tid, pool);
    gbar(a.cnt, ++ep, bid);

    if (sj < 128)
      gemm_tile<128, 128, 2>(a.hp, a.W2T, a.b2, a.yp, 512, 2048, 32, 0, sj, tid, pool);
    gbar(a.cnt, ++ep, bid);

    for (int i = bid * NT + tid; i < 4096 * 256; i += NB * NT) {
      int r = i >> 8, j = i & 255;
      float loc = a.yp[(size_t)r * 512 + j];
      float raw = a.yp[(size_t)r * 512 + 256 + j];
      float sp = (raw > 20.f) ? raw : log1pf(__expf(raw));
      float scale = sp + 0.1f;
      size_t o = (size_t)7 * 4096 * 256 + i;
      nts(loc,                      &a.out[OUT_PMU + o]);
      nts(scale,                    &a.out[OUT_PSD + o]);
      nts(loc + scale * a.eps_p[o], &a.out[OUT_PST + o]);
    }
    gbar(a.cnt, ++ep, bid);
  }
}

// ---------------------------------------------------------------------------
extern "C" void kernel_launch(void* const* d_in, const int* in_sizes, int n_in,
                              void* d_out, int out_size, void* d_ws, size_t ws_size,
                              hipStream_t stream)
{
  (void)in_sizes; (void)n_in; (void)out_size; (void)ws_size;
  Args a;
  a.prev_state = (const float*)d_in[0];
  a.actions    = (const float*)d_in[1];
  a.prev_belief= (const float*)d_in[2];
  a.obs_emb    = (const float*)d_in[3];
  a.nonterm    = (const float*)d_in[4];
  a.W_embed    = (const float*)d_in[5];
  a.b_embed    = (const float*)d_in[6];
  a.Wi         = (const float*)d_in[7];
  a.bi         = (const float*)d_in[8];
  a.Wh         = (const float*)d_in[9];
  a.bh         = (const float*)d_in[10];
  a.W1         = (const float*)d_in[11];
  a.b1         = (const float*)d_in[12];
  a.W2         = (const float*)d_in[13];
  a.b2         = (const float*)d_in[14];
  a.W1p        = (const float*)d_in[15];
  a.b1p        = (const float*)d_in[16];
  a.W2p        = (const float*)d_in[17];
  a.b2p        = (const float*)d_in[18];
  a.eps_p      = (const float*)d_in[19];
  a.eps_q      = (const float*)d_in[20];
  a.out        = (float*)d_out;

  char* ws = (char*)d_ws;
  size_t off = 0;
  auto alloc = [&](size_t bytes) -> char* {
    char* p = ws + off;
    off = (off + bytes + 255) & ~(size_t)255;
    return p;
  };
  a.cnt        = (unsigned*)alloc(4096);
  a.WembT      = (bf16*)alloc((size_t)2048 * 320 * 2);
  a.WiT        = (bf16*)alloc((size_t)6144 * 2048 * 2);
  a.WhT        = (bf16*)alloc((size_t)6144 * 2048 * 2);
  a.W1T        = (bf16*)alloc((size_t)2048 * 2048 * 2);
  a.W2T        = (bf16*)alloc((size_t)512 * 2048 * 2);
  a.W1pT       = (bf16*)alloc((size_t)2048 * 3072 * 2);
  a.W2pT       = (bf16*)alloc((size_t)512 * 2048 * 2);
  a.belief_f32 = (float*)alloc((size_t)512 * 2048 * 4);
  a.bel_init   = (bf16*)alloc((size_t)512 * 2048 * 2);
  a.xcat       = (bf16*)alloc((size_t)512 * 320 * 2);
  a.hidden     = (bf16*)alloc((size_t)512 * 2048 * 2);
  a.obsB       = (bf16*)alloc((size_t)TM1 * 512 * 1024 * 2);   // 67 MB
  a.hq         = (bf16*)alloc((size_t)512 * 2048 * 2);
  a.belA       = (bf16*)alloc((size_t)TM1 * 512 * 2048 * 2);   // 128 MB
  a.hp         = (bf16*)alloc((size_t)4096 * 2048 * 2);
  a.yp         = (float*)alloc((size_t)4096 * 512 * 4);

  hipFuncSetAttribute((const void*)mega,
                      hipFuncAttributeMaxDynamicSharedMemorySize, 98304);
  hipMemsetAsync(a.cnt, 0, 4096, stream);
  mega<<<NB, NT, 98304, stream>>>(a);
}

// Round 15
// 8810.027 us; speedup vs baseline: 2.0602x; 1.0046x over previous
//
#include <hip/hip_runtime.h>
#include <hip/hip_bf16.h>
#include <cstdint>

typedef __hip_bfloat16 bf16;
typedef __attribute__((ext_vector_type(8))) short bf16x8v;   // 8 bf16 in 4 VGPRs
typedef __attribute__((ext_vector_type(4))) float f32x4;

#define NB 256          // persistent blocks (1 per CU)
#define NT 512          // 8 waves (2 per SIMD)
#define TM1 64

// output offsets (elements) in d_out, per reference return order
#define OUT_BEL  ((size_t)0)
#define OUT_PST  ((size_t)67108864)
#define OUT_PMU  ((size_t)75497472)
#define OUT_PSD  ((size_t)83886080)
#define OUT_QST  ((size_t)92274688)
#define OUT_QMU  ((size_t)100663296)
#define OUT_QSD  ((size_t)109051904)

__device__ __forceinline__ void gload_lds16(const bf16* g, bf16* l) {
  __builtin_amdgcn_global_load_lds(
      (const __attribute__((address_space(1))) unsigned int*)g,
      (__attribute__((address_space(3))) unsigned int*)l, 16, 0, 0);
}

__device__ __forceinline__ unsigned short bfb(float f) {
  bf16 h = __float2bfloat16(f);
  return *reinterpret_cast<unsigned short*>(&h);
}

__device__ __forceinline__ float sigmoidf_(float x) { return 1.f / (1.f + __expf(-x)); }

__device__ __forceinline__ void nts(float v, float* p) {
  __builtin_nontemporal_store(v, p);
}

// ---------------------------------------------------------------------------
// hierarchical device-scope grid barrier (epoch-monotone, memset-zeroed)
// ---------------------------------------------------------------------------
__device__ __forceinline__ void gbar(unsigned* bars, unsigned e, int bid) {
  __syncthreads();
  const int g = bid & 7;
  const int tid = threadIdx.x;
  if (tid == 0) {
    __threadfence();   // release
    __hip_atomic_fetch_add(&bars[16 * g], 1u, __ATOMIC_RELAXED, __HIP_MEMORY_SCOPE_AGENT);
  }
  if (bid == 0) {
    if (tid < 8) {
      while (__hip_atomic_load(&bars[16 * tid], __ATOMIC_RELAXED, __HIP_MEMORY_SCOPE_AGENT) < 32u * e)
        __builtin_amdgcn_s_sleep(1);
    }
    __syncthreads();
    if (tid < 8)
      __hip_atomic_store(&bars[128 + 16 * tid], e, __ATOMIC_RELAXED, __HIP_MEMORY_SCOPE_AGENT);
  } else if (tid == 0) {
    while (__hip_atomic_load(&bars[128 + 16 * g], __ATOMIC_RELAXED, __HIP_MEMORY_SCOPE_AGENT) < e)
      __builtin_amdgcn_s_sleep(2);
  }
  if (tid == 0) __threadfence();   // acquire
  __syncthreads();
}

// ---------------------------------------------------------------------------
// generic GEMM tile — SINGLE-barrier K-loop, 3-buffer rotation:
//   wait vmcnt(L) -> s_barrier -> stage tile(it+2) into buf consumed last
//   iter -> MFMA cur.   The pre-MFMA barrier doubles as the read-done fence
//   for the staged buffer (all waves finished iter it-1's reads).
// acc <= 32 VGPRs for all instantiations (BM<=128, BN<=128).
// ---------------------------------------------------------------------------
template<int BM, int BN>
__device__ void gemm_tile(const bf16* __restrict__ A, const bf16* __restrict__ B,
                          const float* __restrict__ bias, void* __restrict__ C,
                          int N, int K, int nm, int mode, int job, int tid,
                          char* pool)
{
  constexpr int LA = BM * 8 / NT;
  constexpr int LB = BN * 8 / NT;
  constexpr int L = LA + LB;
  constexpr int WMt = BM / 4, WNt = BN / 2;
  constexpr int MR = WMt / 16, NR = WNt / 16;
  bf16* sAb = (bf16*)pool;                           // 3 x BM*64
  bf16* sBb = (bf16*)(pool + (size_t)3 * BM * 64 * 2);

  const int m0 = (job % nm) * BM;
  const int n0 = (job / nm) * BN;
  const int lane = tid & 63;
  const int wid = tid >> 6;
  const int wm = wid >> 1, wn = wid & 1;
  const int lr = lane & 15;
  const int lg = lane >> 4;

  const bf16* Abase = A + (size_t)m0 * K;
  const bf16* Bbase = B + (size_t)n0 * K;

  auto stage = [&](int buf, int k0) {
    bf16* dA = sAb + buf * (BM * 64);
    bf16* dB = sBb + buf * (BN * 64);
    #pragma unroll
    for (int i = 0; i < LA; ++i) {
      int c = i * NT + tid;
      int row = c >> 3, kc = c & 7;
      gload_lds16(Abase + (size_t)row * K + k0 + ((kc ^ (row & 7)) << 3), &dA[c * 8]);
    }
    #pragma unroll
    for (int i = 0; i < LB; ++i) {
      int c = i * NT + tid;
      int row = c >> 3, kc = c & 7;
      gload_lds16(Bbase + (size_t)row * K + k0 + ((kc ^ (row & 7)) << 3), &dB[c * 8]);
    }
  };

  f32x4 acc[MR][NR] = {};
  __syncthreads();                 // pool handoff
  const int nk = K >> 6;
  stage(0, 0);
  if (nk > 1) stage(1, 64);
  for (int it = 0; it < nk; ++it) {
    const int cur = it % 3;
    if (it + 1 < nk) { asm volatile("s_waitcnt vmcnt(%0)" :: "n"(L) : "memory"); }
    else             { asm volatile("s_waitcnt vmcnt(0)" ::: "memory"); }
    __builtin_amdgcn_sched_barrier(0);
    __builtin_amdgcn_s_barrier();
    __builtin_amdgcn_sched_barrier(0);
    if (it + 2 < nk) stage((it + 2) % 3, (it + 2) << 6);
    const bf16* cA = sAb + cur * (BM * 64);
    const bf16* cB = sBb + cur * (BN * 64);
    #pragma unroll
    for (int kk = 0; kk < 2; ++kk) {
      const int jg = kk * 4 + lg;
      bf16x8v af[MR], bfv[NR];
      #pragma unroll
      for (int m = 0; m < MR; ++m) {
        int ar = wm * WMt + m * 16 + lr;
        af[m] = *(const bf16x8v*)&cA[ar * 64 + ((jg ^ (ar & 7)) << 3)];
      }
      #pragma unroll
      for (int n = 0; n < NR; ++n) {
        int br = wn * WNt + n * 16 + lr;
        bfv[n] = *(const bf16x8v*)&cB[br * 64 + ((jg ^ (br & 7)) << 3)];
      }
      #pragma unroll
      for (int m = 0; m < MR; ++m)
        #pragma unroll
        for (int n = 0; n < NR; ++n)
          acc[m][n] = __builtin_amdgcn_mfma_f32_16x16x32_bf16(af[m], bfv[n], acc[m][n], 0, 0, 0);
    }
  }

  const int r0 = (lane >> 4) * 4;
  #pragma unroll
  for (int m = 0; m < MR; ++m) {
    #pragma unroll
    for (int n = 0; n < NR; ++n) {
      int gc = n0 + wn * WNt + n * 16 + lr;
      float bv = bias[gc];
      #pragma unroll
      for (int r = 0; r < 4; ++r) {
        int gr = m0 + wm * WMt + m * 16 + r0 + r;
        float v = acc[m][n][r] + bv;
        if (mode == 1)
          ((bf16*)C)[(size_t)gr * N + gc] = __float2bfloat16(v > 0.f ? v : 0.f);
        else
          ((float*)C)[(size_t)gr * N + gc] = v;
      }
    }
  }
}

// ---------------------------------------------------------------------------
// FUSED GRU (64x64x3 gates, acc = 32 VGPRs), single-barrier 3-buffer loop.
// 256 jobs. LDS: A 3x8KB [0,24K) + B 3x24KB [24K,96K). L=4 per stage.
// ---------------------------------------------------------------------------
__device__ void fused_gru(const bf16* __restrict__ hidden, const bf16* __restrict__ belsrc,
                          const bf16* __restrict__ WiT, const bf16* __restrict__ WhT,
                          const float* __restrict__ bi, const float* __restrict__ bh,
                          float* __restrict__ belief_f32, float* __restrict__ out_bel,
                          bf16* __restrict__ belslot,
                          int job, int tid, char* pool)
{
  bf16 (*sA)[64 * 64]  = (bf16(*)[64 * 64])pool;              // 3 x 8KB
  bf16 (*sB)[192 * 64] = (bf16(*)[192 * 64])(pool + 24576);   // 3 x 24KB

  const int m0 = (job & 7) * 64;
  const int j0 = (job >> 3) * 64;
  const int lane = tid & 63;
  const int wid = tid >> 6;
  const int wm = wid >> 2, wn = wid & 3;   // 2 m x 4 n; WMt=32, WNt=16
  const int lr = lane & 15;
  const int lg = lane >> 4;

  auto stage = [&](int buf, int gt) {
    const bf16* Ab; const bf16* Bb; int k0;
    if (gt < 32) { Ab = hidden; Bb = WiT; k0 = gt << 6; }
    else         { Ab = belsrc; Bb = WhT; k0 = (gt - 32) << 6; }
    {
      int c = tid;                       // A: 64 rows x 8 chunks = 512
      int row = c >> 3, kc = c & 7;
      gload_lds16(Ab + (size_t)(m0 + row) * 2048 + k0 + ((kc ^ (row & 7)) << 3),
                  &sA[buf][c * 8]);
    }
    #pragma unroll
    for (int i = 0; i < 3; ++i) {        // B: 192 rows (3 gates x 64)
      int c = i * NT + tid;
      int r = c >> 3, kc = c & 7;
      int grow = (r >> 6) * 2048 + j0 + (r & 63);
      gload_lds16(Bb + (size_t)grow * 2048 + k0 + ((kc ^ (r & 7)) << 3),
                  &sB[buf][c * 8]);
    }
  };

  f32x4 ar_[2] = {}, az_[2] = {}, ain[2] = {}, ahn[2] = {};

  auto body = [&](int gt, f32x4 (&ax)[2]) {
    const int cur = gt % 3;
    if (gt < 63) { asm volatile("s_waitcnt vmcnt(4)" ::: "memory"); }
    else         { asm volatile("s_waitcnt vmcnt(0)" ::: "memory"); }
    __builtin_amdgcn_sched_barrier(0);
    __builtin_amdgcn_s_barrier();
    __builtin_amdgcn_sched_barrier(0);
    if (gt + 2 < 64) stage((gt + 2) % 3, gt + 2);
    #pragma unroll
    for (int kk = 0; kk < 2; ++kk) {
      const int jg = kk * 4 + lg;
      bf16x8v af[2], bg[3];
      #pragma unroll
      for (int m = 0; m < 2; ++m) {
        int arow = wm * 32 + m * 16 + lr;
        af[m] = *(const bf16x8v*)&sA[cur][arow * 64 + ((jg ^ (arow & 7)) << 3)];
      }
      #pragma unroll
      for (int g = 0; g < 3; ++g) {
        int br = g * 64 + wn * 16 + lr;
        bg[g] = *(const bf16x8v*)&sB[cur][br * 64 + ((jg ^ (br & 7)) << 3)];
      }
      #pragma unroll
      for (int m = 0; m < 2; ++m) {
        ar_[m] = __builtin_amdgcn_mfma_f32_16x16x32_bf16(af[m], bg[0], ar_[m], 0, 0, 0);
        az_[m] = __builtin_amdgcn_mfma_f32_16x16x32_bf16(af[m], bg[1], az_[m], 0, 0, 0);
        ax[m]  = __builtin_amdgcn_mfma_f32_16x16x32_bf16(af[m], bg[2], ax[m], 0, 0, 0);
      }
    }
  };

  __syncthreads();                 // pool handoff
  stage(0, 0);
  stage(1, 1);
  for (int gt = 0; gt < 32; ++gt) body(gt, ain);
  for (int gt = 32; gt < 64; ++gt) body(gt, ahn);

  const int gc = j0 + wn * 16 + lr;
  const float br_b  = bi[gc] + bh[gc];
  const float bz_b  = bi[2048 + gc] + bh[2048 + gc];
  const float bin_b = bi[4096 + gc];
  const float bhn_b = bh[4096 + gc];
  const int r0 = (lane >> 4) * 4;
  #pragma unroll
  for (int m = 0; m < 2; ++m) {
    #pragma unroll
    for (int r = 0; r < 4; ++r) {
      int grow = m0 + wm * 32 + m * 16 + r0 + r;
      size_t idx = (size_t)grow * 2048 + gc;
      float rr = sigmoidf_(ar_[m][r] + br_b);
      float zz = sigmoidf_(az_[m][r] + bz_b);
      float nn = tanhf(ain[m][r] + bin_b + rr * (ahn[m][r] + bhn_b));
      float bo = belief_f32[idx];
      float nb = (1.f - zz) * nn + zz * bo;
      belief_f32[idx] = nb;
      nts(nb, &out_bel[idx]);
      belslot[idx] = __float2bfloat16(nb);
    }
  }
}

// ---------------------------------------------------------------------------
// W1p GEMM (64x64), single-barrier 3-buffer loop: dual-source A
// (belA 2048 ++ obs 1024), K=3072, 256 jobs. LDS 3x8KB + 3x8KB = 48KB. L=2.
// ---------------------------------------------------------------------------
__device__ void gemm_w1p(const bf16* __restrict__ Abel, const bf16* __restrict__ Aobs,
                         const bf16* __restrict__ B, const float* __restrict__ bias,
                         bf16* __restrict__ C, int job, int tid, char* pool)
{
  constexpr int K = 3072, NK = 48;
  bf16 (*sA)[64 * 64] = (bf16(*)[64 * 64])pool;               // 3 x 8KB
  bf16 (*sB)[64 * 64] = (bf16(*)[64 * 64])(pool + 24576);     // 3 x 8KB

  const int m0 = (job & 7) * 64;
  const int n0 = (job >> 3) * 64;
  const int lane = tid & 63;
  const int wid = tid >> 6;
  const int wm = wid >> 1, wn = wid & 1;   // 4 x 2; WMt=16, WNt=32
  const int lr = lane & 15;
  const int lg = lane >> 4;

  auto stage = [&](int buf, int k0) {
    {
      int c = tid;
      int row = c >> 3, kc = c & 7;
      int sw = (kc ^ (row & 7)) << 3;
      const bf16* src = (k0 < 2048)
          ? Abel + (size_t)(m0 + row) * 2048 + k0 + sw
          : Aobs + (size_t)(m0 + row) * 1024 + (k0 - 2048) + sw;
      gload_lds16(src, &sA[buf][c * 8]);
    }
    {
      int c = tid;
      int row = c >> 3, kc = c & 7;
      gload_lds16(B + (size_t)(n0 + row) * K + k0 + ((kc ^ (row & 7)) << 3), &sB[buf][c * 8]);
    }
  };

  f32x4 acc[2] = {};
  __syncthreads();
  stage(0, 0);
  stage(1, 64);
  for (int it = 0; it < NK; ++it) {
    const int cur = it % 3;
    if (it + 1 < NK) { asm volatile("s_waitcnt vmcnt(2)" ::: "memory"); }
    else             { asm volatile("s_waitcnt vmcnt(0)" ::: "memory"); }
    __builtin_amdgcn_sched_barrier(0);
    __builtin_amdgcn_s_barrier();
    __builtin_amdgcn_sched_barrier(0);
    if (it + 2 < NK) stage((it + 2) % 3, (it + 2) << 6);
    #pragma unroll
    for (int kk = 0; kk < 2; ++kk) {
      const int jg = kk * 4 + lg;
      int arow = wm * 16 + lr;
      bf16x8v af = *(const bf16x8v*)&sA[cur][arow * 64 + ((jg ^ (arow & 7)) << 3)];
      #pragma unroll
      for (int n = 0; n < 2; ++n) {
        int br = wn * 32 + n * 16 + lr;
        bf16x8v bv = *(const bf16x8v*)&sB[cur][br * 64 + ((jg ^ (br & 7)) << 3)];
        acc[n] = __builtin_amdgcn_mfma_f32_16x16x32_bf16(af, bv, acc[n], 0, 0, 0);
      }
    }
  }

  const int r0 = (lane >> 4) * 4;
  #pragma unroll
  for (int n = 0; n < 2; ++n) {
    int gcn = n0 + wn * 32 + n * 16 + lr;
    float bv = bias[gcn];
    #pragma unroll
    for (int r = 0; r < 4; ++r) {
      int gr = m0 + wm * 16 + r0 + r;
      float v = acc[n][r] + bv;
      C[(size_t)gr * 2048 + gcn] = __float2bfloat16(v > 0.f ? v : 0.f);
    }
  }
}

// ---------------------------------------------------------------------------
// fused W2p GEMM (512x512, K=2048) + posterior epilogue, single-barrier loop.
// 64 jobs: mb 0..7, nl 0..7 (32-col strip of BOTH loc and raw). LDS 48KB.
// ---------------------------------------------------------------------------
__device__ void w2p_tile(const bf16* __restrict__ hq, const bf16* __restrict__ W2pT,
                         const float* __restrict__ b2p, const float* __restrict__ eps,
                         float* __restrict__ o_mu, float* __restrict__ o_sd,
                         float* __restrict__ o_st,
                         const float* __restrict__ nt_next,
                         const float* __restrict__ act_next,
                         bf16* __restrict__ xcat, int make_xcat,
                         int blk, int tid, char* pool)
{
  constexpr int K = 2048, NK = K / 64;
  const int mb = blk & 7, nl = blk >> 3;
  const int m0 = mb * 64;
  const int j0 = nl * 32;

  bf16 (*sA)[64 * 64] = (bf16(*)[64 * 64])pool;               // 3 x 8KB
  bf16 (*sB)[64 * 64] = (bf16(*)[64 * 64])(pool + 24576);     // 3 x 8KB
  float* tile = (float*)pool;                                  // 16KB reuse

  const int lane = tid & 63;
  const int wid = tid >> 6;
  const int wm = wid >> 1, wn = wid & 1;
  const int lr = lane & 15;
  const int lg = lane >> 4;

  const bf16* Abase = hq + (size_t)m0 * K;

  auto stage = [&](int buf, int k0) {
    {
      int c = tid;
      int row = c >> 3, kc = c & 7;
      gload_lds16(Abase + (size_t)row * K + k0 + ((kc ^ (row & 7)) << 3), &sA[buf][c * 8]);
    }
    {
      int c = tid;
      int row = c >> 3, kc = c & 7;
      int grow = (row < 32) ? (j0 + row) : (224 + j0 + row);
      gload_lds16(W2pT + (size_t)grow * K + k0 + ((kc ^ (row & 7)) << 3), &sB[buf][c * 8]);
    }
  };

  f32x4 acc[2] = {};
  __syncthreads();
  stage(0, 0);
  stage(1, 64);
  for (int it = 0; it < NK; ++it) {
    const int cur = it % 3;
    if (it + 1 < NK) { asm volatile("s_waitcnt vmcnt(2)" ::: "memory"); }
    else             { asm volatile("s_waitcnt vmcnt(0)" ::: "memory"); }
    __builtin_amdgcn_sched_barrier(0);
    __builtin_amdgcn_s_barrier();
    __builtin_amdgcn_sched_barrier(0);
    if (it + 2 < NK) stage((it + 2) % 3, (it + 2) << 6);
    #pragma unroll
    for (int kk = 0; kk < 2; ++kk) {
      const int jg = kk * 4 + lg;
      int ar = wm * 16 + lr;
      bf16x8v af = *(const bf16x8v*)&sA[cur][ar * 64 + ((jg ^ (ar & 7)) << 3)];
      #pragma unroll
      for (int n = 0; n < 2; ++n) {
        int br = wn * 32 + n * 16 + lr;
        bf16x8v bfv = *(const bf16x8v*)&sB[cur][br * 64 + ((jg ^ (br & 7)) << 3)];
        acc[n] = __builtin_amdgcn_mfma_f32_16x16x32_bf16(af, bfv, acc[n], 0, 0, 0);
      }
    }
  }
  __syncthreads();   // all waves done reading sA/sB before pool reuse as tile

  const int r0 = (lane >> 4) * 4;
  #pragma unroll
  for (int n = 0; n < 2; ++n) {
    int tc = wn * 32 + n * 16 + lr;
    #pragma unroll
    for (int r = 0; r < 4; ++r)
      tile[(wm * 16 + r0 + r) * 64 + tc] = acc[n][r];
  }
  __syncthreads();

  for (int e = tid; e < 64 * 32; e += NT) {
    int rr = e >> 5, cc = e & 31;
    int b = m0 + rr;
    int j = j0 + cc;
    float loc = tile[rr * 64 + cc] + b2p[j];
    float raw = tile[rr * 64 + 32 + cc] + b2p[256 + j];
    float sp = (raw > 20.f) ? raw : log1pf(__expf(raw));
    float scale = sp + 0.1f;
    float st = loc + scale * eps[(size_t)b * 256 + j];
    nts(loc,   &o_mu[(size_t)b * 256 + j]);
    nts(scale, &o_sd[(size_t)b * 256 + j]);
    nts(st,    &o_st[(size_t)b * 256 + j]);
    if (make_xcat)
      xcat[(size_t)b * 320 + j] = __float2bfloat16(st * nt_next[b]);
  }
  if (make_xcat && nl == 0) {
    for (int e = tid; e < 64 * 64; e += NT) {
      int rr = e >> 6, cc = e & 63;
      int b = m0 + rr;
      xcat[(size_t)b * 320 + 256 + cc] = __float2bfloat16(act_next[(size_t)b * 64 + cc]);
    }
  }
}

// ---------------------------------------------------------------------------
__device__ void transpose_phase(const float* __restrict__ src, bf16* __restrict__ dst,
                                int K, int N, int bid, int tid, float* t /*32x33*/)
{
  const int ntile = (K / 32) * (N / 32);
  const int tx = tid & 31, ty = tid >> 5;   // 32 x 16
  for (int it = bid; it < ntile; it += NB) {
    int kt = it % (K / 32), nt = it / (K / 32);
    int k0 = kt * 32, n0 = nt * 32;
    __syncthreads();
    #pragma unroll
    for (int i = 0; i < 32; i += 16)
      t[(ty + i) * 33 + tx] = src[(size_t)(k0 + ty + i) * N + n0 + tx];
    __syncthreads();
    #pragma unroll
    for (int i = 0; i < 32; i += 16)
      dst[(size_t)(n0 + ty + i) * K + k0 + tx] = __float2bfloat16(t[tx * 33 + ty + i]);
  }
}

struct Args {
  const float *prev_state, *actions, *prev_belief, *obs_emb, *nonterm;
  const float *W_embed, *b_embed, *Wi, *bi, *Wh, *bh;
  const float *W1, *b1, *W2, *b2, *W1p, *b1p, *W2p, *b2p;
  const float *eps_p, *eps_q;
  bf16 *WembT, *WiT, *WhT, *W1T, *W2T, *W1pT, *W2pT;
  float* belief_f32; bf16 *bel_init, *xcat, *hidden, *obsB;
  bf16 *hq, *belA, *hp; float* yp;
  float* out;
  unsigned* cnt;
};

// ---------------------------------------------------------------------------
__global__ __launch_bounds__(NT, 2) void mega(Args a)
{
  extern __shared__ char pool[];        // 96 KB
  const int bid = blockIdx.x;
  const int tid = threadIdx.x;
  const int sj = ((bid & 7) << 5) | (bid >> 3);   // XCD-grouped job id (256 jobs)
  unsigned ep = 0;

  // ---- P0: weight transposes + init + obs bf16 precompute ----
  transpose_phase(a.W_embed, a.WembT, 320, 2048, bid, tid, (float*)pool);
  transpose_phase(a.Wi,  a.WiT,  2048, 6144, bid, tid, (float*)pool);
  transpose_phase(a.Wh,  a.WhT,  2048, 6144, bid, tid, (float*)pool);
  transpose_phase(a.W1,  a.W1T,  2048, 2048, bid, tid, (float*)pool);
  transpose_phase(a.W2,  a.W2T,  2048, 512,  bid, tid, (float*)pool);
  transpose_phase(a.W1p, a.W1pT, 3072, 2048, bid, tid, (float*)pool);
  transpose_phase(a.W2p, a.W2pT, 2048, 512,  bid, tid, (float*)pool);
  for (int i = bid * NT + tid; i < 512 * 2048; i += NB * NT) {
    float v = a.prev_belief[i];
    a.belief_f32[i] = v;
    a.bel_init[i] = __float2bfloat16(v);
  }
  for (int i = bid * NT + tid; i < 512 * 320; i += NB * NT) {
    int b = i / 320, c = i - b * 320;
    float v = (c < 256) ? a.prev_state[b * 256 + c] * a.nonterm[b]
                        : a.actions[b * 64 + (c - 256)];
    a.xcat[i] = __float2bfloat16(v);
  }
  for (int i = bid * NT + tid; i < TM1 * 512 * 1024 / 4; i += NB * NT) {
    float4 v = *(const float4*)&a.obs_emb[(size_t)i * 4];
    ushort4 u; u.x = bfb(v.x); u.y = bfb(v.y); u.z = bfb(v.z); u.w = bfb(v.w);
    *(ushort4*)&a.obsB[(size_t)i * 4] = u;
  }
  gbar(a.cnt, ++ep, bid);

  // ---- hidden_0 = relu(xcat @ WembT + b_embed), 256 jobs 64x64 ----
  gemm_tile<64, 64>(a.xcat, a.WembT, a.b_embed, a.hidden, 2048, 320, 8, 1, sj, tid, pool);
  gbar(a.cnt, ++ep, bid);

  for (int t = 0; t < TM1; ++t) {
    // ---- fused GRU, 256 jobs 64x64x3 ----
    const bf16* belsrc = (t == 0) ? a.bel_init : a.belA + (size_t)(t - 1) * 512 * 2048;
    fused_gru(a.hidden, belsrc, a.WiT, a.WhT, a.bi, a.bh,
              a.belief_f32,
              a.out + OUT_BEL + (size_t)t * 512 * 2048,
              a.belA + (size_t)t * 512 * 2048,
              sj, tid, pool);
    gbar(a.cnt, ++ep, bid);

    // ---- W1p, 256 jobs 64x64 ----
    gemm_w1p(a.belA + (size_t)t * 512 * 2048,
             a.obsB + (size_t)t * 512 * 1024,
             a.W1pT, a.b1p, a.hq, sj, tid, pool);
    gbar(a.cnt, ++ep, bid);

    // ---- fused W2p + posterior (blocks 0..63) ; prior filler (64..255) ----
    {
      int tn = (t < TM1 - 1) ? t + 1 : t;
      if (bid < 64) {
        w2p_tile(a.hq, a.W2pT, a.b2p,
                 a.eps_q + (size_t)t * 512 * 256,
                 a.out + OUT_QMU + (size_t)t * 512 * 256,
                 a.out + OUT_QSD + (size_t)t * 512 * 256,
                 a.out + OUT_QST + (size_t)t * 512 * 256,
                 a.nonterm + (size_t)tn * 512,
                 a.actions + (size_t)tn * 512 * 64,
                 a.xcat, (t < TM1 - 1) ? 1 : 0, bid, tid, pool);
      } else if (t >= 8) {
        // folded prior for chunk fc = t/8 - 1
        const int fc = (t >> 3) - 1;
        const int q  = t & 7;
        const int fb = bid - 64;                     // 0..191
        const bf16* Ach = a.belA + (size_t)fc * 4096 * 2048;
        if (q < 2) {
          gemm_tile<128, 128>(Ach, a.W1T, a.b1, a.hp, 2048, 2048, 32, 1,
                              q * 192 + fb, tid, pool);
        } else if (q == 2) {
          if (fb < 128)
            gemm_tile<128, 128>(Ach, a.W1T, a.b1, a.hp, 2048, 2048, 32, 1,
                                384 + fb, tid, pool);
        } else if (q == 3) {
          if (fb < 128)
            gemm_tile<128, 128>(a.hp, a.W2T, a.b2, a.yp, 512, 2048, 32, 0,
                                fb, tid, pool);
        } else if (q == 4) {
          for (int i = fb * NT + tid; i < 4096 * 256; i += 192 * NT) {
            int r = i >> 8, j = i & 255;
            float loc = a.yp[(size_t)r * 512 + j];
            float raw = a.yp[(size_t)r * 512 + 256 + j];
            float sp = (raw > 20.f) ? raw : log1pf(__expf(raw));
            float scale = sp + 0.1f;
            size_t o = (size_t)fc * 4096 * 256 + i;
            nts(loc,                      &a.out[OUT_PMU + o]);
            nts(scale,                    &a.out[OUT_PSD + o]);
            nts(loc + scale * a.eps_p[o], &a.out[OUT_PST + o]);
          }
        }
      }
    }
    gbar(a.cnt, ++ep, bid);

    // ---- embed: hidden_{t+1}, 256 jobs 64x64 ----
    if (t < TM1 - 1) {
      gemm_tile<64, 64>(a.xcat, a.WembT, a.b_embed, a.hidden, 2048, 320, 8, 1, sj, tid, pool);
      gbar(a.cnt, ++ep, bid);
    }
  }

  // ---- tail: prior chunk 7 only ----
  {
    const bf16* Ach = a.belA + (size_t)7 * 4096 * 2048;
    gemm_tile<128, 128>(Ach, a.W1T, a.b1, a.hp, 2048, 2048, 32, 1, sj, tid, pool);
    gemm_tile<128, 128>(Ach, a.W1T, a.b1, a.hp, 2048, 2048, 32, 1, sj + 256, tid, pool);
    gbar(a.cnt, ++ep, bid);

    if (sj < 128)
      gemm_tile<128, 128>(a.hp, a.W2T, a.b2, a.yp, 512, 2048, 32, 0, sj, tid, pool);
    gbar(a.cnt, ++ep, bid);

    for (int i = bid * NT + tid; i < 4096 * 256; i += NB * NT) {
      int r = i >> 8, j = i & 255;
      float loc = a.yp[(size_t)r * 512 + j];
      float raw = a.yp[(size_t)r * 512 + 256 + j];
      float sp = (raw > 20.f) ? raw : log1pf(__expf(raw));
      float scale = sp + 0.1f;
      size_t o = (size_t)7 * 4096 * 256 + i;
      nts(loc,                      &a.out[OUT_PMU + o]);
      nts(scale,                    &a.out[OUT_PSD + o]);
      nts(loc + scale * a.eps_p[o], &a.out[OUT_PST + o]);
    }
    gbar(a.cnt, ++ep, bid);
  }
}

// ---------------------------------------------------------------------------
extern "C" void kernel_launch(void* const* d_in, const int* in_sizes, int n_in,
                              void* d_out, int out_size, void* d_ws, size_t ws_size,
                              hipStream_t stream)
{
  (void)in_sizes; (void)n_in; (void)out_size; (void)ws_size;
  Args a;
  a.prev_state = (const float*)d_in[0];
  a.actions    = (const float*)d_in[1];
  a.prev_belief= (const float*)d_in[2];
  a.obs_emb    = (const float*)d_in[3];
  a.nonterm    = (const float*)d_in[4];
  a.W_embed    = (const float*)d_in[5];
  a.b_embed    = (const float*)d_in[6];
  a.Wi         = (const float*)d_in[7];
  a.bi         = (const float*)d_in[8];
  a.Wh         = (const float*)d_in[9];
  a.bh         = (const float*)d_in[10];
  a.W1         = (const float*)d_in[11];
  a.b1         = (const float*)d_in[12];
  a.W2         = (const float*)d_in[13];
  a.b2         = (const float*)d_in[14];
  a.W1p        = (const float*)d_in[15];
  a.b1p        = (const float*)d_in[16];
  a.W2p        = (const float*)d_in[17];
  a.b2p        = (const float*)d_in[18];
  a.eps_p      = (const float*)d_in[19];
  a.eps_q      = (const float*)d_in[20];
  a.out        = (float*)d_out;

  char* ws = (char*)d_ws;
  size_t off = 0;
  auto alloc = [&](size_t bytes) -> char* {
    char* p = ws + off;
    off = (off + bytes + 255) & ~(size_t)255;
    return p;
  };
  a.cnt        = (unsigned*)alloc(4096);
  a.WembT      = (bf16*)alloc((size_t)2048 * 320 * 2);
  a.WiT        = (bf16*)alloc((size_t)6144 * 2048 * 2);
  a.WhT        = (bf16*)alloc((size_t)6144 * 2048 * 2);
  a.W1T        = (bf16*)alloc((size_t)2048 * 2048 * 2);
  a.W2T        = (bf16*)alloc((size_t)512 * 2048 * 2);
  a.W1pT       = (bf16*)alloc((size_t)2048 * 3072 * 2);
  a.W2pT       = (bf16*)alloc((size_t)512 * 2048 * 2);
  a.belief_f32 = (float*)alloc((size_t)512 * 2048 * 4);
  a.bel_init   = (bf16*)alloc((size_t)512 * 2048 * 2);
  a.xcat       = (bf16*)alloc((size_t)512 * 320 * 2);
  a.hidden     = (bf16*)alloc((size_t)512 * 2048 * 2);
  a.obsB       = (bf16*)alloc((size_t)TM1 * 512 * 1024 * 2);   // 67 MB
  a.hq         = (bf16*)alloc((size_t)512 * 2048 * 2);
  a.belA       = (bf16*)alloc((size_t)TM1 * 512 * 2048 * 2);   // 128 MB
  a.hp         = (bf16*)alloc((size_t)4096 * 2048 * 2);
  a.yp         = (float*)alloc((size_t)4096 * 512 * 4);

  hipFuncSetAttribute((const void*)mega,
                      hipFuncAttributeMaxDynamicSharedMemorySize, 98304);
  hipMemsetAsync(a.cnt, 0, 4096, stream);
  mega<<<NB, NT, 98304, stream>>>(a);
}

// Round 17
// 8522.038 us; speedup vs baseline: 2.1298x; 1.0338x over previous
//
#include <hip/hip_runtime.h>
#include <hip/hip_bf16.h>
#include <cstdint>

typedef __hip_bfloat16 bf16;
typedef __attribute__((ext_vector_type(8))) short bf16x8v;   // 8 bf16 in 4 VGPRs
typedef __attribute__((ext_vector_type(4))) float f32x4;

#define NB 256          // persistent blocks (1 per CU)
#define NT 512          // 8 waves (2 per SIMD)
#define TM1 64

// output offsets (elements) in d_out, per reference return order
#define OUT_BEL  ((size_t)0)
#define OUT_PST  ((size_t)67108864)
#define OUT_PMU  ((size_t)75497472)
#define OUT_PSD  ((size_t)83886080)
#define OUT_QST  ((size_t)92274688)
#define OUT_QMU  ((size_t)100663296)
#define OUT_QSD  ((size_t)109051904)

__device__ __forceinline__ void gload_lds16(const bf16* g, bf16* l) {
  __builtin_amdgcn_global_load_lds(
      (const __attribute__((address_space(1))) unsigned int*)g,
      (__attribute__((address_space(3))) unsigned int*)l, 16, 0, 0);
}

__device__ __forceinline__ unsigned short bfb(float f) {
  bf16 h = __float2bfloat16(f);
  return *reinterpret_cast<unsigned short*>(&h);
}

__device__ __forceinline__ float sigmoidf_(float x) { return 1.f / (1.f + __expf(-x)); }

// non-temporal stores: inter-phase streams don't dirty L2, so the per-barrier
// release-writeback has ~no payload (R16 fence-cost theory).
__device__ __forceinline__ void nts(float v, float* p) {
  __builtin_nontemporal_store(v, p);
}
__device__ __forceinline__ void ntsb(bf16 v, bf16* p) {
  __builtin_nontemporal_store(*reinterpret_cast<unsigned short*>(&v),
                              reinterpret_cast<unsigned short*>(p));
}

// ---------------------------------------------------------------------------
// hierarchical device-scope grid barrier (epoch-monotone, memset-zeroed)
// R16: split fences — release = wb-only, acquire = inv-only.
// ---------------------------------------------------------------------------
__device__ __forceinline__ void gbar(unsigned* bars, unsigned e, int bid) {
  __syncthreads();
  const int g = bid & 7;
  const int tid = threadIdx.x;
  if (tid == 0) {
    __builtin_amdgcn_fence(__ATOMIC_RELEASE, "agent");   // wbl2 only
    __hip_atomic_fetch_add(&bars[16 * g], 1u, __ATOMIC_RELAXED, __HIP_MEMORY_SCOPE_AGENT);
  }
  if (bid == 0) {
    if (tid < 8) {
      while (__hip_atomic_load(&bars[16 * tid], __ATOMIC_RELAXED, __HIP_MEMORY_SCOPE_AGENT) < 32u * e)
        __builtin_amdgcn_s_sleep(1);
    }
    __syncthreads();
    if (tid < 8)
      __hip_atomic_store(&bars[128 + 16 * tid], e, __ATOMIC_RELAXED, __HIP_MEMORY_SCOPE_AGENT);
  } else if (tid == 0) {
    while (__hip_atomic_load(&bars[128 + 16 * g], __ATOMIC_RELAXED, __HIP_MEMORY_SCOPE_AGENT) < e)
      __builtin_amdgcn_s_sleep(2);
  }
  if (tid == 0) __builtin_amdgcn_fence(__ATOMIC_ACQUIRE, "agent");   // inv only
  __syncthreads();
}

// ---------------------------------------------------------------------------
// generic GEMM tile — single-barrier K-loop, 3-buffer rotation (R15-proven).
// C stores are non-temporal (activation streams). acc <= 32 VGPRs.
// ---------------------------------------------------------------------------
template<int BM, int BN>
__device__ void gemm_tile(const bf16* __restrict__ A, const bf16* __restrict__ B,
                          const float* __restrict__ bias, void* __restrict__ C,
                          int N, int K, int nm, int mode, int job, int tid,
                          char* pool)
{
  constexpr int LA = BM * 8 / NT;
  constexpr int LB = BN * 8 / NT;
  constexpr int L = LA + LB;
  constexpr int WMt = BM / 4, WNt = BN / 2;
  constexpr int MR = WMt / 16, NR = WNt / 16;
  bf16* sAb = (bf16*)pool;                           // 3 x BM*64
  bf16* sBb = (bf16*)(pool + (size_t)3 * BM * 64 * 2);

  const int m0 = (job % nm) * BM;
  const int n0 = (job / nm) * BN;
  const int lane = tid & 63;
  const int wid = tid >> 6;
  const int wm = wid >> 1, wn = wid & 1;
  const int lr = lane & 15;
  const int lg = lane >> 4;

  const bf16* Abase = A + (size_t)m0 * K;
  const bf16* Bbase = B + (size_t)n0 * K;

  auto stage = [&](int buf, int k0) {
    bf16* dA = sAb + buf * (BM * 64);
    bf16* dB = sBb + buf * (BN * 64);
    #pragma unroll
    for (int i = 0; i < LA; ++i) {
      int c = i * NT + tid;
      int row = c >> 3, kc = c & 7;
      gload_lds16(Abase + (size_t)row * K + k0 + ((kc ^ (row & 7)) << 3), &dA[c * 8]);
    }
    #pragma unroll
    for (int i = 0; i < LB; ++i) {
      int c = i * NT + tid;
      int row = c >> 3, kc = c & 7;
      gload_lds16(Bbase + (size_t)row * K + k0 + ((kc ^ (row & 7)) << 3), &dB[c * 8]);
    }
  };

  f32x4 acc[MR][NR] = {};
  __syncthreads();                 // pool handoff
  const int nk = K >> 6;
  stage(0, 0);
  if (nk > 1) stage(1, 64);
  for (int it = 0; it < nk; ++it) {
    const int cur = it % 3;
    if (it + 1 < nk) { asm volatile("s_waitcnt vmcnt(%0)" :: "n"(L) : "memory"); }
    else             { asm volatile("s_waitcnt vmcnt(0)" ::: "memory"); }
    __builtin_amdgcn_sched_barrier(0);
    __builtin_amdgcn_s_barrier();
    __builtin_amdgcn_sched_barrier(0);
    if (it + 2 < nk) stage((it + 2) % 3, (it + 2) << 6);
    const bf16* cA = sAb + cur * (BM * 64);
    const bf16* cB = sBb + cur * (BN * 64);
    #pragma unroll
    for (int kk = 0; kk < 2; ++kk) {
      const int jg = kk * 4 + lg;
      bf16x8v af[MR], bfv[NR];
      #pragma unroll
      for (int m = 0; m < MR; ++m) {
        int ar = wm * WMt + m * 16 + lr;
        af[m] = *(const bf16x8v*)&cA[ar * 64 + ((jg ^ (ar & 7)) << 3)];
      }
      #pragma unroll
      for (int n = 0; n < NR; ++n) {
        int br = wn * WNt + n * 16 + lr;
        bfv[n] = *(const bf16x8v*)&cB[br * 64 + ((jg ^ (br & 7)) << 3)];
      }
      #pragma unroll
      for (int m = 0; m < MR; ++m)
        #pragma unroll
        for (int n = 0; n < NR; ++n)
          acc[m][n] = __builtin_amdgcn_mfma_f32_16x16x32_bf16(af[m], bfv[n], acc[m][n], 0, 0, 0);
    }
  }

  const int r0 = (lane >> 4) * 4;
  #pragma unroll
  for (int m = 0; m < MR; ++m) {
    #pragma unroll
    for (int n = 0; n < NR; ++n) {
      int gc = n0 + wn * WNt + n * 16 + lr;
      float bv = bias[gc];
      #pragma unroll
      for (int r = 0; r < 4; ++r) {
        int gr = m0 + wm * WMt + m * 16 + r0 + r;
        float v = acc[m][n][r] + bv;
        if (mode == 1)
          ntsb(__float2bfloat16(v > 0.f ? v : 0.f), &((bf16*)C)[(size_t)gr * N + gc]);
        else
          nts(v, &((float*)C)[(size_t)gr * N + gc]);
      }
    }
  }
}

// ---------------------------------------------------------------------------
// FUSED GRU (64x64x3 gates, acc = 32 VGPRs), single-barrier 3-buffer loop.
// 256 jobs. LDS: A 3x8KB [0,24K) + B 3x24KB [24K,96K). L=4 per stage.
// ---------------------------------------------------------------------------
__device__ void fused_gru(const bf16* __restrict__ hidden, const bf16* __restrict__ belsrc,
                          const bf16* __restrict__ WiT, const bf16* __restrict__ WhT,
                          const float* __restrict__ bi, const float* __restrict__ bh,
                          float* __restrict__ belief_f32, float* __restrict__ out_bel,
                          bf16* __restrict__ belslot,
                          int job, int tid, char* pool)
{
  bf16 (*sA)[64 * 64]  = (bf16(*)[64 * 64])pool;              // 3 x 8KB
  bf16 (*sB)[192 * 64] = (bf16(*)[192 * 64])(pool + 24576);   // 3 x 24KB

  const int m0 = (job & 7) * 64;
  const int j0 = (job >> 3) * 64;
  const int lane = tid & 63;
  const int wid = tid >> 6;
  const int wm = wid >> 2, wn = wid & 3;   // 2 m x 4 n; WMt=32, WNt=16
  const int lr = lane & 15;
  const int lg = lane >> 4;

  auto stage = [&](int buf, int gt) {
    const bf16* Ab; const bf16* Bb; int k0;
    if (gt < 32) { Ab = hidden; Bb = WiT; k0 = gt << 6; }
    else         { Ab = belsrc; Bb = WhT; k0 = (gt - 32) << 6; }
    {
      int c = tid;                       // A: 64 rows x 8 chunks = 512
      int row = c >> 3, kc = c & 7;
      gload_lds16(Ab + (size_t)(m0 + row) * 2048 + k0 + ((kc ^ (row & 7)) << 3),
                  &sA[buf][c * 8]);
    }
    #pragma unroll
    for (int i = 0; i < 3; ++i) {        // B: 192 rows (3 gates x 64)
      int c = i * NT + tid;
      int r = c >> 3, kc = c & 7;
      int grow = (r >> 6) * 2048 + j0 + (r & 63);
      gload_lds16(Bb + (size_t)grow * 2048 + k0 + ((kc ^ (r & 7)) << 3),
                  &sB[buf][c * 8]);
    }
  };

  f32x4 ar_[2] = {}, az_[2] = {}, ain[2] = {}, ahn[2] = {};

  auto body = [&](int gt, f32x4 (&ax)[2]) {
    const int cur = gt % 3;
    if (gt < 63) { asm volatile("s_waitcnt vmcnt(4)" ::: "memory"); }
    else         { asm volatile("s_waitcnt vmcnt(0)" ::: "memory"); }
    __builtin_amdgcn_sched_barrier(0);
    __builtin_amdgcn_s_barrier();
    __builtin_amdgcn_sched_barrier(0);
    if (gt + 2 < 64) stage((gt + 2) % 3, gt + 2);
    #pragma unroll
    for (int kk = 0; kk < 2; ++kk) {
      const int jg = kk * 4 + lg;
      bf16x8v af[2], bg[3];
      #pragma unroll
      for (int m = 0; m < 2; ++m) {
        int arow = wm * 32 + m * 16 + lr;
        af[m] = *(const bf16x8v*)&sA[cur][arow * 64 + ((jg ^ (arow & 7)) << 3)];
      }
      #pragma unroll
      for (int g = 0; g < 3; ++g) {
        int br = g * 64 + wn * 16 + lr;
        bg[g] = *(const bf16x8v*)&sB[cur][br * 64 + ((jg ^ (br & 7)) << 3)];
      }
      #pragma unroll
      for (int m = 0; m < 2; ++m) {
        ar_[m] = __builtin_amdgcn_mfma_f32_16x16x32_bf16(af[m], bg[0], ar_[m], 0, 0, 0);
        az_[m] = __builtin_amdgcn_mfma_f32_16x16x32_bf16(af[m], bg[1], az_[m], 0, 0, 0);
        ax[m]  = __builtin_amdgcn_mfma_f32_16x16x32_bf16(af[m], bg[2], ax[m], 0, 0, 0);
      }
    }
  };

  __syncthreads();                 // pool handoff
  stage(0, 0);
  stage(1, 1);
  for (int gt = 0; gt < 32; ++gt) body(gt, ain);
  for (int gt = 32; gt < 64; ++gt) body(gt, ahn);

  const int gc = j0 + wn * 16 + lr;
  const float br_b  = bi[gc] + bh[gc];
  const float bz_b  = bi[2048 + gc] + bh[2048 + gc];
  const float bin_b = bi[4096 + gc];
  const float bhn_b = bh[4096 + gc];
  const int r0 = (lane >> 4) * 4;
  #pragma unroll
  for (int m = 0; m < 2; ++m) {
    #pragma unroll
    for (int r = 0; r < 4; ++r) {
      int grow = m0 + wm * 32 + m * 16 + r0 + r;
      size_t idx = (size_t)grow * 2048 + gc;
      float rr = sigmoidf_(ar_[m][r] + br_b);
      float zz = sigmoidf_(az_[m][r] + bz_b);
      float nn = tanhf(ain[m][r] + bin_b + rr * (ahn[m][r] + bhn_b));
      float bo = belief_f32[idx];
      float nb = (1.f - zz) * nn + zz * bo;
      belief_f32[idx] = nb;                 // block-local carry: cached
      nts(nb, &out_bel[idx]);               // output stream: NT
      ntsb(__float2bfloat16(nb), &belslot[idx]);  // inter-phase stream: NT
    }
  }
}

// ---------------------------------------------------------------------------
// W1p GEMM (64x64), single-barrier 3-buffer loop: dual-source A
// (belA 2048 ++ obs 1024), K=3072, 256 jobs. LDS 48KB. L=2.
// ---------------------------------------------------------------------------
__device__ void gemm_w1p(const bf16* __restrict__ Abel, const bf16* __restrict__ Aobs,
                         const bf16* __restrict__ B, const float* __restrict__ bias,
                         bf16* __restrict__ C, int job, int tid, char* pool)
{
  constexpr int K = 3072, NK = 48;
  bf16 (*sA)[64 * 64] = (bf16(*)[64 * 64])pool;               // 3 x 8KB
  bf16 (*sB)[64 * 64] = (bf16(*)[64 * 64])(pool + 24576);     // 3 x 8KB

  const int m0 = (job & 7) * 64;
  const int n0 = (job >> 3) * 64;
  const int lane = tid & 63;
  const int wid = tid >> 6;
  const int wm = wid >> 1, wn = wid & 1;   // 4 x 2; WMt=16, WNt=32
  const int lr = lane & 15;
  const int lg = lane >> 4;

  auto stage = [&](int buf, int k0) {
    {
      int c = tid;
      int row = c >> 3, kc = c & 7;
      int sw = (kc ^ (row & 7)) << 3;
      const bf16* src = (k0 < 2048)
          ? Abel + (size_t)(m0 + row) * 2048 + k0 + sw
          : Aobs + (size_t)(m0 + row) * 1024 + (k0 - 2048) + sw;
      gload_lds16(src, &sA[buf][c * 8]);
    }
    {
      int c = tid;
      int row = c >> 3, kc = c & 7;
      gload_lds16(B + (size_t)(n0 + row) * K + k0 + ((kc ^ (row & 7)) << 3), &sB[buf][c * 8]);
    }
  };

  f32x4 acc[2] = {};
  __syncthreads();
  stage(0, 0);
  stage(1, 64);
  for (int it = 0; it < NK; ++it) {
    const int cur = it % 3;
    if (it + 1 < NK) { asm volatile("s_waitcnt vmcnt(2)" ::: "memory"); }
    else             { asm volatile("s_waitcnt vmcnt(0)" ::: "memory"); }
    __builtin_amdgcn_sched_barrier(0);
    __builtin_amdgcn_s_barrier();
    __builtin_amdgcn_sched_barrier(0);
    if (it + 2 < NK) stage((it + 2) % 3, (it + 2) << 6);
    #pragma unroll
    for (int kk = 0; kk < 2; ++kk) {
      const int jg = kk * 4 + lg;
      int arow = wm * 16 + lr;
      bf16x8v af = *(const bf16x8v*)&sA[cur][arow * 64 + ((jg ^ (arow & 7)) << 3)];
      #pragma unroll
      for (int n = 0; n < 2; ++n) {
        int br = wn * 32 + n * 16 + lr;
        bf16x8v bv = *(const bf16x8v*)&sB[cur][br * 64 + ((jg ^ (br & 7)) << 3)];
        acc[n] = __builtin_amdgcn_mfma_f32_16x16x32_bf16(af, bv, acc[n], 0, 0, 0);
      }
    }
  }

  const int r0 = (lane >> 4) * 4;
  #pragma unroll
  for (int n = 0; n < 2; ++n) {
    int gcn = n0 + wn * 32 + n * 16 + lr;
    float bv = bias[gcn];
    #pragma unroll
    for (int r = 0; r < 4; ++r) {
      int gr = m0 + wm * 16 + r0 + r;
      float v = acc[n][r] + bv;
      ntsb(__float2bfloat16(v > 0.f ? v : 0.f), &C[(size_t)gr * 2048 + gcn]);
    }
  }
}

// ---------------------------------------------------------------------------
// fused W2p GEMM (512x512, K=2048) + posterior epilogue, single-barrier loop.
// ---------------------------------------------------------------------------
__device__ void w2p_tile(const bf16* __restrict__ hq, const bf16* __restrict__ W2pT,
                         const float* __restrict__ b2p, const float* __restrict__ eps,
                         float* __restrict__ o_mu, float* __restrict__ o_sd,
                         float* __restrict__ o_st,
                         const float* __restrict__ nt_next,
                         const float* __restrict__ act_next,
                         bf16* __restrict__ xcat, int make_xcat,
                         int blk, int tid, char* pool)
{
  constexpr int K = 2048, NK = K / 64;
  const int mb = blk & 7, nl = blk >> 3;
  const int m0 = mb * 64;
  const int j0 = nl * 32;

  bf16 (*sA)[64 * 64] = (bf16(*)[64 * 64])pool;               // 3 x 8KB
  bf16 (*sB)[64 * 64] = (bf16(*)[64 * 64])(pool + 24576);     // 3 x 8KB
  float* tile = (float*)pool;                                  // 16KB reuse

  const int lane = tid & 63;
  const int wid = tid >> 6;
  const int wm = wid >> 1, wn = wid & 1;
  const int lr = lane & 15;
  const int lg = lane >> 4;

  const bf16* Abase = hq + (size_t)m0 * K;

  auto stage = [&](int buf, int k0) {
    {
      int c = tid;
      int row = c >> 3, kc = c & 7;
      gload_lds16(Abase + (size_t)row * K + k0 + ((kc ^ (row & 7)) << 3), &sA[buf][c * 8]);
    }
    {
      int c = tid;
      int row = c >> 3, kc = c & 7;
      int grow = (row < 32) ? (j0 + row) : (224 + j0 + row);
      gload_lds16(W2pT + (size_t)grow * K + k0 + ((kc ^ (row & 7)) << 3), &sB[buf][c * 8]);
    }
  };

  f32x4 acc[2] = {};
  __syncthreads();
  stage(0, 0);
  stage(1, 64);
  for (int it = 0; it < NK; ++it) {
    const int cur = it % 3;
    if (it + 1 < NK) { asm volatile("s_waitcnt vmcnt(2)" ::: "memory"); }
    else             { asm volatile("s_waitcnt vmcnt(0)" ::: "memory"); }
    __builtin_amdgcn_sched_barrier(0);
    __builtin_amdgcn_s_barrier();
    __builtin_amdgcn_sched_barrier(0);
    if (it + 2 < NK) stage((it + 2) % 3, (it + 2) << 6);
    #pragma unroll
    for (int kk = 0; kk < 2; ++kk) {
      const int jg = kk * 4 + lg;
      int ar = wm * 16 + lr;
      bf16x8v af = *(const bf16x8v*)&sA[cur][ar * 64 + ((jg ^ (ar & 7)) << 3)];
      #pragma unroll
      for (int n = 0; n < 2; ++n) {
        int br = wn * 32 + n * 16 + lr;
        bf16x8v bfv = *(const bf16x8v*)&sB[cur][br * 64 + ((jg ^ (br & 7)) << 3)];
        acc[n] = __builtin_amdgcn_mfma_f32_16x16x32_bf16(af, bfv, acc[n], 0, 0, 0);
      }
    }
  }
  __syncthreads();   // all waves done reading sA/sB before pool reuse as tile

  const int r0 = (lane >> 4) * 4;
  #pragma unroll
  for (int n = 0; n < 2; ++n) {
    int tc = wn * 32 + n * 16 + lr;
    #pragma unroll
    for (int r = 0; r < 4; ++r)
      tile[(wm * 16 + r0 + r) * 64 + tc] = acc[n][r];
  }
  __syncthreads();

  for (int e = tid; e < 64 * 32; e += NT) {
    int rr = e >> 5, cc = e & 31;
    int b = m0 + rr;
    int j = j0 + cc;
    float loc = tile[rr * 64 + cc] + b2p[j];
    float raw = tile[rr * 64 + 32 + cc] + b2p[256 + j];
    float sp = (raw > 20.f) ? raw : log1pf(__expf(raw));
    float scale = sp + 0.1f;
    float st = loc + scale * eps[(size_t)b * 256 + j];
    nts(loc,   &o_mu[(size_t)b * 256 + j]);
    nts(scale, &o_sd[(size_t)b * 256 + j]);
    nts(st,    &o_st[(size_t)b * 256 + j]);
    if (make_xcat)
      ntsb(__float2bfloat16(st * nt_next[b]), &xcat[(size_t)b * 320 + j]);
  }
  if (make_xcat && nl == 0) {
    for (int e = tid; e < 64 * 64; e += NT) {
      int rr = e >> 6, cc = e & 63;
      int b = m0 + rr;
      ntsb(__float2bfloat16(act_next[(size_t)b * 64 + cc]),
           &xcat[(size_t)b * 320 + 256 + cc]);
    }
  }
}

// ---------------------------------------------------------------------------
__device__ void transpose_phase(const float* __restrict__ src, bf16* __restrict__ dst,
                                int K, int N, int bid, int tid, float* t /*32x33*/)
{
  const int ntile = (K / 32) * (N / 32);
  const int tx = tid & 31, ty = tid >> 5;   // 32 x 16
  for (int it = bid; it < ntile; it += NB) {
    int kt = it % (K / 32), nt = it / (K / 32);
    int k0 = kt * 32, n0 = nt * 32;
    __syncthreads();
    #pragma unroll
    for (int i = 0; i < 32; i += 16)
      t[(ty + i) * 33 + tx] = src[(size_t)(k0 + ty + i) * N + n0 + tx];
    __syncthreads();
    #pragma unroll
    for (int i = 0; i < 32; i += 16)
      dst[(size_t)(n0 + ty + i) * K + k0 + tx] = __float2bfloat16(t[tx * 33 + ty + i]);
  }
}

struct Args {
  const float *prev_state, *actions, *prev_belief, *obs_emb, *nonterm;
  const float *W_embed, *b_embed, *Wi, *bi, *Wh, *bh;
  const float *W1, *b1, *W2, *b2, *W1p, *b1p, *W2p, *b2p;
  const float *eps_p, *eps_q;
  bf16 *WembT, *WiT, *WhT, *W1T, *W2T, *W1pT, *W2pT;
  float* belief_f32; bf16 *bel_init, *xcat, *hidden, *obsB;
  bf16 *hq, *belA, *hp; float* yp;
  float* out;
  unsigned* cnt;
};

// ---------------------------------------------------------------------------
__global__ __launch_bounds__(NT, 2) void mega(Args a)
{
  extern __shared__ char pool[];        // 96 KB
  const int bid = blockIdx.x;
  const int tid = threadIdx.x;
  const int sj = ((bid & 7) << 5) | (bid >> 3);   // XCD-grouped job id (256 jobs)
  unsigned ep = 0;

  // ---- P0: weight transposes + init + obs bf16 precompute ----
  transpose_phase(a.W_embed, a.WembT, 320, 2048, bid, tid, (float*)pool);
  transpose_phase(a.Wi,  a.WiT,  2048, 6144, bid, tid, (float*)pool);
  transpose_phase(a.Wh,  a.WhT,  2048, 6144, bid, tid, (float*)pool);
  transpose_phase(a.W1,  a.W1T,  2048, 2048, bid, tid, (float*)pool);
  transpose_phase(a.W2,  a.W2T,  2048, 512,  bid, tid, (float*)pool);
  transpose_phase(a.W1p, a.W1pT, 3072, 2048, bid, tid, (float*)pool);
  transpose_phase(a.W2p, a.W2pT, 2048, 512,  bid, tid, (float*)pool);
  for (int i = bid * NT + tid; i < 512 * 2048; i += NB * NT) {
    float v = a.prev_belief[i];
    a.belief_f32[i] = v;
    a.bel_init[i] = __float2bfloat16(v);
  }
  for (int i = bid * NT + tid; i < 512 * 320; i += NB * NT) {
    int b = i / 320, c = i - b * 320;
    float v = (c < 256) ? a.prev_state[b * 256 + c] * a.nonterm[b]
                        : a.actions[b * 64 + (c - 256)];
    a.xcat[i] = __float2bfloat16(v);
  }
  for (int i = bid * NT + tid; i < TM1 * 512 * 1024 / 4; i += NB * NT) {
    float4 v = *(const float4*)&a.obs_emb[(size_t)i * 4];
    ushort4 u; u.x = bfb(v.x); u.y = bfb(v.y); u.z = bfb(v.z); u.w = bfb(v.w);
    *(ushort4*)&a.obsB[(size_t)i * 4] = u;
  }
  gbar(a.cnt, ++ep, bid);

  // ---- hidden_0 = relu(xcat @ WembT + b_embed), 256 jobs 64x64 ----
  gemm_tile<64, 64>(a.xcat, a.WembT, a.b_embed, a.hidden, 2048, 320, 8, 1, sj, tid, pool);
  gbar(a.cnt, ++ep, bid);

  for (int t = 0; t < TM1; ++t) {
    // ---- fused GRU, 256 jobs 64x64x3 ----
    const bf16* belsrc = (t == 0) ? a.bel_init : a.belA + (size_t)(t - 1) * 512 * 2048;
    fused_gru(a.hidden, belsrc, a.WiT, a.WhT, a.bi, a.bh,
              a.belief_f32,
              a.out + OUT_BEL + (size_t)t * 512 * 2048,
              a.belA + (size_t)t * 512 * 2048,
              sj, tid, pool);
    gbar(a.cnt, ++ep, bid);

    // ---- W1p, 256 jobs 64x64 ----
    gemm_w1p(a.belA + (size_t)t * 512 * 2048,
             a.obsB + (size_t)t * 512 * 1024,
             a.W1pT, a.b1p, a.hq, sj, tid, pool);
    gbar(a.cnt, ++ep, bid);

    // ---- fused W2p + posterior (blocks 0..63) ; prior filler (64..255) ----
    {
      int tn = (t < TM1 - 1) ? t + 1 : t;
      if (bid < 64) {
        w2p_tile(a.hq, a.W2pT, a.b2p,
                 a.eps_q + (size_t)t * 512 * 256,
                 a.out + OUT_QMU + (size_t)t * 512 * 256,
                 a.out + OUT_QSD + (size_t)t * 512 * 256,
                 a.out + OUT_QST + (size_t)t * 512 * 256,
                 a.nonterm + (size_t)tn * 512,
                 a.actions + (size_t)tn * 512 * 64,
                 a.xcat, (t < TM1 - 1) ? 1 : 0, bid, tid, pool);
      } else if (t >= 8) {
        // folded prior for chunk fc = t/8 - 1
        const int fc = (t >> 3) - 1;
        const int q  = t & 7;
        const int fb = bid - 64;                     // 0..191
        const bf16* Ach = a.belA + (size_t)fc * 4096 * 2048;
        if (q < 2) {
          gemm_tile<128, 128>(Ach, a.W1T, a.b1, a.hp, 2048, 2048, 32, 1,
                              q * 192 + fb, tid, pool);
        } else if (q == 2) {
          if (fb < 128)
            gemm_tile<128, 128>(Ach, a.W1T, a.b1, a.hp, 2048, 2048, 32, 1,
                                384 + fb, tid, pool);
        } else if (q == 3) {
          if (fb < 128)
            gemm_tile<128, 128>(a.hp, a.W2T, a.b2, a.yp, 512, 2048, 32, 0,
                                fb, tid, pool);
        } else if (q == 4) {
          for (int i = fb * NT + tid; i < 4096 * 256; i += 192 * NT) {
            int r = i >> 8, j = i & 255;
            float loc = a.yp[(size_t)r * 512 + j];
            float raw = a.yp[(size_t)r * 512 + 256 + j];
            float sp = (raw > 20.f) ? raw : log1pf(__expf(raw));
            float scale = sp + 0.1f;
            size_t o = (size_t)fc * 4096 * 256 + i;
            nts(loc,                      &a.out[OUT_PMU + o]);
            nts(scale,                    &a.out[OUT_PSD + o]);
            nts(loc + scale * a.eps_p[o], &a.out[OUT_PST + o]);
          }
        }
      }
    }
    gbar(a.cnt, ++ep, bid);

    // ---- embed: hidden_{t+1}, 256 jobs 64x64 ----
    if (t < TM1 - 1) {
      gemm_tile<64, 64>(a.xcat, a.WembT, a.b_embed, a.hidden, 2048, 320, 8, 1, sj, tid, pool);
      gbar(a.cnt, ++ep, bid);
    }
  }

  // ---- tail: prior chunk 7 only ----
  {
    const bf16* Ach = a.belA + (size_t)7 * 4096 * 2048;
    gemm_tile<128, 128>(Ach, a.W1T, a.b1, a.hp, 2048, 2048, 32, 1, sj, tid, pool);
    gemm_tile<128, 128>(Ach, a.W1T, a.b1, a.hp, 2048, 2048, 32, 1, sj + 256, tid, pool);
    gbar(a.cnt, ++ep, bid);

    if (sj < 128)
      gemm_tile<128, 128>(a.hp, a.W2T, a.b2, a.yp, 512, 2048, 32, 0, sj, tid, pool);
    gbar(a.cnt, ++ep, bid);

    for (int i = bid * NT + tid; i < 4096 * 256; i += NB * NT) {
      int r = i >> 8, j = i & 255;
      float loc = a.yp[(size_t)r * 512 + j];
      float raw = a.yp[(size_t)r * 512 + 256 + j];
      float sp = (raw > 20.f) ? raw : log1pf(__expf(raw));
      float scale = sp + 0.1f;
      size_t o = (size_t)7 * 4096 * 256 + i;
      nts(loc,                      &a.out[OUT_PMU + o]);
      nts(scale,                    &a.out[OUT_PSD + o]);
      nts(loc + scale * a.eps_p[o], &a.out[OUT_PST + o]);
    }
    gbar(a.cnt, ++ep, bid);
  }
}

// ---------------------------------------------------------------------------
extern "C" void kernel_launch(void* const* d_in, const int* in_sizes, int n_in,
                              void* d_out, int out_size, void* d_ws, size_t ws_size,
                              hipStream_t stream)
{
  (void)in_sizes; (void)n_in; (void)out_size; (void)ws_size;
  Args a;
  a.prev_state = (const float*)d_in[0];
  a.actions    = (const float*)d_in[1];
  a.prev_belief= (const float*)d_in[2];
  a.obs_emb    = (const float*)d_in[3];
  a.nonterm    = (const float*)d_in[4];
  a.W_embed    = (const float*)d_in[5];
  a.b_embed    = (const float*)d_in[6];
  a.Wi         = (const float*)d_in[7];
  a.bi         = (const float*)d_in[8];
  a.Wh         = (const float*)d_in[9];
  a.bh         = (const float*)d_in[10];
  a.W1         = (const float*)d_in[11];
  a.b1         = (const float*)d_in[12];
  a.W2         = (const float*)d_in[13];
  a.b2         = (const float*)d_in[14];
  a.W1p        = (const float*)d_in[15];
  a.b1p        = (const float*)d_in[16];
  a.W2p        = (const float*)d_in[17];
  a.b2p        = (const float*)d_in[18];
  a.eps_p      = (const float*)d_in[19];
  a.eps_q      = (const float*)d_in[20];
  a.out        = (float*)d_out;

  char* ws = (char*)d_ws;
  size_t off = 0;
  auto alloc = [&](size_t bytes) -> char* {
    char* p = ws + off;
    off = (off + bytes + 255) & ~(size_t)255;
    return p;
  };
  a.cnt        = (unsigned*)alloc(4096);
  a.WembT      = (bf16*)alloc((size_t)2048 * 320 * 2);
  a.WiT        = (bf16*)alloc((size_t)6144 * 2048 * 2);
  a.WhT        = (bf16*)alloc((size_t)6144 * 2048 * 2);
  a.W1T        = (bf16*)alloc((size_t)2048 * 2048 * 2);
  a.W2T        = (bf16*)alloc((size_t)512 * 2048 * 2);
  a.W1pT       = (bf16*)alloc((size_t)2048 * 3072 * 2);
  a.W2pT       = (bf16*)alloc((size_t)512 * 2048 * 2);
  a.belief_f32 = (float*)alloc((size_t)512 * 2048 * 4);
  a.bel_init   = (bf16*)alloc((size_t)512 * 2048 * 2);
  a.xcat       = (bf16*)alloc((size_t)512 * 320 * 2);
  a.hidden     = (bf16*)alloc((size_t)512 * 2048 * 2);
  a.obsB       = (bf16*)alloc((size_t)TM1 * 512 * 1024 * 2);   // 67 MB
  a.hq         = (bf16*)alloc((size_t)512 * 2048 * 2);
  a.belA       = (bf16*)alloc((size_t)TM1 * 512 * 2048 * 2);   // 128 MB
  a.hp         = (bf16*)alloc((size_t)4096 * 2048 * 2);
  a.yp         = (float*)alloc((size_t)4096 * 512 * 4);

  (void)hipFuncSetAttribute((const void*)mega,
                            hipFuncAttributeMaxDynamicSharedMemorySize, 98304);
  (void)hipMemsetAsync(a.cnt, 0, 4096, stream);
  mega<<<NB, NT, 98304, stream>>>(a);
}